// Round 1
// baseline (656.474 us; speedup 1.0000x reference)
//
#include <hip/hip_runtime.h>

#define N_NODES 50000
#define N_EDGES 800000

// ---------------- edge-index dtype detection (int64 vs int32) ----------------
// If edge_index is int64 (little-endian), the high 32-bit word of every value
// is 0 (values in [0, 50000)). If int32, odd words are random node ids.
__global__ void detect_kernel(const unsigned* __restrict__ w, int* __restrict__ flag) {
    int i = blockIdx.x * blockDim.x + threadIdx.x;
    if (i < 1024) {
        if (w[2 * i + 1] != 0u) atomicOr(flag, 1);  // flag=1 -> int32 layout
    }
}

__device__ __forceinline__ int edge_elem(const unsigned* __restrict__ w, int is32, long long idx) {
    return is32 ? (int)w[idx] : (int)w[2 * idx];
}

// ---------------- CSR build ----------------
__global__ void hist_kernel(const unsigned* __restrict__ ew, const int* __restrict__ flag,
                            int* __restrict__ deg) {
    int e = blockIdx.x * blockDim.x + threadIdx.x;
    if (e >= N_EDGES) return;
    int is32 = *flag;
    int d = edge_elem(ew, is32, (long long)N_EDGES + e);
    atomicAdd(&deg[d], 1);
}

__global__ void __launch_bounds__(1024) scan_kernel(const int* __restrict__ deg,
                                                    int* __restrict__ row_ptr,
                                                    int* __restrict__ cursor) {
    __shared__ int sdata[1024];
    __shared__ int running;
    int t = threadIdx.x;
    if (t == 0) running = 0;
    __syncthreads();
    for (int base = 0; base < N_NODES; base += 1024) {
        int i = base + t;
        int v = (i < N_NODES) ? deg[i] : 0;
        sdata[t] = v;
        __syncthreads();
        for (int off = 1; off < 1024; off <<= 1) {
            int y = (t >= off) ? sdata[t - off] : 0;
            __syncthreads();
            sdata[t] += y;
            __syncthreads();
        }
        int incl = sdata[t];
        int r = running;
        if (i < N_NODES) {
            int ex = r + incl - v;
            row_ptr[i] = ex;
            cursor[i] = ex;
        }
        __syncthreads();
        if (t == 0) running = r + sdata[1023];
        __syncthreads();
    }
    if (t == 0) row_ptr[N_NODES] = running;
}

__global__ void scatter_kernel(const unsigned* __restrict__ ew, const int* __restrict__ flag,
                               int* __restrict__ cursor, int* __restrict__ src_csr) {
    int e = blockIdx.x * blockDim.x + threadIdx.x;
    if (e >= N_EDGES) return;
    int is32 = *flag;
    int s = edge_elem(ew, is32, e);
    int d = edge_elem(ew, is32, (long long)N_EDGES + e);
    int pos = atomicAdd(&cursor[d], 1);
    src_csr[pos] = s;
}

// ---------------- f32 GEMM: C[M,256] = A[M,K] @ B[K,256] ----------------
__global__ void __launch_bounds__(256) gemm_kernel(const float* __restrict__ A,
                                                   const float* __restrict__ B,
                                                   float* __restrict__ C, int M, int K) {
    __shared__ float Ast[16][64];  // [k][row] transposed
    __shared__ float Bs[16][64];   // [k][col]
    int tid = threadIdx.x;
    int tx = tid & 15, ty = tid >> 4;
    int rb = blockIdx.x * 64, cb = blockIdx.y * 64;
    float acc[4][4] = {};
    int ar = tid >> 2;          // 0..63 (A tile row)
    int ak = (tid & 3) * 4;     // 0,4,8,12 (A tile k)
    int br = tid >> 4;          // 0..15 (B tile k)
    int bc = (tid & 15) * 4;    // 0..60 (B tile col)
    for (int k0 = 0; k0 < K; k0 += 16) {
        float4 av = make_float4(0.f, 0.f, 0.f, 0.f);
        int arow = rb + ar;
        if (arow < M) av = *(const float4*)&A[(long long)arow * K + k0 + ak];
        float4 bv = *(const float4*)&B[(long long)(k0 + br) * 256 + cb + bc];
        __syncthreads();
        Ast[ak + 0][ar] = av.x;
        Ast[ak + 1][ar] = av.y;
        Ast[ak + 2][ar] = av.z;
        Ast[ak + 3][ar] = av.w;
        *(float4*)&Bs[br][bc] = bv;
        __syncthreads();
#pragma unroll
        for (int kk = 0; kk < 16; ++kk) {
            float4 a4 = *(const float4*)&Ast[kk][ty * 4];
            float4 b4 = *(const float4*)&Bs[kk][tx * 4];
            acc[0][0] += a4.x * b4.x; acc[0][1] += a4.x * b4.y; acc[0][2] += a4.x * b4.z; acc[0][3] += a4.x * b4.w;
            acc[1][0] += a4.y * b4.x; acc[1][1] += a4.y * b4.y; acc[1][2] += a4.y * b4.z; acc[1][3] += a4.y * b4.w;
            acc[2][0] += a4.z * b4.x; acc[2][1] += a4.z * b4.y; acc[2][2] += a4.z * b4.z; acc[2][3] += a4.z * b4.w;
            acc[3][0] += a4.w * b4.x; acc[3][1] += a4.w * b4.y; acc[3][2] += a4.w * b4.z; acc[3][3] += a4.w * b4.w;
        }
    }
#pragma unroll
    for (int ii = 0; ii < 4; ++ii) {
        int r = rb + ty * 4 + ii;
        if (r < M) {
            float4 o = make_float4(acc[ii][0], acc[ii][1], acc[ii][2], acc[ii][3]);
            *(float4*)&C[(long long)r * 256 + cb + tx * 4] = o;
        }
    }
}

// ---------------- per-node attention logits ----------------
__global__ void __launch_bounds__(256) alphas_kernel(const float* __restrict__ g,
                                                     const float* __restrict__ a_src,
                                                     const float* __restrict__ a_dst,
                                                     float* __restrict__ alpha_s,
                                                     float* __restrict__ alpha_d) {
    int i = blockIdx.x;
    int t = threadIdx.x;  // t = hd*64 + c
    float v = g[(long long)i * 256 + t];
    float s = v * a_src[t];
    float d = v * a_dst[t];
#pragma unroll
    for (int off = 32; off; off >>= 1) {
        s += __shfl_down(s, off, 64);
        d += __shfl_down(d, off, 64);
    }
    int lane = t & 63, hd = t >> 6;
    if (lane == 0) {
        alpha_s[i * 4 + hd] = s;
        alpha_d[i * 4 + hd] = d;
    }
}

// ---------------- softmax-weighted aggregation (one wave per node) ----------------
// lane l owns channels [4l, 4l+3], head = l>>4. Softmax without max-subtraction
// (mathematically identical; logits bounded ~|6| so exp is safe in fp32).
template <int LAYER>
__global__ void __launch_bounds__(256) aggregate_kernel(
    const float* __restrict__ g, const float* __restrict__ alpha_s,
    const float* __restrict__ alpha_d, const int* __restrict__ row_ptr,
    const int* __restrict__ src_csr, const float* __restrict__ bias,
    float* __restrict__ out, const float* __restrict__ fc_w,
    const float* __restrict__ fc_b, float* __restrict__ final_out) {
    int wave = threadIdx.x >> 6;
    int lane = threadIdx.x & 63;
    int i = blockIdx.x * 4 + wave;
    int hd = lane >> 4;
    const float4* g4 = (const float4*)g;

    float ad = alpha_d[i * 4 + hd];
    // self loop
    float e0 = alpha_s[i * 4 + hd] + ad;
    e0 = e0 > 0.f ? e0 : 0.2f * e0;
    float w0 = __expf(e0);
    float4 hv = g4[(long long)i * 64 + lane];
    float ax = w0 * hv.x, ay = w0 * hv.y, az = w0 * hv.z, aw = w0 * hv.w;
    float wsum = w0;

    int p1 = row_ptr[i + 1];
    for (int p = row_ptr[i]; p < p1; ++p) {
        int j = src_csr[p];
        float e = alpha_s[j * 4 + hd] + ad;
        e = e > 0.f ? e : 0.2f * e;
        float wt = __expf(e);
        wsum += wt;
        float4 hj = g4[(long long)j * 64 + lane];
        ax += wt * hj.x; ay += wt * hj.y; az += wt * hj.z; aw += wt * hj.w;
    }
    float inv = 1.f / (wsum + 1e-16f);
    int c = lane * 4;
    float4 b4 = *(const float4*)&bias[c];
    float o0 = ax * inv + b4.x;
    float o1 = ay * inv + b4.y;
    float o2 = az * inv + b4.z;
    float o3 = aw * inv + b4.w;
    // ELU
    o0 = o0 > 0.f ? o0 : __expf(o0) - 1.f;
    o1 = o1 > 0.f ? o1 : __expf(o1) - 1.f;
    o2 = o2 > 0.f ? o2 : __expf(o2) - 1.f;
    o3 = o3 > 0.f ? o3 : __expf(o3) - 1.f;
    if (LAYER == 1) {
        float4 o = make_float4(o0, o1, o2, o3);
        ((float4*)out)[(long long)i * 64 + lane] = o;
    } else {
        float4 fw = *(const float4*)&fc_w[c];
        float dot = o0 * fw.x + o1 * fw.y + o2 * fw.z + o3 * fw.w;
#pragma unroll
        for (int off = 32; off; off >>= 1) dot += __shfl_down(dot, off, 64);
        if (lane == 0) final_out[i] = 1.f / (1.f + __expf(-(dot + fc_b[0])));
    }
}

// ---------------- launch ----------------
extern "C" void kernel_launch(void* const* d_in, const int* in_sizes, int n_in,
                              void* d_out, int out_size, void* d_ws, size_t ws_size,
                              hipStream_t stream) {
    const float* x   = (const float*)d_in[0];
    const unsigned* ei = (const unsigned*)d_in[1];
    const float* W1  = (const float*)d_in[2];
    const float* as1 = (const float*)d_in[3];
    const float* ad1 = (const float*)d_in[4];
    const float* b1  = (const float*)d_in[5];
    const float* W2  = (const float*)d_in[6];
    const float* as2 = (const float*)d_in[7];
    const float* ad2 = (const float*)d_in[8];
    const float* b2  = (const float*)d_in[9];
    const float* fcw = (const float*)d_in[10];
    const float* fcb = (const float*)d_in[11];

    char* ws = (char*)d_ws;
    float* g       = (float*)(ws + 0);           // 50000*256 f32 = 51.2 MB
    float* hact    = (float*)(ws + 51200000);    // 51.2 MB
    float* asv     = (float*)(ws + 102400000);   // 0.8 MB
    float* adv     = (float*)(ws + 103200000);   // 0.8 MB
    int* row_ptr   = (int*)(ws + 104000000);     // 50001 ints
    int* deg       = (int*)(ws + 104200016);     // 50000 ints
    int* cursor    = (int*)(ws + 104400016);     // 50000 ints
    int* src_csr   = (int*)(ws + 104600016);     // 800000 ints
    int* flag      = (int*)(ws + 107800016);     // 1 int

    hipMemsetAsync(flag, 0, 4, stream);
    hipMemsetAsync(deg, 0, N_NODES * 4, stream);

    detect_kernel<<<4, 256, 0, stream>>>(ei, flag);
    hist_kernel<<<(N_EDGES + 255) / 256, 256, 0, stream>>>(ei, flag, deg);
    scan_kernel<<<1, 1024, 0, stream>>>(deg, row_ptr, cursor);
    scatter_kernel<<<(N_EDGES + 255) / 256, 256, 0, stream>>>(ei, flag, cursor, src_csr);

    // layer 1
    gemm_kernel<<<dim3((N_NODES + 63) / 64, 4), 256, 0, stream>>>(x, W1, g, N_NODES, 128);
    alphas_kernel<<<N_NODES, 256, 0, stream>>>(g, as1, ad1, asv, adv);
    aggregate_kernel<1><<<N_NODES / 4, 256, 0, stream>>>(g, asv, adv, row_ptr, src_csr, b1,
                                                         hact, nullptr, nullptr, nullptr);
    // layer 2
    gemm_kernel<<<dim3((N_NODES + 63) / 64, 4), 256, 0, stream>>>(hact, W2, g, N_NODES, 256);
    alphas_kernel<<<N_NODES, 256, 0, stream>>>(g, as2, ad2, asv, adv);
    aggregate_kernel<2><<<N_NODES / 4, 256, 0, stream>>>(g, asv, adv, row_ptr, src_csr, b2,
                                                         nullptr, fcw, fcb, (float*)d_out);
}

// Round 2
// 472.713 us; speedup vs baseline: 1.3887x; 1.3887x over previous
//
#include <hip/hip_runtime.h>
#include <hip/hip_bf16.h>

#define N_NODES 50000
#define N_EDGES 800000

__device__ __forceinline__ float bf2f(unsigned short u) {
    union { unsigned u32; float f; } v; v.u32 = (unsigned)u << 16; return v.f;
}
__device__ __forceinline__ unsigned short f2bf(float f) {
    __hip_bfloat16 h = __float2bfloat16(f);
    return *reinterpret_cast<unsigned short*>(&h);
}

// ---------------- edge-index dtype detection (int64 vs int32) ----------------
__global__ void detect_kernel(const unsigned* __restrict__ w, int* __restrict__ flag) {
    int i = blockIdx.x * blockDim.x + threadIdx.x;
    if (i < 1024) {
        if (w[2 * i + 1] != 0u) atomicOr(flag, 1);  // flag=1 -> int32 layout
    }
}

__device__ __forceinline__ int edge_elem(const unsigned* __restrict__ w, int is32, long long idx) {
    return is32 ? (int)w[idx] : (int)w[2 * idx];
}

// ---------------- CSR build ----------------
__global__ void hist_kernel(const unsigned* __restrict__ ew, const int* __restrict__ flag,
                            int* __restrict__ deg) {
    int e = blockIdx.x * blockDim.x + threadIdx.x;
    if (e >= N_EDGES) return;
    int is32 = *flag;
    int d = edge_elem(ew, is32, (long long)N_EDGES + e);
    atomicAdd(&deg[d], 1);
}

// block-level scan (196 blocks x 256)
__global__ void __launch_bounds__(256) scan1_kernel(const int* __restrict__ deg,
                                                    int* __restrict__ excl,  // = row_ptr
                                                    int* __restrict__ bsum) {
    __shared__ int s[256];
    int b = blockIdx.x, t = threadIdx.x, i = b * 256 + t;
    int v = (i < N_NODES) ? deg[i] : 0;
    s[t] = v;
    __syncthreads();
    for (int off = 1; off < 256; off <<= 1) {
        int y = (t >= off) ? s[t - off] : 0;
        __syncthreads();
        s[t] += y;
        __syncthreads();
    }
    if (i < N_NODES) excl[i] = s[t] - v;
    if (t == 255) bsum[b] = s[255];
}

__global__ void __launch_bounds__(256) scan2_kernel(const int* __restrict__ bsum,
                                                    int* __restrict__ boff,
                                                    int* __restrict__ row_ptr) {
    __shared__ int s[256];
    int t = threadIdx.x;
    int v = (t < 196) ? bsum[t] : 0;
    s[t] = v;
    __syncthreads();
    for (int off = 1; off < 256; off <<= 1) {
        int y = (t >= off) ? s[t - off] : 0;
        __syncthreads();
        s[t] += y;
        __syncthreads();
    }
    if (t < 196) boff[t] = s[t] - v;
    if (t == 255) row_ptr[N_NODES] = s[255];
}

__global__ void __launch_bounds__(256) scan3_kernel(const int* __restrict__ boff,
                                                    int* __restrict__ row_ptr,
                                                    int* __restrict__ cursor) {
    int i = blockIdx.x * 256 + threadIdx.x;
    if (i < N_NODES) {
        int v = row_ptr[i] + boff[blockIdx.x];
        row_ptr[i] = v;
        cursor[i] = v;
    }
}

__global__ void scatter_kernel(const unsigned* __restrict__ ew, const int* __restrict__ flag,
                               int* __restrict__ cursor, int* __restrict__ src_csr) {
    int e = blockIdx.x * blockDim.x + threadIdx.x;
    if (e >= N_EDGES) return;
    int is32 = *flag;
    int s = edge_elem(ew, is32, e);
    int d = edge_elem(ew, is32, (long long)N_EDGES + e);
    int pos = atomicAdd(&cursor[d], 1);
    src_csr[pos] = s;
}

// ---------------- f32 GEMM: Gbf[M,256](bf16) = A[M,K] @ B[K,256] ----------------
__global__ void __launch_bounds__(256) gemm_kernel(const float* __restrict__ A,
                                                   const float* __restrict__ B,
                                                   unsigned short* __restrict__ Gbf,
                                                   int M, int K) {
    __shared__ float Ast[16][64];  // [k][row]
    __shared__ float Bs[16][64];   // [k][col]
    int tid = threadIdx.x;
    int tx = tid & 15, ty = tid >> 4;
    int rb = blockIdx.x * 64, cb = blockIdx.y * 64;
    float acc[4][4] = {};
    int ar = tid >> 2;
    int ak = (tid & 3) * 4;
    int br = tid >> 4;
    int bc = (tid & 15) * 4;
    for (int k0 = 0; k0 < K; k0 += 16) {
        float4 av = make_float4(0.f, 0.f, 0.f, 0.f);
        int arow = rb + ar;
        if (arow < M) av = *(const float4*)&A[(long long)arow * K + k0 + ak];
        float4 bv = *(const float4*)&B[(long long)(k0 + br) * 256 + cb + bc];
        __syncthreads();
        Ast[ak + 0][ar] = av.x;
        Ast[ak + 1][ar] = av.y;
        Ast[ak + 2][ar] = av.z;
        Ast[ak + 3][ar] = av.w;
        *(float4*)&Bs[br][bc] = bv;
        __syncthreads();
#pragma unroll
        for (int kk = 0; kk < 16; ++kk) {
            float4 a4 = *(const float4*)&Ast[kk][ty * 4];
            float4 b4 = *(const float4*)&Bs[kk][tx * 4];
            acc[0][0] += a4.x * b4.x; acc[0][1] += a4.x * b4.y; acc[0][2] += a4.x * b4.z; acc[0][3] += a4.x * b4.w;
            acc[1][0] += a4.y * b4.x; acc[1][1] += a4.y * b4.y; acc[1][2] += a4.y * b4.z; acc[1][3] += a4.y * b4.w;
            acc[2][0] += a4.z * b4.x; acc[2][1] += a4.z * b4.y; acc[2][2] += a4.z * b4.z; acc[2][3] += a4.z * b4.w;
            acc[3][0] += a4.w * b4.x; acc[3][1] += a4.w * b4.y; acc[3][2] += a4.w * b4.z; acc[3][3] += a4.w * b4.w;
        }
    }
#pragma unroll
    for (int ii = 0; ii < 4; ++ii) {
        int r = rb + ty * 4 + ii;
        if (r < M) {
            ushort4 o;
            o.x = f2bf(acc[ii][0]);
            o.y = f2bf(acc[ii][1]);
            o.z = f2bf(acc[ii][2]);
            o.w = f2bf(acc[ii][3]);
            *(ushort4*)&Gbf[(long long)r * 256 + cb + tx * 4] = o;
        }
    }
}

// ---------------- per-node attention logits (reads bf16 h) ----------------
__global__ void __launch_bounds__(256) alphas_kernel(const unsigned short* __restrict__ g,
                                                     const float* __restrict__ a_src,
                                                     const float* __restrict__ a_dst,
                                                     float* __restrict__ alpha_s,
                                                     float* __restrict__ alpha_d) {
    int i = blockIdx.x;
    int t = threadIdx.x;  // t = hd*64 + c
    float v = bf2f(g[(long long)i * 256 + t]);
    float s = v * a_src[t];
    float d = v * a_dst[t];
#pragma unroll
    for (int off = 32; off; off >>= 1) {
        s += __shfl_down(s, off, 64);
        d += __shfl_down(d, off, 64);
    }
    int lane = t & 63, hd = t >> 6;
    if (lane == 0) {
        alpha_s[i * 4 + hd] = s;
        alpha_d[i * 4 + hd] = d;
    }
}

// ---------------- softmax-weighted aggregation (one wave per node) ----------------
template <int LAYER>
__global__ void __launch_bounds__(256) aggregate_kernel(
    const unsigned short* __restrict__ g, const float* __restrict__ alpha_s,
    const float* __restrict__ alpha_d, const int* __restrict__ row_ptr,
    const int* __restrict__ src_csr, const float* __restrict__ bias,
    float* __restrict__ out, const float* __restrict__ fc_w,
    const float* __restrict__ fc_b, float* __restrict__ final_out) {
    int wave = threadIdx.x >> 6;
    int lane = threadIdx.x & 63;
    int i = blockIdx.x * 4 + wave;
    int hd = lane >> 4;
    const ushort4* g4 = (const ushort4*)g;  // row stride 64 in ushort4 units

    float ad = alpha_d[i * 4 + hd];
    // self loop
    float e0 = alpha_s[i * 4 + hd] + ad;
    e0 = e0 > 0.f ? e0 : 0.2f * e0;
    float w0 = __expf(e0);
    ushort4 hv = g4[(long long)i * 64 + lane];
    float ax = w0 * bf2f(hv.x), ay = w0 * bf2f(hv.y);
    float az = w0 * bf2f(hv.z), aw = w0 * bf2f(hv.w);
    float wsum = w0;

    int p = row_ptr[i], p1 = row_ptr[i + 1];
    for (; p + 2 <= p1; p += 2) {
        int j0 = src_csr[p];
        int j1 = src_csr[p + 1];
        ushort4 h0 = g4[(long long)j0 * 64 + lane];
        ushort4 h1 = g4[(long long)j1 * 64 + lane];
        float eA = alpha_s[j0 * 4 + hd] + ad;
        float eB = alpha_s[j1 * 4 + hd] + ad;
        eA = eA > 0.f ? eA : 0.2f * eA;
        eB = eB > 0.f ? eB : 0.2f * eB;
        float wA = __expf(eA);
        float wB = __expf(eB);
        wsum += wA + wB;
        ax += wA * bf2f(h0.x) + wB * bf2f(h1.x);
        ay += wA * bf2f(h0.y) + wB * bf2f(h1.y);
        az += wA * bf2f(h0.z) + wB * bf2f(h1.z);
        aw += wA * bf2f(h0.w) + wB * bf2f(h1.w);
    }
    if (p < p1) {
        int j = src_csr[p];
        ushort4 hj = g4[(long long)j * 64 + lane];
        float e = alpha_s[j * 4 + hd] + ad;
        e = e > 0.f ? e : 0.2f * e;
        float wt = __expf(e);
        wsum += wt;
        ax += wt * bf2f(hj.x); ay += wt * bf2f(hj.y);
        az += wt * bf2f(hj.z); aw += wt * bf2f(hj.w);
    }
    float inv = 1.f / (wsum + 1e-16f);
    int c = lane * 4;
    float4 b4 = *(const float4*)&bias[c];
    float o0 = ax * inv + b4.x;
    float o1 = ay * inv + b4.y;
    float o2 = az * inv + b4.z;
    float o3 = aw * inv + b4.w;
    // ELU
    o0 = o0 > 0.f ? o0 : __expf(o0) - 1.f;
    o1 = o1 > 0.f ? o1 : __expf(o1) - 1.f;
    o2 = o2 > 0.f ? o2 : __expf(o2) - 1.f;
    o3 = o3 > 0.f ? o3 : __expf(o3) - 1.f;
    if (LAYER == 1) {
        float4 o = make_float4(o0, o1, o2, o3);
        ((float4*)out)[(long long)i * 64 + lane] = o;
    } else {
        float4 fw = *(const float4*)&fc_w[c];
        float dot = o0 * fw.x + o1 * fw.y + o2 * fw.z + o3 * fw.w;
#pragma unroll
        for (int off = 32; off; off >>= 1) dot += __shfl_down(dot, off, 64);
        if (lane == 0) final_out[i] = 1.f / (1.f + __expf(-(dot + fc_b[0])));
    }
}

// ---------------- launch ----------------
extern "C" void kernel_launch(void* const* d_in, const int* in_sizes, int n_in,
                              void* d_out, int out_size, void* d_ws, size_t ws_size,
                              hipStream_t stream) {
    const float* x   = (const float*)d_in[0];
    const unsigned* ei = (const unsigned*)d_in[1];
    const float* W1  = (const float*)d_in[2];
    const float* as1 = (const float*)d_in[3];
    const float* ad1 = (const float*)d_in[4];
    const float* b1  = (const float*)d_in[5];
    const float* W2  = (const float*)d_in[6];
    const float* as2 = (const float*)d_in[7];
    const float* ad2 = (const float*)d_in[8];
    const float* b2  = (const float*)d_in[9];
    const float* fcw = (const float*)d_in[10];
    const float* fcb = (const float*)d_in[11];

    char* ws = (char*)d_ws;
    unsigned short* gbf = (unsigned short*)(ws + 0);   // 50000*256 bf16 = 25.6 MB
    float* hact    = (float*)(ws + 25600000);          // 50000*256 f32 = 51.2 MB
    float* asv     = (float*)(ws + 76800000);          // 0.8 MB
    float* adv     = (float*)(ws + 77600000);          // 0.8 MB
    int* row_ptr   = (int*)(ws + 78400000);            // 50001 ints
    int* deg       = (int*)(ws + 78600016);            // 50000 ints
    int* cursor    = (int*)(ws + 78800016);            // 50000 ints
    int* src_csr   = (int*)(ws + 79000016);            // 800000 ints
    int* flag      = (int*)(ws + 82200016);            // 1 int
    int* bsum      = (int*)(ws + 82200032);            // 196 ints
    int* boff      = (int*)(ws + 82201056);            // 196 ints

    hipMemsetAsync(flag, 0, 4, stream);
    hipMemsetAsync(deg, 0, N_NODES * 4, stream);

    detect_kernel<<<4, 256, 0, stream>>>(ei, flag);
    hist_kernel<<<(N_EDGES + 255) / 256, 256, 0, stream>>>(ei, flag, deg);
    scan1_kernel<<<196, 256, 0, stream>>>(deg, row_ptr, bsum);
    scan2_kernel<<<1, 256, 0, stream>>>(bsum, boff, row_ptr);
    scan3_kernel<<<196, 256, 0, stream>>>(boff, row_ptr, cursor);
    scatter_kernel<<<(N_EDGES + 255) / 256, 256, 0, stream>>>(ei, flag, cursor, src_csr);

    // layer 1
    gemm_kernel<<<dim3((N_NODES + 63) / 64, 4), 256, 0, stream>>>(x, W1, gbf, N_NODES, 128);
    alphas_kernel<<<N_NODES, 256, 0, stream>>>(gbf, as1, ad1, asv, adv);
    aggregate_kernel<1><<<N_NODES / 4, 256, 0, stream>>>(gbf, asv, adv, row_ptr, src_csr, b1,
                                                         hact, nullptr, nullptr, nullptr);
    // layer 2
    gemm_kernel<<<dim3((N_NODES + 63) / 64, 4), 256, 0, stream>>>(hact, W2, gbf, N_NODES, 256);
    alphas_kernel<<<N_NODES, 256, 0, stream>>>(gbf, as2, ad2, asv, adv);
    aggregate_kernel<2><<<N_NODES / 4, 256, 0, stream>>>(gbf, asv, adv, row_ptr, src_csr, b2,
                                                         nullptr, fcw, fcb, (float*)d_out);
}

// Round 3
// 354.096 us; speedup vs baseline: 1.8539x; 1.3350x over previous
//
#include <hip/hip_runtime.h>
#include <hip/hip_bf16.h>

#define N_NODES 50000
#define N_EDGES 800000

typedef __attribute__((ext_vector_type(8))) short bf16x8;
typedef __attribute__((ext_vector_type(4))) float f32x4;
typedef unsigned short ushort_t;

__device__ __forceinline__ float bf2f(unsigned short u) {
    union { unsigned u32; float f; } v; v.u32 = (unsigned)u << 16; return v.f;
}
__device__ __forceinline__ unsigned short f2bf(float f) {
    __hip_bfloat16 h = __float2bfloat16(f);
    return *reinterpret_cast<unsigned short*>(&h);
}

__device__ __forceinline__ void gload16(const void* src, void* lds) {
    __builtin_amdgcn_global_load_lds(
        (const __attribute__((address_space(1))) unsigned int*)src,
        (__attribute__((address_space(3))) unsigned int*)lds, 16, 0, 0);
}

// ---------------- edge-index dtype detection (int64 vs int32) ----------------
__global__ void detect_kernel(const unsigned* __restrict__ w, int* __restrict__ flag) {
    int i = blockIdx.x * blockDim.x + threadIdx.x;
    if (i < 1024) {
        if (w[2 * i + 1] != 0u) atomicOr(flag, 1);  // flag=1 -> int32 layout
    }
}

__device__ __forceinline__ int edge_elem(const unsigned* __restrict__ w, int is32, long long idx) {
    return is32 ? (int)w[idx] : (int)w[2 * idx];
}

// ---------------- CSR build ----------------
__global__ void hist_kernel(const unsigned* __restrict__ ew, const int* __restrict__ flag,
                            int* __restrict__ deg) {
    int e = blockIdx.x * blockDim.x + threadIdx.x;
    if (e >= N_EDGES) return;
    int is32 = *flag;
    int d = edge_elem(ew, is32, (long long)N_EDGES + e);
    atomicAdd(&deg[d], 1);
}

__global__ void __launch_bounds__(256) scan1_kernel(const int* __restrict__ deg,
                                                    int* __restrict__ excl, int* __restrict__ bsum) {
    __shared__ int s[256];
    int b = blockIdx.x, t = threadIdx.x, i = b * 256 + t;
    int v = (i < N_NODES) ? deg[i] : 0;
    s[t] = v;
    __syncthreads();
    for (int off = 1; off < 256; off <<= 1) {
        int y = (t >= off) ? s[t - off] : 0;
        __syncthreads();
        s[t] += y;
        __syncthreads();
    }
    if (i < N_NODES) excl[i] = s[t] - v;
    if (t == 255) bsum[b] = s[255];
}

__global__ void __launch_bounds__(256) scan2_kernel(const int* __restrict__ bsum,
                                                    int* __restrict__ boff, int* __restrict__ row_ptr) {
    __shared__ int s[256];
    int t = threadIdx.x;
    int v = (t < 196) ? bsum[t] : 0;
    s[t] = v;
    __syncthreads();
    for (int off = 1; off < 256; off <<= 1) {
        int y = (t >= off) ? s[t - off] : 0;
        __syncthreads();
        s[t] += y;
        __syncthreads();
    }
    if (t < 196) boff[t] = s[t] - v;
    if (t == 255) row_ptr[N_NODES] = s[255];
}

__global__ void __launch_bounds__(256) scan3_kernel(const int* __restrict__ boff,
                                                    int* __restrict__ row_ptr, int* __restrict__ cursor) {
    int i = blockIdx.x * 256 + threadIdx.x;
    if (i < N_NODES) {
        int v = row_ptr[i] + boff[blockIdx.x];
        row_ptr[i] = v;
        cursor[i] = v;
    }
}

__global__ void scatter_kernel(const unsigned* __restrict__ ew, const int* __restrict__ flag,
                               int* __restrict__ cursor, int* __restrict__ src_csr) {
    int e = blockIdx.x * blockDim.x + threadIdx.x;
    if (e >= N_EDGES) return;
    int is32 = *flag;
    int s = edge_elem(ew, is32, e);
    int d = edge_elem(ew, is32, (long long)N_EDGES + e);
    int pos = atomicAdd(&cursor[d], 1);
    src_csr[pos] = s;
}

// ---------------- input conversions ----------------
__global__ void __launch_bounds__(256) convert_x_kernel(const float* __restrict__ x,
                                                        ushort_t* __restrict__ xbf, int n4) {
    int i = blockIdx.x * 256 + threadIdx.x;
    if (i >= n4) return;
    float4 v = ((const float4*)x)[i];
    ushort4 o;
    o.x = f2bf(v.x); o.y = f2bf(v.y); o.z = f2bf(v.z); o.w = f2bf(v.w);
    ((ushort4*)xbf)[i] = o;
}

// W [K][256] fp32 -> Wt [256][K] bf16
template <int K>
__global__ void __launch_bounds__(256) transpose_w_kernel(const float* __restrict__ W,
                                                          ushort_t* __restrict__ Wt) {
    int id = blockIdx.x * 256 + threadIdx.x;  // id = n*K + k
    if (id >= 256 * K) return;
    int n = id / K, k = id % K;
    Wt[id] = f2bf(W[k * 256 + n]);
}

// ---------------- MFMA bf16 GEMM: C[M,256](bf16) = A[M,K](bf16) @ Wt^T ----------------
// Wt is [256][K] bf16 (i.e., B[k][n] = Wt[n][k]). Tiles: BM=64, BN=64, BK=64.
// 4 waves in 2x2 grid; each wave does 32x32 via 2x2 of 16x16x32 MFMA fragments.
// LDS: B panel [64][K] (whole K, staged once), A double-buffered [2][64][64].
// 16B-chunk XOR swizzle (chunk ^= row&7) on both, applied via pre-swizzled
// global source for global_load_lds and matching XOR on ds_read addresses.
template <int K>
__global__ void __launch_bounds__(256) mfma_gemm_kernel(const ushort_t* __restrict__ A,
                                                        const ushort_t* __restrict__ Wt,
                                                        ushort_t* __restrict__ C, int M) {
    constexpr int CPR = K / 8;   // 16B chunks per B row
    constexpr int NT = K / 64;   // K-tiles
    __shared__ ushort_t Bs[64 * K];
    __shared__ ushort_t As[2][64 * 64];

    int tid = threadIdx.x;
    int wave = tid >> 6, lane = tid & 63;
    int l15 = lane & 15, l4 = lane >> 4;
    int wr = wave >> 1, wc = wave & 1;
    int colblock = blockIdx.x;           // 0..3 (head)
    int rowblock = blockIdx.y;

    // ---- stage B panel (64 cols x K) ----
    for (int base = 0; base < 64 * CPR; base += 256) {
        int p = base + wave * 64 + lane;            // chunk id, linear in LDS
        int row = p / CPR;
        int cs = p % CPR;
        int c = cs ^ (row & 7);
        const ushort_t* src = Wt + (long long)(colblock * 64 + row) * K + c * 8;
        void* dst = ((char*)Bs) + (base + wave * 64) * 16;  // wave-uniform base
        gload16(src, dst);
    }
    // ---- stage A tile 0 ----
    {
        int r = lane >> 3, cs = lane & 7;
        int c = cs ^ r;
#pragma unroll
        for (int q = 0; q < 2; ++q) {
            int lrow = wave * 16 + q * 8;
            int grow = rowblock * 64 + lrow + r;
            if (grow >= M) grow = M - 1;
            const ushort_t* src = A + (long long)grow * K + c * 8;
            void* dst = ((char*)&As[0][0]) + lrow * 128;
            gload16(src, dst);
        }
    }
    __syncthreads();

    f32x4 acc[2][2] = {};
#pragma unroll
    for (int t = 0; t < NT; ++t) {
        if (t + 1 < NT) {  // stage next A tile
            int r = lane >> 3, cs = lane & 7;
            int c = cs ^ r;
#pragma unroll
            for (int q = 0; q < 2; ++q) {
                int lrow = wave * 16 + q * 8;
                int grow = rowblock * 64 + lrow + r;
                if (grow >= M) grow = M - 1;
                const ushort_t* src = A + (long long)grow * K + (t + 1) * 64 + c * 8;
                void* dst = ((char*)&As[(t + 1) & 1][0]) + lrow * 128;
                gload16(src, dst);
            }
        }
        const ushort_t* At = &As[t & 1][0];
#pragma unroll
        for (int w = 0; w < 2; ++w) {  // 32-wide k window
            bf16x8 a[2], b[2];
#pragma unroll
            for (int mi = 0; mi < 2; ++mi) {
                int row = wr * 32 + mi * 16 + l15;
                int slot = (w * 4 + l4) ^ (l15 & 7);
                a[mi] = *(const bf16x8*)&At[row * 64 + slot * 8];
            }
#pragma unroll
            for (int ni = 0; ni < 2; ++ni) {
                int brow = wc * 32 + ni * 16 + l15;
                int slot = (t * 8 + w * 4 + l4) ^ (l15 & 7);
                b[ni] = *(const bf16x8*)&Bs[brow * CPR * 8 + slot * 8];
            }
#pragma unroll
            for (int mi = 0; mi < 2; ++mi)
#pragma unroll
                for (int ni = 0; ni < 2; ++ni)
                    acc[mi][ni] = __builtin_amdgcn_mfma_f32_16x16x32_bf16(a[mi], b[ni],
                                                                          acc[mi][ni], 0, 0, 0);
        }
        __syncthreads();
    }

    // ---- epilogue: repack via LDS (reuse A buffers), 32x40-ushort region per wave ----
    ushort_t* ep = ((ushort_t*)&As[0][0]) + wave * 1280;
#pragma unroll
    for (int mi = 0; mi < 2; ++mi)
#pragma unroll
        for (int ni = 0; ni < 2; ++ni)
#pragma unroll
            for (int q = 0; q < 4; ++q) {
                int row = mi * 16 + l4 * 4 + q;
                int col = ni * 16 + l15;
                ep[row * 40 + col] = f2bf(acc[mi][ni][q]);
            }
    __syncthreads();
#pragma unroll
    for (int j = 0; j < 2; ++j) {
        int p = lane * 2 + j;
        int row = p >> 2, seg = p & 3;
        uint4 v = *(const uint4*)&ep[row * 40 + seg * 8];
        int grow = rowblock * 64 + wr * 32 + row;
        int gcol = colblock * 64 + wc * 32 + seg * 8;
        if (grow < M) *(uint4*)&C[(long long)grow * 256 + gcol] = v;
    }
}

// ---------------- per-node attention logits (reads bf16 h) ----------------
__global__ void __launch_bounds__(256) alphas_kernel(const ushort_t* __restrict__ g,
                                                     const float* __restrict__ a_src,
                                                     const float* __restrict__ a_dst,
                                                     float* __restrict__ alpha_s,
                                                     float* __restrict__ alpha_d) {
    int i = blockIdx.x;
    int t = threadIdx.x;  // t = hd*64 + c
    float v = bf2f(g[(long long)i * 256 + t]);
    float s = v * a_src[t];
    float d = v * a_dst[t];
#pragma unroll
    for (int off = 32; off; off >>= 1) {
        s += __shfl_down(s, off, 64);
        d += __shfl_down(d, off, 64);
    }
    int lane = t & 63, hd = t >> 6;
    if (lane == 0) {
        alpha_s[i * 4 + hd] = s;
        alpha_d[i * 4 + hd] = d;
    }
}

// ---------------- softmax-weighted aggregation (one wave per node) ----------------
template <int LAYER>
__global__ void __launch_bounds__(256) aggregate_kernel(
    const ushort_t* __restrict__ g, const float* __restrict__ alpha_s,
    const float* __restrict__ alpha_d, const int* __restrict__ row_ptr,
    const int* __restrict__ src_csr, const float* __restrict__ bias,
    ushort_t* __restrict__ out_bf, const float* __restrict__ fc_w,
    const float* __restrict__ fc_b, float* __restrict__ final_out) {
    int wave = threadIdx.x >> 6;
    int lane = threadIdx.x & 63;
    int i = blockIdx.x * 4 + wave;
    int hd = lane >> 4;
    const ushort4* g4 = (const ushort4*)g;

    float ad = alpha_d[i * 4 + hd];
    float e0 = alpha_s[i * 4 + hd] + ad;
    e0 = e0 > 0.f ? e0 : 0.2f * e0;
    float w0 = __expf(e0);
    ushort4 hv = g4[(long long)i * 64 + lane];
    float ax = w0 * bf2f(hv.x), ay = w0 * bf2f(hv.y);
    float az = w0 * bf2f(hv.z), aw = w0 * bf2f(hv.w);
    float wsum = w0;

    int p = row_ptr[i], p1 = row_ptr[i + 1];
    for (; p + 2 <= p1; p += 2) {
        int j0 = src_csr[p];
        int j1 = src_csr[p + 1];
        ushort4 h0 = g4[(long long)j0 * 64 + lane];
        ushort4 h1 = g4[(long long)j1 * 64 + lane];
        float eA = alpha_s[j0 * 4 + hd] + ad;
        float eB = alpha_s[j1 * 4 + hd] + ad;
        eA = eA > 0.f ? eA : 0.2f * eA;
        eB = eB > 0.f ? eB : 0.2f * eB;
        float wA = __expf(eA);
        float wB = __expf(eB);
        wsum += wA + wB;
        ax += wA * bf2f(h0.x) + wB * bf2f(h1.x);
        ay += wA * bf2f(h0.y) + wB * bf2f(h1.y);
        az += wA * bf2f(h0.z) + wB * bf2f(h1.z);
        aw += wA * bf2f(h0.w) + wB * bf2f(h1.w);
    }
    if (p < p1) {
        int j = src_csr[p];
        ushort4 hj = g4[(long long)j * 64 + lane];
        float e = alpha_s[j * 4 + hd] + ad;
        e = e > 0.f ? e : 0.2f * e;
        float wt = __expf(e);
        wsum += wt;
        ax += wt * bf2f(hj.x); ay += wt * bf2f(hj.y);
        az += wt * bf2f(hj.z); aw += wt * bf2f(hj.w);
    }
    float inv = 1.f / (wsum + 1e-16f);
    int c = lane * 4;
    float4 b4 = *(const float4*)&bias[c];
    float o0 = ax * inv + b4.x;
    float o1 = ay * inv + b4.y;
    float o2 = az * inv + b4.z;
    float o3 = aw * inv + b4.w;
    o0 = o0 > 0.f ? o0 : __expf(o0) - 1.f;
    o1 = o1 > 0.f ? o1 : __expf(o1) - 1.f;
    o2 = o2 > 0.f ? o2 : __expf(o2) - 1.f;
    o3 = o3 > 0.f ? o3 : __expf(o3) - 1.f;
    if (LAYER == 1) {
        ushort4 o;
        o.x = f2bf(o0); o.y = f2bf(o1); o.z = f2bf(o2); o.w = f2bf(o3);
        ((ushort4*)out_bf)[(long long)i * 64 + lane] = o;
    } else {
        float4 fw = *(const float4*)&fc_w[c];
        float dot = o0 * fw.x + o1 * fw.y + o2 * fw.z + o3 * fw.w;
#pragma unroll
        for (int off = 32; off; off >>= 1) dot += __shfl_down(dot, off, 64);
        if (lane == 0) final_out[i] = 1.f / (1.f + __expf(-(dot + fc_b[0])));
    }
}

// ---------------- launch ----------------
extern "C" void kernel_launch(void* const* d_in, const int* in_sizes, int n_in,
                              void* d_out, int out_size, void* d_ws, size_t ws_size,
                              hipStream_t stream) {
    const float* x   = (const float*)d_in[0];
    const unsigned* ei = (const unsigned*)d_in[1];
    const float* W1  = (const float*)d_in[2];
    const float* as1 = (const float*)d_in[3];
    const float* ad1 = (const float*)d_in[4];
    const float* b1  = (const float*)d_in[5];
    const float* W2  = (const float*)d_in[6];
    const float* as2 = (const float*)d_in[7];
    const float* ad2 = (const float*)d_in[8];
    const float* b2  = (const float*)d_in[9];
    const float* fcw = (const float*)d_in[10];
    const float* fcb = (const float*)d_in[11];

    char* ws = (char*)d_ws;
    ushort_t* gbf    = (ushort_t*)(ws + 0);           // 50000*256 bf16 = 25.6 MB
    ushort_t* hactbf = (ushort_t*)(ws + 25600000);    // 25.6 MB
    ushort_t* xbf    = (ushort_t*)(ws + 51200000);    // 12.8 MB
    ushort_t* W1t    = (ushort_t*)(ws + 64000000);    // 64 KB
    ushort_t* W2t    = (ushort_t*)(ws + 64100000);    // 128 KB
    float* asv       = (float*)(ws + 64300000);       // 0.8 MB
    float* adv       = (float*)(ws + 65100000);       // 0.8 MB
    int* row_ptr     = (int*)(ws + 65900000);         // 50001 ints
    int* deg         = (int*)(ws + 66100016);         // 50000 ints
    int* cursor      = (int*)(ws + 66300016);         // 50000 ints
    int* src_csr     = (int*)(ws + 66500016);         // 800000 ints
    int* flag        = (int*)(ws + 69700016);         // 1 int
    int* bsum        = (int*)(ws + 69700032);         // 196 ints
    int* boff        = (int*)(ws + 69701056);         // 196 ints

    hipMemsetAsync(flag, 0, 4, stream);
    hipMemsetAsync(deg, 0, N_NODES * 4, stream);

    detect_kernel<<<4, 256, 0, stream>>>(ei, flag);
    hist_kernel<<<(N_EDGES + 255) / 256, 256, 0, stream>>>(ei, flag, deg);
    scan1_kernel<<<196, 256, 0, stream>>>(deg, row_ptr, bsum);
    scan2_kernel<<<1, 256, 0, stream>>>(bsum, boff, row_ptr);
    scan3_kernel<<<196, 256, 0, stream>>>(boff, row_ptr, cursor);
    scatter_kernel<<<(N_EDGES + 255) / 256, 256, 0, stream>>>(ei, flag, cursor, src_csr);

    convert_x_kernel<<<(N_NODES * 128 / 4 + 255) / 256, 256, 0, stream>>>(x, xbf, N_NODES * 128 / 4);
    transpose_w_kernel<128><<<(256 * 128 + 255) / 256, 256, 0, stream>>>(W1, W1t);
    transpose_w_kernel<256><<<(256 * 256 + 255) / 256, 256, 0, stream>>>(W2, W2t);

    // layer 1
    mfma_gemm_kernel<128><<<dim3(4, (N_NODES + 63) / 64), 256, 0, stream>>>(xbf, W1t, gbf, N_NODES);
    alphas_kernel<<<N_NODES, 256, 0, stream>>>(gbf, as1, ad1, asv, adv);
    aggregate_kernel<1><<<N_NODES / 4, 256, 0, stream>>>(gbf, asv, adv, row_ptr, src_csr, b1,
                                                         hactbf, nullptr, nullptr, nullptr);
    // layer 2
    mfma_gemm_kernel<256><<<dim3(4, (N_NODES + 63) / 64), 256, 0, stream>>>(hactbf, W2t, gbf, N_NODES);
    alphas_kernel<<<N_NODES, 256, 0, stream>>>(gbf, as2, ad2, asv, adv);
    aggregate_kernel<2><<<N_NODES / 4, 256, 0, stream>>>(gbf, asv, adv, row_ptr, src_csr, b2,
                                                         nullptr, fcw, fcb, (float*)d_out);
}

// Round 4
// 351.512 us; speedup vs baseline: 1.8676x; 1.0074x over previous
//
#include <hip/hip_runtime.h>
#include <hip/hip_bf16.h>

#define N_NODES 50000
#define N_EDGES 800000

typedef __attribute__((ext_vector_type(8))) short bf16x8;
typedef __attribute__((ext_vector_type(4))) float f32x4;
typedef __attribute__((ext_vector_type(2))) float f32x2;
typedef unsigned short ushort_t;

__device__ __forceinline__ float bf2f(unsigned short u) {
    union { unsigned u32; float f; } v; v.u32 = (unsigned)u << 16; return v.f;
}
__device__ __forceinline__ unsigned short f2bf(float f) {
    __hip_bfloat16 h = __float2bfloat16(f);
    return *reinterpret_cast<unsigned short*>(&h);
}
// unpack a u32 holding 2 bf16 (lo=ch c, hi=ch c+1) to 2 f32
__device__ __forceinline__ f32x2 bfpair(unsigned u) {
    union { unsigned a; float f; } lo, hi;
    lo.a = u << 16;
    hi.a = u & 0xFFFF0000u;
    f32x2 r; r.x = lo.f; r.y = hi.f; return r;
}
__device__ __forceinline__ void pkfma(f32x2& d, f32x2 a, f32x2 b) {
    asm("v_pk_fma_f32 %0, %1, %2, %0" : "+v"(d) : "v"(a), "v"(b));
}

__device__ __forceinline__ void gload16(const void* src, void* lds) {
    __builtin_amdgcn_global_load_lds(
        (const __attribute__((address_space(1))) unsigned int*)src,
        (__attribute__((address_space(3))) unsigned int*)lds, 16, 0, 0);
}

// ---------------- edge-index dtype detection (int64 vs int32) ----------------
__global__ void detect_kernel(const unsigned* __restrict__ w, int* __restrict__ flag) {
    int i = blockIdx.x * blockDim.x + threadIdx.x;
    if (i < 1024) {
        if (w[2 * i + 1] != 0u) atomicOr(flag, 1);  // flag=1 -> int32 layout
    }
}

__device__ __forceinline__ int edge_elem(const unsigned* __restrict__ w, int is32, long long idx) {
    return is32 ? (int)w[idx] : (int)w[2 * idx];
}

// ---------------- CSR build ----------------
__global__ void hist_kernel(const unsigned* __restrict__ ew, const int* __restrict__ flag,
                            int* __restrict__ deg) {
    int e = blockIdx.x * blockDim.x + threadIdx.x;
    if (e >= N_EDGES) return;
    int is32 = *flag;
    int d = edge_elem(ew, is32, (long long)N_EDGES + e);
    atomicAdd(&deg[d], 1);
}

__global__ void __launch_bounds__(256) scan1_kernel(const int* __restrict__ deg,
                                                    int* __restrict__ excl, int* __restrict__ bsum) {
    __shared__ int s[256];
    int b = blockIdx.x, t = threadIdx.x, i = b * 256 + t;
    int v = (i < N_NODES) ? deg[i] : 0;
    s[t] = v;
    __syncthreads();
    for (int off = 1; off < 256; off <<= 1) {
        int y = (t >= off) ? s[t - off] : 0;
        __syncthreads();
        s[t] += y;
        __syncthreads();
    }
    if (i < N_NODES) excl[i] = s[t] - v;
    if (t == 255) bsum[b] = s[255];
}

__global__ void __launch_bounds__(256) scan2_kernel(const int* __restrict__ bsum,
                                                    int* __restrict__ boff, int* __restrict__ row_ptr) {
    __shared__ int s[256];
    int t = threadIdx.x;
    int v = (t < 196) ? bsum[t] : 0;
    s[t] = v;
    __syncthreads();
    for (int off = 1; off < 256; off <<= 1) {
        int y = (t >= off) ? s[t - off] : 0;
        __syncthreads();
        s[t] += y;
        __syncthreads();
    }
    if (t < 196) boff[t] = s[t] - v;
    if (t == 255) row_ptr[N_NODES] = s[255];
}

__global__ void __launch_bounds__(256) scan3_kernel(const int* __restrict__ boff,
                                                    int* __restrict__ row_ptr, int* __restrict__ cursor) {
    int i = blockIdx.x * 256 + threadIdx.x;
    if (i < N_NODES) {
        int v = row_ptr[i] + boff[blockIdx.x];
        row_ptr[i] = v;
        cursor[i] = v;
    }
}

__global__ void scatter_kernel(const unsigned* __restrict__ ew, const int* __restrict__ flag,
                               int* __restrict__ cursor, int* __restrict__ src_csr,
                               int* __restrict__ dst_csr) {
    int e = blockIdx.x * blockDim.x + threadIdx.x;
    if (e >= N_EDGES) return;
    int is32 = *flag;
    int s = edge_elem(ew, is32, e);
    int d = edge_elem(ew, is32, (long long)N_EDGES + e);
    int pos = atomicAdd(&cursor[d], 1);
    src_csr[pos] = s;
    dst_csr[pos] = d;
}

// ---------------- input conversions ----------------
__global__ void __launch_bounds__(256) convert_x_kernel(const float* __restrict__ x,
                                                        ushort_t* __restrict__ xbf, int n4) {
    int i = blockIdx.x * 256 + threadIdx.x;
    if (i >= n4) return;
    float4 v = ((const float4*)x)[i];
    ushort4 o;
    o.x = f2bf(v.x); o.y = f2bf(v.y); o.z = f2bf(v.z); o.w = f2bf(v.w);
    ((ushort4*)xbf)[i] = o;
}

// W [K][256] fp32 -> Wt [256][K] bf16
template <int K>
__global__ void __launch_bounds__(256) transpose_w_kernel(const float* __restrict__ W,
                                                          ushort_t* __restrict__ Wt) {
    int id = blockIdx.x * 256 + threadIdx.x;  // id = n*K + k
    if (id >= 256 * K) return;
    int n = id / K, k = id % K;
    Wt[id] = f2bf(W[k * 256 + n]);
}

// ---------------- MFMA bf16 GEMM (BM=64,BN=64,BK=64, 2x2 waves) ----------------
template <int K>
__global__ void __launch_bounds__(256) mfma_gemm_kernel(const ushort_t* __restrict__ A,
                                                        const ushort_t* __restrict__ Wt,
                                                        ushort_t* __restrict__ C, int M) {
    constexpr int CPR = K / 8;
    constexpr int NT = K / 64;
    __shared__ ushort_t Bs[64 * K];
    __shared__ ushort_t As[2][64 * 64];

    int tid = threadIdx.x;
    int wave = tid >> 6, lane = tid & 63;
    int l15 = lane & 15, l4 = lane >> 4;
    int wr = wave >> 1, wc = wave & 1;
    int colblock = blockIdx.x;
    int rowblock = blockIdx.y;

    for (int base = 0; base < 64 * CPR; base += 256) {
        int p = base + wave * 64 + lane;
        int row = p / CPR;
        int cs = p % CPR;
        int c = cs ^ (row & 7);
        const ushort_t* src = Wt + (long long)(colblock * 64 + row) * K + c * 8;
        void* dst = ((char*)Bs) + (base + wave * 64) * 16;
        gload16(src, dst);
    }
    {
        int r = lane >> 3, cs = lane & 7;
        int c = cs ^ r;
#pragma unroll
        for (int q = 0; q < 2; ++q) {
            int lrow = wave * 16 + q * 8;
            int grow = rowblock * 64 + lrow + r;
            if (grow >= M) grow = M - 1;
            const ushort_t* src = A + (long long)grow * K + c * 8;
            void* dst = ((char*)&As[0][0]) + lrow * 128;
            gload16(src, dst);
        }
    }
    __syncthreads();

    f32x4 acc[2][2] = {};
#pragma unroll
    for (int t = 0; t < NT; ++t) {
        if (t + 1 < NT) {
            int r = lane >> 3, cs = lane & 7;
            int c = cs ^ r;
#pragma unroll
            for (int q = 0; q < 2; ++q) {
                int lrow = wave * 16 + q * 8;
                int grow = rowblock * 64 + lrow + r;
                if (grow >= M) grow = M - 1;
                const ushort_t* src = A + (long long)grow * K + (t + 1) * 64 + c * 8;
                void* dst = ((char*)&As[(t + 1) & 1][0]) + lrow * 128;
                gload16(src, dst);
            }
        }
        const ushort_t* At = &As[t & 1][0];
#pragma unroll
        for (int w = 0; w < 2; ++w) {
            bf16x8 a[2], b[2];
#pragma unroll
            for (int mi = 0; mi < 2; ++mi) {
                int row = wr * 32 + mi * 16 + l15;
                int slot = (w * 4 + l4) ^ (l15 & 7);
                a[mi] = *(const bf16x8*)&At[row * 64 + slot * 8];
            }
#pragma unroll
            for (int ni = 0; ni < 2; ++ni) {
                int brow = wc * 32 + ni * 16 + l15;
                int slot = (t * 8 + w * 4 + l4) ^ (l15 & 7);
                b[ni] = *(const bf16x8*)&Bs[brow * CPR * 8 + slot * 8];
            }
#pragma unroll
            for (int mi = 0; mi < 2; ++mi)
#pragma unroll
                for (int ni = 0; ni < 2; ++ni)
                    acc[mi][ni] = __builtin_amdgcn_mfma_f32_16x16x32_bf16(a[mi], b[ni],
                                                                          acc[mi][ni], 0, 0, 0);
        }
        __syncthreads();
    }

    ushort_t* ep = ((ushort_t*)&As[0][0]) + wave * 1280;
#pragma unroll
    for (int mi = 0; mi < 2; ++mi)
#pragma unroll
        for (int ni = 0; ni < 2; ++ni)
#pragma unroll
            for (int q = 0; q < 4; ++q) {
                int row = mi * 16 + l4 * 4 + q;
                int col = ni * 16 + l15;
                ep[row * 40 + col] = f2bf(acc[mi][ni][q]);
            }
    __syncthreads();
#pragma unroll
    for (int j = 0; j < 2; ++j) {
        int p = lane * 2 + j;
        int row = p >> 2, seg = p & 3;
        uint4 v = *(const uint4*)&ep[row * 40 + seg * 8];
        int grow = rowblock * 64 + wr * 32 + row;
        int gcol = colblock * 64 + wc * 32 + seg * 8;
        if (grow < M) *(uint4*)&C[(long long)grow * 256 + gcol] = v;
    }
}

// ---------------- per-node attention logits (reads bf16 h) ----------------
__global__ void __launch_bounds__(256) alphas_kernel(const ushort_t* __restrict__ g,
                                                     const float* __restrict__ a_src,
                                                     const float* __restrict__ a_dst,
                                                     float* __restrict__ alpha_s,
                                                     float* __restrict__ alpha_d) {
    int i = blockIdx.x;
    int t = threadIdx.x;
    float v = bf2f(g[(long long)i * 256 + t]);
    float s = v * a_src[t];
    float d = v * a_dst[t];
#pragma unroll
    for (int off = 32; off; off >>= 1) {
        s += __shfl_down(s, off, 64);
        d += __shfl_down(d, off, 64);
    }
    int lane = t & 63, hd = t >> 6;
    if (lane == 0) {
        alpha_s[i * 4 + hd] = s;
        alpha_d[i * 4 + hd] = d;
    }
}

// ---------------- per-edge softmax weights (all 4 heads) ----------------
__global__ void __launch_bounds__(256) weights_kernel(const float* __restrict__ alpha_s,
                                                      const float* __restrict__ alpha_d,
                                                      const int* __restrict__ src_csr,
                                                      const int* __restrict__ dst_csr,
                                                      float* __restrict__ w_csr) {
    int e = blockIdx.x * 256 + threadIdx.x;
    if (e >= N_EDGES) return;
    int j = src_csr[e], d = dst_csr[e];
    float4 a = *(const float4*)&alpha_s[j * 4];
    float4 b = *(const float4*)&alpha_d[d * 4];
    float4 o;
    float e0 = a.x + b.x; e0 = e0 > 0.f ? e0 : 0.2f * e0; o.x = __expf(e0);
    float e1 = a.y + b.y; e1 = e1 > 0.f ? e1 : 0.2f * e1; o.y = __expf(e1);
    float e2 = a.z + b.z; e2 = e2 > 0.f ? e2 : 0.2f * e2; o.z = __expf(e2);
    float e3 = a.w + b.w; e3 = e3 > 0.f ? e3 : 0.2f * e3; o.w = __expf(e3);
    *(float4*)&w_csr[e * 4] = o;
}

// ---------------- softmax-weighted aggregation (one wave per node) ----------------
template <int LAYER>
__global__ void __launch_bounds__(256) aggregate_kernel(
    const ushort_t* __restrict__ g, const float* __restrict__ alpha_s,
    const float* __restrict__ alpha_d, const int* __restrict__ row_ptr,
    const int* __restrict__ src_csr, const float* __restrict__ w_csr,
    const float* __restrict__ bias, ushort_t* __restrict__ out_bf,
    const float* __restrict__ fc_w, const float* __restrict__ fc_b,
    float* __restrict__ final_out) {
    int wave = threadIdx.x >> 6;
    int lane = threadIdx.x & 63;
    int i = blockIdx.x * 4 + wave;
    int hd = lane >> 4;
    const uint2* g2 = (const uint2*)g;  // row = 64 uint2 (4 bf16 each)

    // self loop
    float e0 = alpha_s[i * 4 + hd] + alpha_d[i * 4 + hd];
    e0 = e0 > 0.f ? e0 : 0.2f * e0;
    float w0 = __expf(e0);
    uint2 hv = g2[(long long)i * 64 + lane];
    f32x2 wp0; wp0.x = w0; wp0.y = w0;
    f32x2 acc01 = {0.f, 0.f}, acc23 = {0.f, 0.f};
    pkfma(acc01, wp0, bfpair(hv.x));
    pkfma(acc23, wp0, bfpair(hv.y));
    float wsum = w0;

    int p = row_ptr[i], p1 = row_ptr[i + 1];
    for (; p + 4 <= p1; p += 4) {
        int jA = src_csr[p + 0];
        int jB = src_csr[p + 1];
        int jC = src_csr[p + 2];
        int jD = src_csr[p + 3];
        float wA = w_csr[(p + 0) * 4 + hd];
        float wB = w_csr[(p + 1) * 4 + hd];
        float wC = w_csr[(p + 2) * 4 + hd];
        float wD = w_csr[(p + 3) * 4 + hd];
        uint2 hA = g2[(long long)jA * 64 + lane];
        uint2 hB = g2[(long long)jB * 64 + lane];
        uint2 hC = g2[(long long)jC * 64 + lane];
        uint2 hD = g2[(long long)jD * 64 + lane];
        wsum += wA + wB + wC + wD;
        f32x2 wpA; wpA.x = wA; wpA.y = wA;
        f32x2 wpB; wpB.x = wB; wpB.y = wB;
        f32x2 wpC; wpC.x = wC; wpC.y = wC;
        f32x2 wpD; wpD.x = wD; wpD.y = wD;
        pkfma(acc01, wpA, bfpair(hA.x)); pkfma(acc23, wpA, bfpair(hA.y));
        pkfma(acc01, wpB, bfpair(hB.x)); pkfma(acc23, wpB, bfpair(hB.y));
        pkfma(acc01, wpC, bfpair(hC.x)); pkfma(acc23, wpC, bfpair(hC.y));
        pkfma(acc01, wpD, bfpair(hD.x)); pkfma(acc23, wpD, bfpair(hD.y));
    }
    for (; p < p1; ++p) {
        int j = src_csr[p];
        float wt = w_csr[p * 4 + hd];
        uint2 hj = g2[(long long)j * 64 + lane];
        wsum += wt;
        f32x2 wp; wp.x = wt; wp.y = wt;
        pkfma(acc01, wp, bfpair(hj.x));
        pkfma(acc23, wp, bfpair(hj.y));
    }
    float inv = 1.f / (wsum + 1e-16f);
    int c = lane * 4;
    float4 b4 = *(const float4*)&bias[c];
    float o0 = acc01.x * inv + b4.x;
    float o1 = acc01.y * inv + b4.y;
    float o2 = acc23.x * inv + b4.z;
    float o3 = acc23.y * inv + b4.w;
    o0 = o0 > 0.f ? o0 : __expf(o0) - 1.f;
    o1 = o1 > 0.f ? o1 : __expf(o1) - 1.f;
    o2 = o2 > 0.f ? o2 : __expf(o2) - 1.f;
    o3 = o3 > 0.f ? o3 : __expf(o3) - 1.f;
    if (LAYER == 1) {
        ushort4 o;
        o.x = f2bf(o0); o.y = f2bf(o1); o.z = f2bf(o2); o.w = f2bf(o3);
        ((ushort4*)out_bf)[(long long)i * 64 + lane] = o;
    } else {
        float4 fw = *(const float4*)&fc_w[c];
        float dot = o0 * fw.x + o1 * fw.y + o2 * fw.z + o3 * fw.w;
#pragma unroll
        for (int off = 32; off; off >>= 1) dot += __shfl_down(dot, off, 64);
        if (lane == 0) final_out[i] = 1.f / (1.f + __expf(-(dot + fc_b[0])));
    }
}

// ---------------- launch ----------------
extern "C" void kernel_launch(void* const* d_in, const int* in_sizes, int n_in,
                              void* d_out, int out_size, void* d_ws, size_t ws_size,
                              hipStream_t stream) {
    const float* x   = (const float*)d_in[0];
    const unsigned* ei = (const unsigned*)d_in[1];
    const float* W1  = (const float*)d_in[2];
    const float* as1 = (const float*)d_in[3];
    const float* ad1 = (const float*)d_in[4];
    const float* b1  = (const float*)d_in[5];
    const float* W2  = (const float*)d_in[6];
    const float* as2 = (const float*)d_in[7];
    const float* ad2 = (const float*)d_in[8];
    const float* b2  = (const float*)d_in[9];
    const float* fcw = (const float*)d_in[10];
    const float* fcb = (const float*)d_in[11];

    char* ws = (char*)d_ws;
    ushort_t* gbf    = (ushort_t*)(ws + 0);           // 25.6 MB
    ushort_t* hactbf = (ushort_t*)(ws + 25600000);    // 25.6 MB
    ushort_t* xbf    = (ushort_t*)(ws + 51200000);    // 12.8 MB
    ushort_t* W1t    = (ushort_t*)(ws + 64000000);
    ushort_t* W2t    = (ushort_t*)(ws + 64100000);
    float* asv       = (float*)(ws + 64300000);
    float* adv       = (float*)(ws + 65100000);
    int* row_ptr     = (int*)(ws + 65900000);
    int* deg         = (int*)(ws + 66100016);
    int* cursor      = (int*)(ws + 66300016);
    int* src_csr     = (int*)(ws + 66500016);
    int* dst_csr     = (int*)(ws + 69700016);
    float* w_csr     = (float*)(ws + 72900032);       // 12.8 MB
    int* flag        = (int*)(ws + 85700032);
    int* bsum        = (int*)(ws + 85700048);
    int* boff        = (int*)(ws + 85701072);

    hipMemsetAsync(flag, 0, 4, stream);
    hipMemsetAsync(deg, 0, N_NODES * 4, stream);

    detect_kernel<<<4, 256, 0, stream>>>(ei, flag);
    hist_kernel<<<(N_EDGES + 255) / 256, 256, 0, stream>>>(ei, flag, deg);
    scan1_kernel<<<196, 256, 0, stream>>>(deg, row_ptr, bsum);
    scan2_kernel<<<1, 256, 0, stream>>>(bsum, boff, row_ptr);
    scan3_kernel<<<196, 256, 0, stream>>>(boff, row_ptr, cursor);
    scatter_kernel<<<(N_EDGES + 255) / 256, 256, 0, stream>>>(ei, flag, cursor, src_csr, dst_csr);

    convert_x_kernel<<<(N_NODES * 128 / 4 + 255) / 256, 256, 0, stream>>>(x, xbf, N_NODES * 128 / 4);
    transpose_w_kernel<128><<<(256 * 128 + 255) / 256, 256, 0, stream>>>(W1, W1t);
    transpose_w_kernel<256><<<(256 * 256 + 255) / 256, 256, 0, stream>>>(W2, W2t);

    // layer 1
    mfma_gemm_kernel<128><<<dim3(4, (N_NODES + 63) / 64), 256, 0, stream>>>(xbf, W1t, gbf, N_NODES);
    alphas_kernel<<<N_NODES, 256, 0, stream>>>(gbf, as1, ad1, asv, adv);
    weights_kernel<<<(N_EDGES + 255) / 256, 256, 0, stream>>>(asv, adv, src_csr, dst_csr, w_csr);
    aggregate_kernel<1><<<N_NODES / 4, 256, 0, stream>>>(gbf, asv, adv, row_ptr, src_csr, w_csr,
                                                         b1, hactbf, nullptr, nullptr, nullptr);
    // layer 2
    mfma_gemm_kernel<256><<<dim3(4, (N_NODES + 63) / 64), 256, 0, stream>>>(hactbf, W2t, gbf, N_NODES);
    alphas_kernel<<<N_NODES, 256, 0, stream>>>(gbf, as2, ad2, asv, adv);
    weights_kernel<<<(N_EDGES + 255) / 256, 256, 0, stream>>>(asv, adv, src_csr, dst_csr, w_csr);
    aggregate_kernel<2><<<N_NODES / 4, 256, 0, stream>>>(gbf, asv, adv, row_ptr, src_csr, w_csr,
                                                         b2, nullptr, fcw, fcb, (float*)d_out);
}

// Round 5
// 308.536 us; speedup vs baseline: 2.1277x; 1.1393x over previous
//
#include <hip/hip_runtime.h>
#include <hip/hip_bf16.h>

#define N_NODES 50000
#define N_EDGES 800000

typedef __attribute__((ext_vector_type(8))) short bf16x8;
typedef __attribute__((ext_vector_type(4))) float f32x4;
typedef __attribute__((ext_vector_type(2))) float f32x2;
typedef unsigned short ushort_t;

__device__ __forceinline__ float bf2f(unsigned short u) {
    union { unsigned u32; float f; } v; v.u32 = (unsigned)u << 16; return v.f;
}
__device__ __forceinline__ unsigned short f2bf(float f) {
    __hip_bfloat16 h = __float2bfloat16(f);
    return *reinterpret_cast<unsigned short*>(&h);
}
__device__ __forceinline__ f32x2 bfpair(unsigned u) {
    union { unsigned a; float f; } lo, hi;
    lo.a = u << 16;
    hi.a = u & 0xFFFF0000u;
    f32x2 r; r.x = lo.f; r.y = hi.f; return r;
}
__device__ __forceinline__ void pkfma(f32x2& d, f32x2 a, f32x2 b) {
    asm("v_pk_fma_f32 %0, %1, %2, %0" : "+v"(d) : "v"(a), "v"(b));
}
__device__ __forceinline__ void gload16(const void* src, void* lds) {
    __builtin_amdgcn_global_load_lds(
        (const __attribute__((address_space(1))) unsigned int*)src,
        (__attribute__((address_space(3))) unsigned int*)lds, 16, 0, 0);
}

// inline int64-vs-int32 layout detection (odd 32-bit words all zero -> int64)
__device__ __forceinline__ int detect_is32_block(const unsigned* __restrict__ w,
                                                 int* s_is32, int tid) {
    if (tid == 0) {
        unsigned o = 0;
#pragma unroll
        for (int k = 1; k < 32; k += 2) o |= w[k];
        *s_is32 = (o != 0u);
    }
    __syncthreads();
    return *s_is32;
}

__device__ __forceinline__ int edge_elem(const unsigned* __restrict__ w, int is32, long long idx) {
    return is32 ? (int)w[idx] : (int)w[2 * idx];
}

// ---------------- CSR build ----------------
__global__ void __launch_bounds__(256) hist_kernel(const unsigned* __restrict__ ew,
                                                   int* __restrict__ deg) {
    __shared__ int s_is32;
    int is32 = detect_is32_block(ew, &s_is32, threadIdx.x);
    int e = blockIdx.x * 256 + threadIdx.x;
    if (e >= N_EDGES) return;
    int d = edge_elem(ew, is32, (long long)N_EDGES + e);
    atomicAdd(&deg[d], 1);
}

__global__ void __launch_bounds__(256) scan1_kernel(const int* __restrict__ deg,
                                                    int* __restrict__ excl, int* __restrict__ bsum) {
    __shared__ int s[256];
    int b = blockIdx.x, t = threadIdx.x, i = b * 256 + t;
    int v = (i < N_NODES) ? deg[i] : 0;
    s[t] = v;
    __syncthreads();
    for (int off = 1; off < 256; off <<= 1) {
        int y = (t >= off) ? s[t - off] : 0;
        __syncthreads();
        s[t] += y;
        __syncthreads();
    }
    if (i < N_NODES) excl[i] = s[t] - v;
    if (t == 255) bsum[b] = s[255];
}

__global__ void __launch_bounds__(256) scan2_kernel(const int* __restrict__ bsum,
                                                    int* __restrict__ boff, int* __restrict__ row_ptr) {
    __shared__ int s[256];
    int t = threadIdx.x;
    int v = (t < 196) ? bsum[t] : 0;
    s[t] = v;
    __syncthreads();
    for (int off = 1; off < 256; off <<= 1) {
        int y = (t >= off) ? s[t - off] : 0;
        __syncthreads();
        s[t] += y;
        __syncthreads();
    }
    if (t < 196) boff[t] = s[t] - v;
    if (t == 255) row_ptr[N_NODES] = s[255];
}

__global__ void __launch_bounds__(256) scan3_kernel(const int* __restrict__ boff,
                                                    int* __restrict__ row_ptr, int* __restrict__ cursor) {
    int i = blockIdx.x * 256 + threadIdx.x;
    if (i < N_NODES) {
        int v = row_ptr[i] + boff[blockIdx.x];
        row_ptr[i] = v;
        cursor[i] = v;
    }
}

__global__ void __launch_bounds__(256) scatter_kernel(const unsigned* __restrict__ ew,
                                                      int* __restrict__ cursor,
                                                      int* __restrict__ src_csr,
                                                      int* __restrict__ dst_csr) {
    __shared__ int s_is32;
    int is32 = detect_is32_block(ew, &s_is32, threadIdx.x);
    int e = blockIdx.x * 256 + threadIdx.x;
    if (e >= N_EDGES) return;
    int s = edge_elem(ew, is32, e);
    int d = edge_elem(ew, is32, (long long)N_EDGES + e);
    int pos = atomicAdd(&cursor[d], 1);
    src_csr[pos] = s;
    dst_csr[pos] = d;
}

// ---------------- fused prep: x->bf16, W1^T->bf16, W2^T->bf16 ----------------
#define CONV_BLOCKS 6250   /* 50000*128/4 / 256 */
__global__ void __launch_bounds__(256) prep_kernel(const float* __restrict__ x,
                                                   ushort_t* __restrict__ xbf,
                                                   const float* __restrict__ W1,
                                                   ushort_t* __restrict__ W1t,
                                                   const float* __restrict__ W2,
                                                   ushort_t* __restrict__ W2t) {
    int b = blockIdx.x, t = threadIdx.x;
    if (b < CONV_BLOCKS) {
        int i = b * 256 + t;
        float4 v = ((const float4*)x)[i];
        ushort4 o;
        o.x = f2bf(v.x); o.y = f2bf(v.y); o.z = f2bf(v.z); o.w = f2bf(v.w);
        ((ushort4*)xbf)[i] = o;
    } else if (b < CONV_BLOCKS + 128) {
        int id = (b - CONV_BLOCKS) * 256 + t;       // id = n*128 + k
        int n = id >> 7, k = id & 127;
        W1t[id] = f2bf(W1[k * 256 + n]);
    } else {
        int id = (b - CONV_BLOCKS - 128) * 256 + t; // id = n*256 + k
        int n = id >> 8, k = id & 255;
        W2t[id] = f2bf(W2[k * 256 + n]);
    }
}

// ---------------- MFMA bf16 GEMM + fused alpha logits ----------------
// C[M,256](bf16) = A[M,K](bf16) @ Wt^T ; colblock == head; epilogue also
// computes alpha_s/alpha_d for this head's 64 channels.
template <int K>
__global__ void __launch_bounds__(256) mfma_gemm_kernel(const ushort_t* __restrict__ A,
                                                        const ushort_t* __restrict__ Wt,
                                                        ushort_t* __restrict__ C, int M,
                                                        const float* __restrict__ a_src,
                                                        const float* __restrict__ a_dst,
                                                        float* __restrict__ alpha_s,
                                                        float* __restrict__ alpha_d) {
    constexpr int CPR = K / 8;
    constexpr int NT = K / 64;
    __shared__ ushort_t Bs[64 * K];
    __shared__ ushort_t As[2][64 * 64];
    __shared__ float ps[64][2], pd[64][2];

    int tid = threadIdx.x;
    int wave = tid >> 6, lane = tid & 63;
    int l15 = lane & 15, l4 = lane >> 4;
    int wr = wave >> 1, wc = wave & 1;
    int colblock = blockIdx.x;   // head
    int rowblock = blockIdx.y;

    for (int base = 0; base < 64 * CPR; base += 256) {
        int p = base + wave * 64 + lane;
        int row = p / CPR;
        int cs = p % CPR;
        int c = cs ^ (row & 7);
        const ushort_t* src = Wt + (long long)(colblock * 64 + row) * K + c * 8;
        void* dst = ((char*)Bs) + (base + wave * 64) * 16;
        gload16(src, dst);
    }
    {
        int r = lane >> 3, cs = lane & 7;
        int c = cs ^ r;
#pragma unroll
        for (int q = 0; q < 2; ++q) {
            int lrow = wave * 16 + q * 8;
            int grow = rowblock * 64 + lrow + r;
            if (grow >= M) grow = M - 1;
            const ushort_t* src = A + (long long)grow * K + c * 8;
            void* dst = ((char*)&As[0][0]) + lrow * 128;
            gload16(src, dst);
        }
    }
    __syncthreads();

    f32x4 acc[2][2] = {};
#pragma unroll
    for (int t = 0; t < NT; ++t) {
        if (t + 1 < NT) {
            int r = lane >> 3, cs = lane & 7;
            int c = cs ^ r;
#pragma unroll
            for (int q = 0; q < 2; ++q) {
                int lrow = wave * 16 + q * 8;
                int grow = rowblock * 64 + lrow + r;
                if (grow >= M) grow = M - 1;
                const ushort_t* src = A + (long long)grow * K + (t + 1) * 64 + c * 8;
                void* dst = ((char*)&As[(t + 1) & 1][0]) + lrow * 128;
                gload16(src, dst);
            }
        }
        const ushort_t* At = &As[t & 1][0];
#pragma unroll
        for (int w = 0; w < 2; ++w) {
            bf16x8 a[2], b[2];
#pragma unroll
            for (int mi = 0; mi < 2; ++mi) {
                int row = wr * 32 + mi * 16 + l15;
                int slot = (w * 4 + l4) ^ (l15 & 7);
                a[mi] = *(const bf16x8*)&At[row * 64 + slot * 8];
            }
#pragma unroll
            for (int ni = 0; ni < 2; ++ni) {
                int brow = wc * 32 + ni * 16 + l15;
                int slot = (t * 8 + w * 4 + l4) ^ (l15 & 7);
                b[ni] = *(const bf16x8*)&Bs[brow * CPR * 8 + slot * 8];
            }
#pragma unroll
            for (int mi = 0; mi < 2; ++mi)
#pragma unroll
                for (int ni = 0; ni < 2; ++ni)
                    acc[mi][ni] = __builtin_amdgcn_mfma_f32_16x16x32_bf16(a[mi], b[ni],
                                                                          acc[mi][ni], 0, 0, 0);
        }
        __syncthreads();
    }

    // ---- fused alpha partials: per-row dot with a_src/a_dst (this head) ----
    {
        float as0 = a_src[colblock * 64 + wc * 32 + l15];
        float as1 = a_src[colblock * 64 + wc * 32 + 16 + l15];
        float ad0 = a_dst[colblock * 64 + wc * 32 + l15];
        float ad1 = a_dst[colblock * 64 + wc * 32 + 16 + l15];
#pragma unroll
        for (int mi = 0; mi < 2; ++mi)
#pragma unroll
            for (int q = 0; q < 4; ++q) {
                float sv = acc[mi][0][q] * as0 + acc[mi][1][q] * as1;
                float dv = acc[mi][0][q] * ad0 + acc[mi][1][q] * ad1;
#pragma unroll
                for (int w = 1; w < 16; w <<= 1) {
                    sv += __shfl_xor(sv, w, 64);
                    dv += __shfl_xor(dv, w, 64);
                }
                if (l15 == 0) {
                    int row = wr * 32 + mi * 16 + l4 * 4 + q;
                    ps[row][wc] = sv;
                    pd[row][wc] = dv;
                }
            }
    }

    // ---- epilogue: repack C via LDS ----
    ushort_t* ep = ((ushort_t*)&As[0][0]) + wave * 1280;
#pragma unroll
    for (int mi = 0; mi < 2; ++mi)
#pragma unroll
        for (int ni = 0; ni < 2; ++ni)
#pragma unroll
            for (int q = 0; q < 4; ++q) {
                int row = mi * 16 + l4 * 4 + q;
                int col = ni * 16 + l15;
                ep[row * 40 + col] = f2bf(acc[mi][ni][q]);
            }
    __syncthreads();
#pragma unroll
    for (int j = 0; j < 2; ++j) {
        int p = lane * 2 + j;
        int row = p >> 2, seg = p & 3;
        uint4 v = *(const uint4*)&ep[row * 40 + seg * 8];
        int grow = rowblock * 64 + wr * 32 + row;
        int gcol = colblock * 64 + wc * 32 + seg * 8;
        if (grow < M) *(uint4*)&C[(long long)grow * 256 + gcol] = v;
    }
    if (tid < 64) {
        int ga = rowblock * 64 + tid;
        if (ga < M) {
            alpha_s[ga * 4 + colblock] = ps[tid][0] + ps[tid][1];
            alpha_d[ga * 4 + colblock] = pd[tid][0] + pd[tid][1];
        }
    }
}

// ---------------- per-edge softmax weights (all 4 heads) ----------------
__global__ void __launch_bounds__(256) weights_kernel(const float* __restrict__ alpha_s,
                                                      const float* __restrict__ alpha_d,
                                                      const int* __restrict__ src_csr,
                                                      const int* __restrict__ dst_csr,
                                                      float* __restrict__ w_csr) {
    int e = blockIdx.x * 256 + threadIdx.x;
    if (e >= N_EDGES) return;
    int j = src_csr[e], d = dst_csr[e];
    float4 a = *(const float4*)&alpha_s[j * 4];
    float4 b = *(const float4*)&alpha_d[d * 4];
    float4 o;
    float e0 = a.x + b.x; e0 = e0 > 0.f ? e0 : 0.2f * e0; o.x = __expf(e0);
    float e1 = a.y + b.y; e1 = e1 > 0.f ? e1 : 0.2f * e1; o.y = __expf(e1);
    float e2 = a.z + b.z; e2 = e2 > 0.f ? e2 : 0.2f * e2; o.z = __expf(e2);
    float e3 = a.w + b.w; e3 = e3 > 0.f ? e3 : 0.2f * e3; o.w = __expf(e3);
    *(float4*)&w_csr[e * 4] = o;
}

// ---------------- softmax-weighted aggregation (one wave per node) ----------------
template <int LAYER>
__global__ void __launch_bounds__(256) aggregate_kernel(
    const ushort_t* __restrict__ g, const float* __restrict__ alpha_s,
    const float* __restrict__ alpha_d, const int* __restrict__ row_ptr,
    const int* __restrict__ src_csr, const float* __restrict__ w_csr,
    const float* __restrict__ bias, ushort_t* __restrict__ out_bf,
    const float* __restrict__ fc_w, const float* __restrict__ fc_b,
    float* __restrict__ final_out) {
    int wave = threadIdx.x >> 6;
    int lane = threadIdx.x & 63;
    int i = blockIdx.x * 4 + wave;
    int hd = lane >> 4;
    const uint2* g2 = (const uint2*)g;

    // self loop
    float e0 = alpha_s[i * 4 + hd] + alpha_d[i * 4 + hd];
    e0 = e0 > 0.f ? e0 : 0.2f * e0;
    float w0 = __expf(e0);
    uint2 hv = g2[(long long)i * 64 + lane];
    f32x2 wp0; wp0.x = w0; wp0.y = w0;
    f32x2 acc01 = {0.f, 0.f}, acc23 = {0.f, 0.f};
    pkfma(acc01, wp0, bfpair(hv.x));
    pkfma(acc23, wp0, bfpair(hv.y));
    float wsum = w0;

    int p = row_ptr[i], p1 = row_ptr[i + 1];
    for (; p + 8 <= p1; p += 8) {
        int j[8]; float wt[8]; uint2 hh[8];
#pragma unroll
        for (int u = 0; u < 8; ++u) j[u] = src_csr[p + u];
#pragma unroll
        for (int u = 0; u < 8; ++u) wt[u] = w_csr[(p + u) * 4 + hd];
#pragma unroll
        for (int u = 0; u < 8; ++u) hh[u] = g2[(long long)j[u] * 64 + lane];
#pragma unroll
        for (int u = 0; u < 8; ++u) {
            wsum += wt[u];
            f32x2 wp; wp.x = wt[u]; wp.y = wt[u];
            pkfma(acc01, wp, bfpair(hh[u].x));
            pkfma(acc23, wp, bfpair(hh[u].y));
        }
    }
    for (; p + 4 <= p1; p += 4) {
        int j[4]; float wt[4]; uint2 hh[4];
#pragma unroll
        for (int u = 0; u < 4; ++u) j[u] = src_csr[p + u];
#pragma unroll
        for (int u = 0; u < 4; ++u) wt[u] = w_csr[(p + u) * 4 + hd];
#pragma unroll
        for (int u = 0; u < 4; ++u) hh[u] = g2[(long long)j[u] * 64 + lane];
#pragma unroll
        for (int u = 0; u < 4; ++u) {
            wsum += wt[u];
            f32x2 wp; wp.x = wt[u]; wp.y = wt[u];
            pkfma(acc01, wp, bfpair(hh[u].x));
            pkfma(acc23, wp, bfpair(hh[u].y));
        }
    }
    for (; p < p1; ++p) {
        int j = src_csr[p];
        float wt = w_csr[p * 4 + hd];
        uint2 hj = g2[(long long)j * 64 + lane];
        wsum += wt;
        f32x2 wp; wp.x = wt; wp.y = wt;
        pkfma(acc01, wp, bfpair(hj.x));
        pkfma(acc23, wp, bfpair(hj.y));
    }
    float inv = 1.f / (wsum + 1e-16f);
    int c = lane * 4;
    float4 b4 = *(const float4*)&bias[c];
    float o0 = acc01.x * inv + b4.x;
    float o1 = acc01.y * inv + b4.y;
    float o2 = acc23.x * inv + b4.z;
    float o3 = acc23.y * inv + b4.w;
    o0 = o0 > 0.f ? o0 : __expf(o0) - 1.f;
    o1 = o1 > 0.f ? o1 : __expf(o1) - 1.f;
    o2 = o2 > 0.f ? o2 : __expf(o2) - 1.f;
    o3 = o3 > 0.f ? o3 : __expf(o3) - 1.f;
    if (LAYER == 1) {
        ushort4 o;
        o.x = f2bf(o0); o.y = f2bf(o1); o.z = f2bf(o2); o.w = f2bf(o3);
        ((ushort4*)out_bf)[(long long)i * 64 + lane] = o;
    } else {
        float4 fw = *(const float4*)&fc_w[c];
        float dot = o0 * fw.x + o1 * fw.y + o2 * fw.z + o3 * fw.w;
#pragma unroll
        for (int off = 32; off; off >>= 1) dot += __shfl_down(dot, off, 64);
        if (lane == 0) final_out[i] = 1.f / (1.f + __expf(-(dot + fc_b[0])));
    }
}

// ---------------- launch ----------------
extern "C" void kernel_launch(void* const* d_in, const int* in_sizes, int n_in,
                              void* d_out, int out_size, void* d_ws, size_t ws_size,
                              hipStream_t stream) {
    const float* x   = (const float*)d_in[0];
    const unsigned* ei = (const unsigned*)d_in[1];
    const float* W1  = (const float*)d_in[2];
    const float* as1 = (const float*)d_in[3];
    const float* ad1 = (const float*)d_in[4];
    const float* b1  = (const float*)d_in[5];
    const float* W2  = (const float*)d_in[6];
    const float* as2 = (const float*)d_in[7];
    const float* ad2 = (const float*)d_in[8];
    const float* b2  = (const float*)d_in[9];
    const float* fcw = (const float*)d_in[10];
    const float* fcb = (const float*)d_in[11];

    char* ws = (char*)d_ws;
    ushort_t* gbf    = (ushort_t*)(ws + 0);           // 25.6 MB
    ushort_t* hactbf = (ushort_t*)(ws + 25600000);    // 12.8 MB used
    ushort_t* xbf    = (ushort_t*)(ws + 51200000);    // 12.8 MB
    ushort_t* W1t    = (ushort_t*)(ws + 64000000);
    ushort_t* W2t    = (ushort_t*)(ws + 64100000);
    float* asv       = (float*)(ws + 64300000);
    float* adv       = (float*)(ws + 65100000);
    int* row_ptr     = (int*)(ws + 65900000);
    int* deg         = (int*)(ws + 66100016);
    int* cursor      = (int*)(ws + 66300016);
    int* src_csr     = (int*)(ws + 66500016);
    int* dst_csr     = (int*)(ws + 69700016);
    float* w_csr     = (float*)(ws + 72900032);       // 12.8 MB
    int* bsum        = (int*)(ws + 85700048);
    int* boff        = (int*)(ws + 85701072);

    hipMemsetAsync(deg, 0, N_NODES * 4, stream);

    prep_kernel<<<CONV_BLOCKS + 128 + 256, 256, 0, stream>>>(x, xbf, W1, W1t, W2, W2t);
    hist_kernel<<<(N_EDGES + 255) / 256, 256, 0, stream>>>(ei, deg);
    scan1_kernel<<<196, 256, 0, stream>>>(deg, row_ptr, bsum);
    scan2_kernel<<<1, 256, 0, stream>>>(bsum, boff, row_ptr);
    scan3_kernel<<<196, 256, 0, stream>>>(boff, row_ptr, cursor);
    scatter_kernel<<<(N_EDGES + 255) / 256, 256, 0, stream>>>(ei, cursor, src_csr, dst_csr);

    // layer 1
    mfma_gemm_kernel<128><<<dim3(4, (N_NODES + 63) / 64), 256, 0, stream>>>(
        xbf, W1t, gbf, N_NODES, as1, ad1, asv, adv);
    weights_kernel<<<(N_EDGES + 255) / 256, 256, 0, stream>>>(asv, adv, src_csr, dst_csr, w_csr);
    aggregate_kernel<1><<<N_NODES / 4, 256, 0, stream>>>(gbf, asv, adv, row_ptr, src_csr, w_csr,
                                                         b1, hactbf, nullptr, nullptr, nullptr);
    // layer 2
    mfma_gemm_kernel<256><<<dim3(4, (N_NODES + 63) / 64), 256, 0, stream>>>(
        hactbf, W2t, gbf, N_NODES, as2, ad2, asv, adv);
    weights_kernel<<<(N_EDGES + 255) / 256, 256, 0, stream>>>(asv, adv, src_csr, dst_csr, w_csr);
    aggregate_kernel<2><<<N_NODES / 4, 256, 0, stream>>>(gbf, asv, adv, row_ptr, src_csr, w_csr,
                                                         b2, nullptr, fcw, fcb, (float*)d_out);
}

// Round 6
// 292.263 us; speedup vs baseline: 2.2462x; 1.0557x over previous
//
#include <hip/hip_runtime.h>
#include <hip/hip_bf16.h>

#define N_NODES 50000
#define N_EDGES 800000

typedef __attribute__((ext_vector_type(8))) short bf16x8;
typedef __attribute__((ext_vector_type(4))) float f32x4;
typedef __attribute__((ext_vector_type(2))) float f32x2;
typedef unsigned short ushort_t;

__device__ __forceinline__ float bf2f(unsigned short u) {
    union { unsigned u32; float f; } v; v.u32 = (unsigned)u << 16; return v.f;
}
__device__ __forceinline__ unsigned short f2bf(float f) {
    __hip_bfloat16 h = __float2bfloat16(f);
    return *reinterpret_cast<unsigned short*>(&h);
}
__device__ __forceinline__ f32x2 bfpair(unsigned u) {
    union { unsigned a; float f; } lo, hi;
    lo.a = u << 16;
    hi.a = u & 0xFFFF0000u;
    f32x2 r; r.x = lo.f; r.y = hi.f; return r;
}
__device__ __forceinline__ void pkfma(f32x2& d, f32x2 a, f32x2 b) {
    asm("v_pk_fma_f32 %0, %1, %2, %0" : "+v"(d) : "v"(a), "v"(b));
}
__device__ __forceinline__ void gload16(const void* src, void* lds) {
    __builtin_amdgcn_global_load_lds(
        (const __attribute__((address_space(1))) unsigned int*)src,
        (__attribute__((address_space(3))) unsigned int*)lds, 16, 0, 0);
}

// inline int64-vs-int32 layout detection (odd 32-bit words all zero -> int64)
__device__ __forceinline__ int detect_is32_block(const unsigned* __restrict__ w,
                                                 int* s_is32, int tid) {
    if (tid == 0) {
        unsigned o = 0;
#pragma unroll
        for (int k = 1; k < 32; k += 2) o |= w[k];
        *s_is32 = (o != 0u);
    }
    __syncthreads();
    return *s_is32;
}

__device__ __forceinline__ int edge_elem(const unsigned* __restrict__ w, int is32, long long idx) {
    return is32 ? (int)w[idx] : (int)w[2 * idx];
}

// ---------------- CSR build ----------------
__global__ void __launch_bounds__(256) hist_kernel(const unsigned* __restrict__ ew,
                                                   int* __restrict__ deg) {
    __shared__ int s_is32;
    int is32 = detect_is32_block(ew, &s_is32, threadIdx.x);
    int e = blockIdx.x * 256 + threadIdx.x;
    if (e >= N_EDGES) return;
    int d = edge_elem(ew, is32, (long long)N_EDGES + e);
    atomicAdd(&deg[d], 1);
}

__global__ void __launch_bounds__(256) scan1_kernel(const int* __restrict__ deg,
                                                    int* __restrict__ excl, int* __restrict__ bsum) {
    __shared__ int s[256];
    int b = blockIdx.x, t = threadIdx.x, i = b * 256 + t;
    int v = (i < N_NODES) ? deg[i] : 0;
    s[t] = v;
    __syncthreads();
    for (int off = 1; off < 256; off <<= 1) {
        int y = (t >= off) ? s[t - off] : 0;
        __syncthreads();
        s[t] += y;
        __syncthreads();
    }
    if (i < N_NODES) excl[i] = s[t] - v;
    if (t == 255) bsum[b] = s[255];
}

__global__ void __launch_bounds__(256) scan2_kernel(const int* __restrict__ bsum,
                                                    int* __restrict__ boff, int* __restrict__ row_ptr) {
    __shared__ int s[256];
    int t = threadIdx.x;
    int v = (t < 196) ? bsum[t] : 0;
    s[t] = v;
    __syncthreads();
    for (int off = 1; off < 256; off <<= 1) {
        int y = (t >= off) ? s[t - off] : 0;
        __syncthreads();
        s[t] += y;
        __syncthreads();
    }
    if (t < 196) boff[t] = s[t] - v;
    if (t == 255) row_ptr[N_NODES] = s[255];
}

__global__ void __launch_bounds__(256) scan3_kernel(const int* __restrict__ boff,
                                                    int* __restrict__ row_ptr, int* __restrict__ cursor) {
    int i = blockIdx.x * 256 + threadIdx.x;
    if (i < N_NODES) {
        int v = row_ptr[i] + boff[blockIdx.x];
        row_ptr[i] = v;
        cursor[i] = v;
    }
}

__global__ void __launch_bounds__(256) scatter_kernel(const unsigned* __restrict__ ew,
                                                      int* __restrict__ cursor,
                                                      int* __restrict__ src_csr,
                                                      int* __restrict__ dst_csr) {
    __shared__ int s_is32;
    int is32 = detect_is32_block(ew, &s_is32, threadIdx.x);
    int e = blockIdx.x * 256 + threadIdx.x;
    if (e >= N_EDGES) return;
    int s = edge_elem(ew, is32, e);
    int d = edge_elem(ew, is32, (long long)N_EDGES + e);
    int pos = atomicAdd(&cursor[d], 1);
    src_csr[pos] = s;
    dst_csr[pos] = d;
}

// ---------------- fused prep: x->bf16, W1^T->bf16, W2^T->bf16 ----------------
#define CONV_BLOCKS 6250   /* 50000*128/4 / 256 */
__global__ void __launch_bounds__(256) prep_kernel(const float* __restrict__ x,
                                                   ushort_t* __restrict__ xbf,
                                                   const float* __restrict__ W1,
                                                   ushort_t* __restrict__ W1t,
                                                   const float* __restrict__ W2,
                                                   ushort_t* __restrict__ W2t) {
    int b = blockIdx.x, t = threadIdx.x;
    if (b < CONV_BLOCKS) {
        int i = b * 256 + t;
        float4 v = ((const float4*)x)[i];
        ushort4 o;
        o.x = f2bf(v.x); o.y = f2bf(v.y); o.z = f2bf(v.z); o.w = f2bf(v.w);
        ((ushort4*)xbf)[i] = o;
    } else if (b < CONV_BLOCKS + 128) {
        int id = (b - CONV_BLOCKS) * 256 + t;       // id = n*128 + k
        int n = id >> 7, k = id & 127;
        W1t[id] = f2bf(W1[k * 256 + n]);
    } else {
        int id = (b - CONV_BLOCKS - 128) * 256 + t; // id = n*256 + k
        int n = id >> 8, k = id & 255;
        W2t[id] = f2bf(W2[k * 256 + n]);
    }
}

// ---------------- MFMA bf16 GEMM + fused alpha logits ----------------
// C[M,256] = A[M,K](bf16) @ Wt^T. OUTFP8: C stored as e4m3 (1B/ch), else bf16.
// colblock == head; epilogue computes alpha_s/alpha_d from fp32 accs.
template <int K, int OUTFP8>
__global__ void __launch_bounds__(256) mfma_gemm_kernel(const ushort_t* __restrict__ A,
                                                        const ushort_t* __restrict__ Wt,
                                                        void* __restrict__ Cv, int M,
                                                        const float* __restrict__ a_src,
                                                        const float* __restrict__ a_dst,
                                                        float* __restrict__ alpha_s,
                                                        float* __restrict__ alpha_d) {
    constexpr int CPR = K / 8;
    constexpr int NT = K / 64;
    __shared__ ushort_t Bs[64 * K];
    __shared__ ushort_t As[2][64 * 64];
    __shared__ float ps[64][2], pd[64][2];

    int tid = threadIdx.x;
    int wave = tid >> 6, lane = tid & 63;
    int l15 = lane & 15, l4 = lane >> 4;
    int wr = wave >> 1, wc = wave & 1;
    int colblock = blockIdx.x;   // head
    int rowblock = blockIdx.y;

    for (int base = 0; base < 64 * CPR; base += 256) {
        int p = base + wave * 64 + lane;
        int row = p / CPR;
        int cs = p % CPR;
        int c = cs ^ (row & 7);
        const ushort_t* src = Wt + (long long)(colblock * 64 + row) * K + c * 8;
        void* dst = ((char*)Bs) + (base + wave * 64) * 16;
        gload16(src, dst);
    }
    {
        int r = lane >> 3, cs = lane & 7;
        int c = cs ^ r;
#pragma unroll
        for (int q = 0; q < 2; ++q) {
            int lrow = wave * 16 + q * 8;
            int grow = rowblock * 64 + lrow + r;
            if (grow >= M) grow = M - 1;
            const ushort_t* src = A + (long long)grow * K + c * 8;
            void* dst = ((char*)&As[0][0]) + lrow * 128;
            gload16(src, dst);
        }
    }
    __syncthreads();

    f32x4 acc[2][2] = {};
#pragma unroll
    for (int t = 0; t < NT; ++t) {
        if (t + 1 < NT) {
            int r = lane >> 3, cs = lane & 7;
            int c = cs ^ r;
#pragma unroll
            for (int q = 0; q < 2; ++q) {
                int lrow = wave * 16 + q * 8;
                int grow = rowblock * 64 + lrow + r;
                if (grow >= M) grow = M - 1;
                const ushort_t* src = A + (long long)grow * K + (t + 1) * 64 + c * 8;
                void* dst = ((char*)&As[(t + 1) & 1][0]) + lrow * 128;
                gload16(src, dst);
            }
        }
        const ushort_t* At = &As[t & 1][0];
#pragma unroll
        for (int w = 0; w < 2; ++w) {
            bf16x8 a[2], b[2];
#pragma unroll
            for (int mi = 0; mi < 2; ++mi) {
                int row = wr * 32 + mi * 16 + l15;
                int slot = (w * 4 + l4) ^ (l15 & 7);
                a[mi] = *(const bf16x8*)&At[row * 64 + slot * 8];
            }
#pragma unroll
            for (int ni = 0; ni < 2; ++ni) {
                int brow = wc * 32 + ni * 16 + l15;
                int slot = (t * 8 + w * 4 + l4) ^ (l15 & 7);
                b[ni] = *(const bf16x8*)&Bs[brow * CPR * 8 + slot * 8];
            }
#pragma unroll
            for (int mi = 0; mi < 2; ++mi)
#pragma unroll
                for (int ni = 0; ni < 2; ++ni)
                    acc[mi][ni] = __builtin_amdgcn_mfma_f32_16x16x32_bf16(a[mi], b[ni],
                                                                          acc[mi][ni], 0, 0, 0);
        }
        __syncthreads();
    }

    // ---- fused alpha partials: per-row dot with a_src/a_dst (this head) ----
    {
        float as0 = a_src[colblock * 64 + wc * 32 + l15];
        float as1 = a_src[colblock * 64 + wc * 32 + 16 + l15];
        float ad0 = a_dst[colblock * 64 + wc * 32 + l15];
        float ad1 = a_dst[colblock * 64 + wc * 32 + 16 + l15];
#pragma unroll
        for (int mi = 0; mi < 2; ++mi)
#pragma unroll
            for (int q = 0; q < 4; ++q) {
                float sv = acc[mi][0][q] * as0 + acc[mi][1][q] * as1;
                float dv = acc[mi][0][q] * ad0 + acc[mi][1][q] * ad1;
#pragma unroll
                for (int w = 1; w < 16; w <<= 1) {
                    sv += __shfl_xor(sv, w, 64);
                    dv += __shfl_xor(dv, w, 64);
                }
                if (l15 == 0) {
                    int row = wr * 32 + mi * 16 + l4 * 4 + q;
                    ps[row][wc] = sv;
                    pd[row][wc] = dv;
                }
            }
    }

    // ---- epilogue: repack via LDS (bf16 staging), store bf16 or fp8 ----
    ushort_t* ep = ((ushort_t*)&As[0][0]) + wave * 1280;
#pragma unroll
    for (int mi = 0; mi < 2; ++mi)
#pragma unroll
        for (int ni = 0; ni < 2; ++ni)
#pragma unroll
            for (int q = 0; q < 4; ++q) {
                int row = mi * 16 + l4 * 4 + q;
                int col = ni * 16 + l15;
                ep[row * 40 + col] = f2bf(acc[mi][ni][q]);
            }
    __syncthreads();
#pragma unroll
    for (int j = 0; j < 2; ++j) {
        int p = lane * 2 + j;
        int row = p >> 2, seg = p & 3;
        uint4 v = *(const uint4*)&ep[row * 40 + seg * 8];
        int grow = rowblock * 64 + wr * 32 + row;
        int gcol = colblock * 64 + wc * 32 + seg * 8;
        if (grow < M) {
            if constexpr (OUTFP8) {
                f32x2 f01 = bfpair(v.x), f23 = bfpair(v.y);
                f32x2 f45 = bfpair(v.z), f67 = bfpair(v.w);
                int d0 = 0, d1 = 0;
                d0 = __builtin_amdgcn_cvt_pk_fp8_f32(f01.x, f01.y, d0, false);
                d0 = __builtin_amdgcn_cvt_pk_fp8_f32(f23.x, f23.y, d0, true);
                d1 = __builtin_amdgcn_cvt_pk_fp8_f32(f45.x, f45.y, d1, false);
                d1 = __builtin_amdgcn_cvt_pk_fp8_f32(f67.x, f67.y, d1, true);
                uint2 o; o.x = (unsigned)d0; o.y = (unsigned)d1;
                *(uint2*)((char*)Cv + (long long)grow * 256 + gcol) = o;
            } else {
                *(uint4*)&((ushort_t*)Cv)[(long long)grow * 256 + gcol] = v;
            }
        }
    }
    if (tid < 64) {
        int ga = rowblock * 64 + tid;
        if (ga < M) {
            alpha_s[ga * 4 + colblock] = ps[tid][0] + ps[tid][1];
            alpha_d[ga * 4 + colblock] = pd[tid][0] + pd[tid][1];
        }
    }
}

// ---------------- per-edge softmax weights (all 4 heads) ----------------
__global__ void __launch_bounds__(256) weights_kernel(const float* __restrict__ alpha_s,
                                                      const float* __restrict__ alpha_d,
                                                      const int* __restrict__ src_csr,
                                                      const int* __restrict__ dst_csr,
                                                      float* __restrict__ w_csr) {
    int e = blockIdx.x * 256 + threadIdx.x;
    if (e >= N_EDGES) return;
    int j = src_csr[e], d = dst_csr[e];
    float4 a = *(const float4*)&alpha_s[j * 4];
    float4 b = *(const float4*)&alpha_d[d * 4];
    float4 o;
    float e0 = a.x + b.x; e0 = e0 > 0.f ? e0 : 0.2f * e0; o.x = __expf(e0);
    float e1 = a.y + b.y; e1 = e1 > 0.f ? e1 : 0.2f * e1; o.y = __expf(e1);
    float e2 = a.z + b.z; e2 = e2 > 0.f ? e2 : 0.2f * e2; o.z = __expf(e2);
    float e3 = a.w + b.w; e3 = e3 > 0.f ? e3 : 0.2f * e3; o.w = __expf(e3);
    *(float4*)&w_csr[e * 4] = o;
}

// ---------------- softmax-weighted aggregation (one wave per node) ----------------
// LAYER 1: g is fp8 e4m3 (256 B/row). LAYER 2: g is bf16 (512 B/row).
template <int LAYER>
__global__ void __launch_bounds__(256) aggregate_kernel(
    const void* __restrict__ gv, const float* __restrict__ alpha_s,
    const float* __restrict__ alpha_d, const int* __restrict__ row_ptr,
    const int* __restrict__ src_csr, const float* __restrict__ w_csr,
    const float* __restrict__ bias, ushort_t* __restrict__ out_bf,
    const float* __restrict__ fc_w, const float* __restrict__ fc_b,
    float* __restrict__ final_out) {
    int wave = threadIdx.x >> 6;
    int lane = threadIdx.x & 63;
    int i = blockIdx.x * 4 + wave;
    int hd = lane >> 4;
    const uint2* g2 = (const uint2*)gv;   // bf16 rows (layer 2)
    const unsigned* g1 = (const unsigned*)gv;  // fp8 rows (layer 1)

    // self loop
    float e0 = alpha_s[i * 4 + hd] + alpha_d[i * 4 + hd];
    e0 = e0 > 0.f ? e0 : 0.2f * e0;
    float w0 = __expf(e0);
    f32x2 wp0; wp0.x = w0; wp0.y = w0;
    f32x2 acc01 = {0.f, 0.f}, acc23 = {0.f, 0.f};
    if (LAYER == 1) {
        unsigned sv = g1[((long long)i << 6) + lane];
        pkfma(acc01, wp0, __builtin_amdgcn_cvt_pk_f32_fp8(sv, false));
        pkfma(acc23, wp0, __builtin_amdgcn_cvt_pk_f32_fp8(sv, true));
    } else {
        uint2 hv = g2[((long long)i << 6) + lane];
        pkfma(acc01, wp0, bfpair(hv.x));
        pkfma(acc23, wp0, bfpair(hv.y));
    }
    float wsum = w0;

    int p = row_ptr[i], p1 = row_ptr[i + 1];
    if (LAYER == 1) {
        for (; p + 8 <= p1; p += 8) {
            int j[8]; float wt[8]; unsigned hh[8];
#pragma unroll
            for (int u = 0; u < 8; ++u) j[u] = src_csr[p + u];
#pragma unroll
            for (int u = 0; u < 8; ++u) wt[u] = w_csr[(p + u) * 4 + hd];
#pragma unroll
            for (int u = 0; u < 8; ++u) hh[u] = g1[((long long)j[u] << 6) + lane];
#pragma unroll
            for (int u = 0; u < 8; ++u) {
                wsum += wt[u];
                f32x2 wp; wp.x = wt[u]; wp.y = wt[u];
                pkfma(acc01, wp, __builtin_amdgcn_cvt_pk_f32_fp8(hh[u], false));
                pkfma(acc23, wp, __builtin_amdgcn_cvt_pk_f32_fp8(hh[u], true));
            }
        }
        for (; p < p1; ++p) {
            int j = src_csr[p];
            float wt = w_csr[p * 4 + hd];
            unsigned hj = g1[((long long)j << 6) + lane];
            wsum += wt;
            f32x2 wp; wp.x = wt; wp.y = wt;
            pkfma(acc01, wp, __builtin_amdgcn_cvt_pk_f32_fp8(hj, false));
            pkfma(acc23, wp, __builtin_amdgcn_cvt_pk_f32_fp8(hj, true));
        }
    } else {
        for (; p + 8 <= p1; p += 8) {
            int j[8]; float wt[8]; uint2 hh[8];
#pragma unroll
            for (int u = 0; u < 8; ++u) j[u] = src_csr[p + u];
#pragma unroll
            for (int u = 0; u < 8; ++u) wt[u] = w_csr[(p + u) * 4 + hd];
#pragma unroll
            for (int u = 0; u < 8; ++u) hh[u] = g2[((long long)j[u] << 6) + lane];
#pragma unroll
            for (int u = 0; u < 8; ++u) {
                wsum += wt[u];
                f32x2 wp; wp.x = wt[u]; wp.y = wt[u];
                pkfma(acc01, wp, bfpair(hh[u].x));
                pkfma(acc23, wp, bfpair(hh[u].y));
            }
        }
        for (; p < p1; ++p) {
            int j = src_csr[p];
            float wt = w_csr[p * 4 + hd];
            uint2 hj = g2[((long long)j << 6) + lane];
            wsum += wt;
            f32x2 wp; wp.x = wt; wp.y = wt;
            pkfma(acc01, wp, bfpair(hj.x));
            pkfma(acc23, wp, bfpair(hj.y));
        }
    }
    float inv = 1.f / (wsum + 1e-16f);
    int c = lane * 4;
    float4 b4 = *(const float4*)&bias[c];
    float o0 = acc01.x * inv + b4.x;
    float o1 = acc01.y * inv + b4.y;
    float o2 = acc23.x * inv + b4.z;
    float o3 = acc23.y * inv + b4.w;
    o0 = o0 > 0.f ? o0 : __expf(o0) - 1.f;
    o1 = o1 > 0.f ? o1 : __expf(o1) - 1.f;
    o2 = o2 > 0.f ? o2 : __expf(o2) - 1.f;
    o3 = o3 > 0.f ? o3 : __expf(o3) - 1.f;
    if (LAYER == 1) {
        ushort4 o;
        o.x = f2bf(o0); o.y = f2bf(o1); o.z = f2bf(o2); o.w = f2bf(o3);
        ((ushort4*)out_bf)[(long long)i * 64 + lane] = o;
    } else {
        float4 fw = *(const float4*)&fc_w[c];
        float dot = o0 * fw.x + o1 * fw.y + o2 * fw.z + o3 * fw.w;
#pragma unroll
        for (int off = 32; off; off >>= 1) dot += __shfl_down(dot, off, 64);
        if (lane == 0) final_out[i] = 1.f / (1.f + __expf(-(dot + fc_b[0])));
    }
}

// ---------------- launch ----------------
extern "C" void kernel_launch(void* const* d_in, const int* in_sizes, int n_in,
                              void* d_out, int out_size, void* d_ws, size_t ws_size,
                              hipStream_t stream) {
    const float* x   = (const float*)d_in[0];
    const unsigned* ei = (const unsigned*)d_in[1];
    const float* W1  = (const float*)d_in[2];
    const float* as1 = (const float*)d_in[3];
    const float* ad1 = (const float*)d_in[4];
    const float* b1  = (const float*)d_in[5];
    const float* W2  = (const float*)d_in[6];
    const float* as2 = (const float*)d_in[7];
    const float* ad2 = (const float*)d_in[8];
    const float* b2  = (const float*)d_in[9];
    const float* fcw = (const float*)d_in[10];
    const float* fcb = (const float*)d_in[11];

    char* ws = (char*)d_ws;
    void* g1f8       = (void*)(ws + 0);               // 50000*256 fp8 = 12.8 MB
    void* g2bf       = (void*)(ws + 12800000);        // 25.6 MB (bf16, layer2)
    ushort_t* hactbf = (ushort_t*)(ws + 38400000);    // 25.6 MB
    ushort_t* xbf    = (ushort_t*)(ws + 64000000);    // 12.8 MB
    ushort_t* W1t    = (ushort_t*)(ws + 76800000);
    ushort_t* W2t    = (ushort_t*)(ws + 76900000);
    float* asv       = (float*)(ws + 77100000);
    float* adv       = (float*)(ws + 77900000);
    int* row_ptr     = (int*)(ws + 78700000);
    int* deg         = (int*)(ws + 78900016);
    int* cursor      = (int*)(ws + 79100016);
    int* src_csr     = (int*)(ws + 79300016);
    int* dst_csr     = (int*)(ws + 82500016);
    float* w_csr     = (float*)(ws + 85700032);       // 12.8 MB
    int* bsum        = (int*)(ws + 98500048);
    int* boff        = (int*)(ws + 98501072);

    hipMemsetAsync(deg, 0, N_NODES * 4, stream);

    prep_kernel<<<CONV_BLOCKS + 128 + 256, 256, 0, stream>>>(x, xbf, W1, W1t, W2, W2t);
    hist_kernel<<<(N_EDGES + 255) / 256, 256, 0, stream>>>(ei, deg);
    scan1_kernel<<<196, 256, 0, stream>>>(deg, row_ptr, bsum);
    scan2_kernel<<<1, 256, 0, stream>>>(bsum, boff, row_ptr);
    scan3_kernel<<<196, 256, 0, stream>>>(boff, row_ptr, cursor);
    scatter_kernel<<<(N_EDGES + 255) / 256, 256, 0, stream>>>(ei, cursor, src_csr, dst_csr);

    // layer 1 (g stored fp8)
    mfma_gemm_kernel<128, 1><<<dim3(4, (N_NODES + 63) / 64), 256, 0, stream>>>(
        xbf, W1t, g1f8, N_NODES, as1, ad1, asv, adv);
    weights_kernel<<<(N_EDGES + 255) / 256, 256, 0, stream>>>(asv, adv, src_csr, dst_csr, w_csr);
    aggregate_kernel<1><<<N_NODES / 4, 256, 0, stream>>>(g1f8, asv, adv, row_ptr, src_csr, w_csr,
                                                         b1, hactbf, nullptr, nullptr, nullptr);
    // layer 2 (g stored bf16)
    mfma_gemm_kernel<256, 0><<<dim3(4, (N_NODES + 63) / 64), 256, 0, stream>>>(
        hactbf, W2t, g2bf, N_NODES, as2, ad2, asv, adv);
    weights_kernel<<<(N_EDGES + 255) / 256, 256, 0, stream>>>(asv, adv, src_csr, dst_csr, w_csr);
    aggregate_kernel<2><<<N_NODES / 4, 256, 0, stream>>>(g2bf, asv, adv, row_ptr, src_csr, w_csr,
                                                         b2, nullptr, fcw, fcb, (float*)d_out);
}

// Round 7
// 269.811 us; speedup vs baseline: 2.4331x; 1.0832x over previous
//
#include <hip/hip_runtime.h>
#include <hip/hip_bf16.h>

#define N_NODES 50000
#define N_EDGES 800000

typedef __attribute__((ext_vector_type(8))) short bf16x8;
typedef __attribute__((ext_vector_type(4))) float f32x4;
typedef __attribute__((ext_vector_type(2))) float f32x2;
typedef unsigned short ushort_t;

__device__ __forceinline__ float bf2f(unsigned short u) {
    union { unsigned u32; float f; } v; v.u32 = (unsigned)u << 16; return v.f;
}
__device__ __forceinline__ unsigned short f2bf(float f) {
    __hip_bfloat16 h = __float2bfloat16(f);
    return *reinterpret_cast<unsigned short*>(&h);
}
__device__ __forceinline__ f32x2 bfpair(unsigned u) {
    union { unsigned a; float f; } lo, hi;
    lo.a = u << 16;
    hi.a = u & 0xFFFF0000u;
    f32x2 r; r.x = lo.f; r.y = hi.f; return r;
}
__device__ __forceinline__ void pkfma(f32x2& d, f32x2 a, f32x2 b) {
    asm("v_pk_fma_f32 %0, %1, %2, %0" : "+v"(d) : "v"(a), "v"(b));
}
__device__ __forceinline__ void gload16(const void* src, void* lds) {
    __builtin_amdgcn_global_load_lds(
        (const __attribute__((address_space(1))) unsigned int*)src,
        (__attribute__((address_space(3))) unsigned int*)lds, 16, 0, 0);
}

// inline int64-vs-int32 layout detection (odd 32-bit words all zero -> int64)
__device__ __forceinline__ int detect_is32_block(const unsigned* __restrict__ w,
                                                 int* s_is32, int tid) {
    if (tid == 0) {
        unsigned o = 0;
#pragma unroll
        for (int k = 1; k < 32; k += 2) o |= w[k];
        *s_is32 = (o != 0u);
    }
    __syncthreads();
    return *s_is32;
}

__device__ __forceinline__ int edge_elem(const unsigned* __restrict__ w, int is32, long long idx) {
    return is32 ? (int)w[idx] : (int)w[2 * idx];
}

// ---------------- CSR build ----------------
__global__ void __launch_bounds__(256) hist_kernel(const unsigned* __restrict__ ew,
                                                   int* __restrict__ deg) {
    __shared__ int s_is32;
    int is32 = detect_is32_block(ew, &s_is32, threadIdx.x);
    int e = blockIdx.x * 256 + threadIdx.x;
    if (e >= N_EDGES) return;
    int d = edge_elem(ew, is32, (long long)N_EDGES + e);
    atomicAdd(&deg[d], 1);
}

__global__ void __launch_bounds__(256) scan1_kernel(const int* __restrict__ deg,
                                                    int* __restrict__ excl, int* __restrict__ bsum) {
    __shared__ int s[256];
    int b = blockIdx.x, t = threadIdx.x, i = b * 256 + t;
    int v = (i < N_NODES) ? deg[i] : 0;
    s[t] = v;
    __syncthreads();
    for (int off = 1; off < 256; off <<= 1) {
        int y = (t >= off) ? s[t - off] : 0;
        __syncthreads();
        s[t] += y;
        __syncthreads();
    }
    if (i < N_NODES) excl[i] = s[t] - v;
    if (t == 255) bsum[b] = s[255];
}

__global__ void __launch_bounds__(256) scan2_kernel(const int* __restrict__ bsum,
                                                    int* __restrict__ boff, int* __restrict__ row_ptr) {
    __shared__ int s[256];
    int t = threadIdx.x;
    int v = (t < 196) ? bsum[t] : 0;
    s[t] = v;
    __syncthreads();
    for (int off = 1; off < 256; off <<= 1) {
        int y = (t >= off) ? s[t - off] : 0;
        __syncthreads();
        s[t] += y;
        __syncthreads();
    }
    if (t < 196) boff[t] = s[t] - v;
    if (t == 255) row_ptr[N_NODES] = s[255];
}

__global__ void __launch_bounds__(256) scan3_kernel(const int* __restrict__ boff,
                                                    int* __restrict__ row_ptr, int* __restrict__ cursor) {
    int i = blockIdx.x * 256 + threadIdx.x;
    if (i < N_NODES) {
        int v = row_ptr[i] + boff[blockIdx.x];
        row_ptr[i] = v;
        cursor[i] = v;
    }
}

__global__ void __launch_bounds__(256) scatter_kernel(const unsigned* __restrict__ ew,
                                                      int* __restrict__ cursor,
                                                      int* __restrict__ src_csr,
                                                      int* __restrict__ dst_csr) {
    __shared__ int s_is32;
    int is32 = detect_is32_block(ew, &s_is32, threadIdx.x);
    int e = blockIdx.x * 256 + threadIdx.x;
    if (e >= N_EDGES) return;
    int s = edge_elem(ew, is32, e);
    int d = edge_elem(ew, is32, (long long)N_EDGES + e);
    int pos = atomicAdd(&cursor[d], 1);
    src_csr[pos] = s;
    dst_csr[pos] = d;
}

// ---------------- fused prep: x->bf16, W1^T->bf16, W2^T->bf16 ----------------
#define CONV_BLOCKS 6250   /* 50000*128/4 / 256 */
__global__ void __launch_bounds__(256) prep_kernel(const float* __restrict__ x,
                                                   ushort_t* __restrict__ xbf,
                                                   const float* __restrict__ W1,
                                                   ushort_t* __restrict__ W1t,
                                                   const float* __restrict__ W2,
                                                   ushort_t* __restrict__ W2t) {
    int b = blockIdx.x, t = threadIdx.x;
    if (b < CONV_BLOCKS) {
        int i = b * 256 + t;
        float4 v = ((const float4*)x)[i];
        ushort4 o;
        o.x = f2bf(v.x); o.y = f2bf(v.y); o.z = f2bf(v.z); o.w = f2bf(v.w);
        ((ushort4*)xbf)[i] = o;
    } else if (b < CONV_BLOCKS + 128) {
        int id = (b - CONV_BLOCKS) * 256 + t;       // id = n*128 + k
        int n = id >> 7, k = id & 127;
        W1t[id] = f2bf(W1[k * 256 + n]);
    } else {
        int id = (b - CONV_BLOCKS - 128) * 256 + t; // id = n*256 + k
        int n = id >> 8, k = id & 255;
        W2t[id] = f2bf(W2[k * 256 + n]);
    }
}

// ---------------- MFMA bf16 GEMM + fused alpha logits ----------------
// C[M,256] = A[M,K](bf16) @ Wt^T, stored as fp8 e4m3 (1B/ch).
// colblock == head; epilogue computes alpha_s/alpha_d from fp32 accs.
template <int K>
__global__ void __launch_bounds__(256) mfma_gemm_kernel(const ushort_t* __restrict__ A,
                                                        const ushort_t* __restrict__ Wt,
                                                        void* __restrict__ Cv, int M,
                                                        const float* __restrict__ a_src,
                                                        const float* __restrict__ a_dst,
                                                        float* __restrict__ alpha_s,
                                                        float* __restrict__ alpha_d) {
    constexpr int CPR = K / 8;
    constexpr int NT = K / 64;
    __shared__ ushort_t Bs[64 * K];
    __shared__ ushort_t As[2][64 * 64];
    __shared__ float ps[64][2], pd[64][2];

    int tid = threadIdx.x;
    int wave = tid >> 6, lane = tid & 63;
    int l15 = lane & 15, l4 = lane >> 4;
    int wr = wave >> 1, wc = wave & 1;
    int colblock = blockIdx.x;   // head
    int rowblock = blockIdx.y;

    for (int base = 0; base < 64 * CPR; base += 256) {
        int p = base + wave * 64 + lane;
        int row = p / CPR;
        int cs = p % CPR;
        int c = cs ^ (row & 7);
        const ushort_t* src = Wt + (long long)(colblock * 64 + row) * K + c * 8;
        void* dst = ((char*)Bs) + (base + wave * 64) * 16;
        gload16(src, dst);
    }
    {
        int r = lane >> 3, cs = lane & 7;
        int c = cs ^ r;
#pragma unroll
        for (int q = 0; q < 2; ++q) {
            int lrow = wave * 16 + q * 8;
            int grow = rowblock * 64 + lrow + r;
            if (grow >= M) grow = M - 1;
            const ushort_t* src = A + (long long)grow * K + c * 8;
            void* dst = ((char*)&As[0][0]) + lrow * 128;
            gload16(src, dst);
        }
    }
    __syncthreads();

    f32x4 acc[2][2] = {};
#pragma unroll
    for (int t = 0; t < NT; ++t) {
        if (t + 1 < NT) {
            int r = lane >> 3, cs = lane & 7;
            int c = cs ^ r;
#pragma unroll
            for (int q = 0; q < 2; ++q) {
                int lrow = wave * 16 + q * 8;
                int grow = rowblock * 64 + lrow + r;
                if (grow >= M) grow = M - 1;
                const ushort_t* src = A + (long long)grow * K + (t + 1) * 64 + c * 8;
                void* dst = ((char*)&As[(t + 1) & 1][0]) + lrow * 128;
                gload16(src, dst);
            }
        }
        const ushort_t* At = &As[t & 1][0];
#pragma unroll
        for (int w = 0; w < 2; ++w) {
            bf16x8 a[2], b[2];
#pragma unroll
            for (int mi = 0; mi < 2; ++mi) {
                int row = wr * 32 + mi * 16 + l15;
                int slot = (w * 4 + l4) ^ (l15 & 7);
                a[mi] = *(const bf16x8*)&At[row * 64 + slot * 8];
            }
#pragma unroll
            for (int ni = 0; ni < 2; ++ni) {
                int brow = wc * 32 + ni * 16 + l15;
                int slot = (t * 8 + w * 4 + l4) ^ (l15 & 7);
                b[ni] = *(const bf16x8*)&Bs[brow * CPR * 8 + slot * 8];
            }
#pragma unroll
            for (int mi = 0; mi < 2; ++mi)
#pragma unroll
                for (int ni = 0; ni < 2; ++ni)
                    acc[mi][ni] = __builtin_amdgcn_mfma_f32_16x16x32_bf16(a[mi], b[ni],
                                                                          acc[mi][ni], 0, 0, 0);
        }
        __syncthreads();
    }

    // ---- fused alpha partials: per-row dot with a_src/a_dst (this head) ----
    {
        float as0 = a_src[colblock * 64 + wc * 32 + l15];
        float as1 = a_src[colblock * 64 + wc * 32 + 16 + l15];
        float ad0 = a_dst[colblock * 64 + wc * 32 + l15];
        float ad1 = a_dst[colblock * 64 + wc * 32 + 16 + l15];
#pragma unroll
        for (int mi = 0; mi < 2; ++mi)
#pragma unroll
            for (int q = 0; q < 4; ++q) {
                float sv = acc[mi][0][q] * as0 + acc[mi][1][q] * as1;
                float dv = acc[mi][0][q] * ad0 + acc[mi][1][q] * ad1;
#pragma unroll
                for (int w = 1; w < 16; w <<= 1) {
                    sv += __shfl_xor(sv, w, 64);
                    dv += __shfl_xor(dv, w, 64);
                }
                if (l15 == 0) {
                    int row = wr * 32 + mi * 16 + l4 * 4 + q;
                    ps[row][wc] = sv;
                    pd[row][wc] = dv;
                }
            }
    }

    // ---- epilogue: repack via LDS (bf16 staging), store fp8 ----
    ushort_t* ep = ((ushort_t*)&As[0][0]) + wave * 1280;
#pragma unroll
    for (int mi = 0; mi < 2; ++mi)
#pragma unroll
        for (int ni = 0; ni < 2; ++ni)
#pragma unroll
            for (int q = 0; q < 4; ++q) {
                int row = mi * 16 + l4 * 4 + q;
                int col = ni * 16 + l15;
                ep[row * 40 + col] = f2bf(acc[mi][ni][q]);
            }
    __syncthreads();
#pragma unroll
    for (int j = 0; j < 2; ++j) {
        int p = lane * 2 + j;
        int row = p >> 2, seg = p & 3;
        uint4 v = *(const uint4*)&ep[row * 40 + seg * 8];
        int grow = rowblock * 64 + wr * 32 + row;
        int gcol = colblock * 64 + wc * 32 + seg * 8;
        if (grow < M) {
            f32x2 f01 = bfpair(v.x), f23 = bfpair(v.y);
            f32x2 f45 = bfpair(v.z), f67 = bfpair(v.w);
            int d0 = 0, d1 = 0;
            d0 = __builtin_amdgcn_cvt_pk_fp8_f32(f01.x, f01.y, d0, false);
            d0 = __builtin_amdgcn_cvt_pk_fp8_f32(f23.x, f23.y, d0, true);
            d1 = __builtin_amdgcn_cvt_pk_fp8_f32(f45.x, f45.y, d1, false);
            d1 = __builtin_amdgcn_cvt_pk_fp8_f32(f67.x, f67.y, d1, true);
            uint2 o; o.x = (unsigned)d0; o.y = (unsigned)d1;
            *(uint2*)((char*)Cv + (long long)grow * 256 + gcol) = o;
        }
    }
    if (tid < 64) {
        int ga = rowblock * 64 + tid;
        if (ga < M) {
            alpha_s[ga * 4 + colblock] = ps[tid][0] + ps[tid][1];
            alpha_d[ga * 4 + colblock] = pd[tid][0] + pd[tid][1];
        }
    }
}

// ---------------- per-edge softmax weights (all 4 heads) ----------------
__global__ void __launch_bounds__(256) weights_kernel(const float* __restrict__ alpha_s,
                                                      const float* __restrict__ alpha_d,
                                                      const int* __restrict__ src_csr,
                                                      const int* __restrict__ dst_csr,
                                                      float* __restrict__ w_csr) {
    int e = blockIdx.x * 256 + threadIdx.x;
    if (e >= N_EDGES) return;
    int j = src_csr[e], d = dst_csr[e];
    float4 a = *(const float4*)&alpha_s[j * 4];
    float4 b = *(const float4*)&alpha_d[d * 4];
    float4 o;
    float e0 = a.x + b.x; e0 = e0 > 0.f ? e0 : 0.2f * e0; o.x = __expf(e0);
    float e1 = a.y + b.y; e1 = e1 > 0.f ? e1 : 0.2f * e1; o.y = __expf(e1);
    float e2 = a.z + b.z; e2 = e2 > 0.f ? e2 : 0.2f * e2; o.z = __expf(e2);
    float e3 = a.w + b.w; e3 = e3 > 0.f ? e3 : 0.2f * e3; o.w = __expf(e3);
    *(float4*)&w_csr[e * 4] = o;
}

// ---------------- softmax-weighted aggregation (one wave per node) ----------------
// g rows are fp8 e4m3 (256 B/row) for BOTH layers.
template <int LAYER>
__global__ void __launch_bounds__(256) aggregate_kernel(
    const void* __restrict__ gv, const float* __restrict__ alpha_s,
    const float* __restrict__ alpha_d, const int* __restrict__ row_ptr,
    const int* __restrict__ src_csr, const float* __restrict__ w_csr,
    const float* __restrict__ bias, ushort_t* __restrict__ out_bf,
    const float* __restrict__ fc_w, const float* __restrict__ fc_b,
    float* __restrict__ final_out) {
    int wave = threadIdx.x >> 6;
    int lane = threadIdx.x & 63;
    int i = blockIdx.x * 4 + wave;
    int hd = lane >> 4;
    const unsigned* g1 = (const unsigned*)gv;  // fp8 rows: 64 u32/row

    // self loop
    float e0 = alpha_s[i * 4 + hd] + alpha_d[i * 4 + hd];
    e0 = e0 > 0.f ? e0 : 0.2f * e0;
    float w0 = __expf(e0);
    f32x2 wp0; wp0.x = w0; wp0.y = w0;
    f32x2 acc01 = {0.f, 0.f}, acc23 = {0.f, 0.f};
    {
        unsigned sv = g1[((long long)i << 6) + lane];
        pkfma(acc01, wp0, __builtin_amdgcn_cvt_pk_f32_fp8(sv, false));
        pkfma(acc23, wp0, __builtin_amdgcn_cvt_pk_f32_fp8(sv, true));
    }
    float wsum = w0;

    int p = row_ptr[i], p1 = row_ptr[i + 1];
    for (; p + 8 <= p1; p += 8) {
        int j[8]; float wt[8]; unsigned hh[8];
#pragma unroll
        for (int u = 0; u < 8; ++u) j[u] = src_csr[p + u];
#pragma unroll
        for (int u = 0; u < 8; ++u) wt[u] = w_csr[(p + u) * 4 + hd];
#pragma unroll
        for (int u = 0; u < 8; ++u) hh[u] = g1[((long long)j[u] << 6) + lane];
#pragma unroll
        for (int u = 0; u < 8; ++u) {
            wsum += wt[u];
            f32x2 wp; wp.x = wt[u]; wp.y = wt[u];
            pkfma(acc01, wp, __builtin_amdgcn_cvt_pk_f32_fp8(hh[u], false));
            pkfma(acc23, wp, __builtin_amdgcn_cvt_pk_f32_fp8(hh[u], true));
        }
    }
    for (; p < p1; ++p) {
        int j = src_csr[p];
        float wt = w_csr[p * 4 + hd];
        unsigned hj = g1[((long long)j << 6) + lane];
        wsum += wt;
        f32x2 wp; wp.x = wt; wp.y = wt;
        pkfma(acc01, wp, __builtin_amdgcn_cvt_pk_f32_fp8(hj, false));
        pkfma(acc23, wp, __builtin_amdgcn_cvt_pk_f32_fp8(hj, true));
    }
    float inv = 1.f / (wsum + 1e-16f);
    int c = lane * 4;
    float4 b4 = *(const float4*)&bias[c];
    float o0 = acc01.x * inv + b4.x;
    float o1 = acc01.y * inv + b4.y;
    float o2 = acc23.x * inv + b4.z;
    float o3 = acc23.y * inv + b4.w;
    o0 = o0 > 0.f ? o0 : __expf(o0) - 1.f;
    o1 = o1 > 0.f ? o1 : __expf(o1) - 1.f;
    o2 = o2 > 0.f ? o2 : __expf(o2) - 1.f;
    o3 = o3 > 0.f ? o3 : __expf(o3) - 1.f;
    if (LAYER == 1) {
        ushort4 o;
        o.x = f2bf(o0); o.y = f2bf(o1); o.z = f2bf(o2); o.w = f2bf(o3);
        ((ushort4*)out_bf)[(long long)i * 64 + lane] = o;
    } else {
        float4 fw = *(const float4*)&fc_w[c];
        float dot = o0 * fw.x + o1 * fw.y + o2 * fw.z + o3 * fw.w;
#pragma unroll
        for (int off = 32; off; off >>= 1) dot += __shfl_down(dot, off, 64);
        if (lane == 0) final_out[i] = 1.f / (1.f + __expf(-(dot + fc_b[0])));
    }
}

// ---------------- launch ----------------
extern "C" void kernel_launch(void* const* d_in, const int* in_sizes, int n_in,
                              void* d_out, int out_size, void* d_ws, size_t ws_size,
                              hipStream_t stream) {
    const float* x   = (const float*)d_in[0];
    const unsigned* ei = (const unsigned*)d_in[1];
    const float* W1  = (const float*)d_in[2];
    const float* as1 = (const float*)d_in[3];
    const float* ad1 = (const float*)d_in[4];
    const float* b1  = (const float*)d_in[5];
    const float* W2  = (const float*)d_in[6];
    const float* as2 = (const float*)d_in[7];
    const float* ad2 = (const float*)d_in[8];
    const float* b2  = (const float*)d_in[9];
    const float* fcw = (const float*)d_in[10];
    const float* fcb = (const float*)d_in[11];

    char* ws = (char*)d_ws;
    void* g1f8       = (void*)(ws + 0);               // 50000*256 fp8 = 12.8 MB
    void* g2f8       = (void*)(ws + 12800000);        // 12.8 MB (fp8, layer2)
    ushort_t* hactbf = (ushort_t*)(ws + 25600000);    // 25.6 MB
    ushort_t* xbf    = (ushort_t*)(ws + 51200000);    // 12.8 MB
    ushort_t* W1t    = (ushort_t*)(ws + 64000000);
    ushort_t* W2t    = (ushort_t*)(ws + 64100000);
    float* asv       = (float*)(ws + 64300000);
    float* adv       = (float*)(ws + 65100000);
    int* row_ptr     = (int*)(ws + 65900000);
    int* deg         = (int*)(ws + 66100016);
    int* cursor      = (int*)(ws + 66300016);
    int* src_csr     = (int*)(ws + 66500016);
    int* dst_csr     = (int*)(ws + 69700016);
    float* w_csr     = (float*)(ws + 72900032);       // 12.8 MB
    int* bsum        = (int*)(ws + 85700048);
    int* boff        = (int*)(ws + 85701072);

    hipMemsetAsync(deg, 0, N_NODES * 4, stream);

    prep_kernel<<<CONV_BLOCKS + 128 + 256, 256, 0, stream>>>(x, xbf, W1, W1t, W2, W2t);
    hist_kernel<<<(N_EDGES + 255) / 256, 256, 0, stream>>>(ei, deg);
    scan1_kernel<<<196, 256, 0, stream>>>(deg, row_ptr, bsum);
    scan2_kernel<<<1, 256, 0, stream>>>(bsum, boff, row_ptr);
    scan3_kernel<<<196, 256, 0, stream>>>(boff, row_ptr, cursor);
    scatter_kernel<<<(N_EDGES + 255) / 256, 256, 0, stream>>>(ei, cursor, src_csr, dst_csr);

    // layer 1 (g stored fp8)
    mfma_gemm_kernel<128><<<dim3(4, (N_NODES + 63) / 64), 256, 0, stream>>>(
        xbf, W1t, g1f8, N_NODES, as1, ad1, asv, adv);
    weights_kernel<<<(N_EDGES + 255) / 256, 256, 0, stream>>>(asv, adv, src_csr, dst_csr, w_csr);
    aggregate_kernel<1><<<N_NODES / 4, 256, 0, stream>>>(g1f8, asv, adv, row_ptr, src_csr, w_csr,
                                                         b1, hactbf, nullptr, nullptr, nullptr);
    // layer 2 (g stored fp8)
    mfma_gemm_kernel<256><<<dim3(4, (N_NODES + 63) / 64), 256, 0, stream>>>(
        hactbf, W2t, g2f8, N_NODES, as2, ad2, asv, adv);
    weights_kernel<<<(N_EDGES + 255) / 256, 256, 0, stream>>>(asv, adv, src_csr, dst_csr, w_csr);
    aggregate_kernel<2><<<N_NODES / 4, 256, 0, stream>>>(g2f8, asv, adv, row_ptr, src_csr, w_csr,
                                                         b2, nullptr, fcw, fcb, (float*)d_out);
}

// Round 8
// 267.552 us; speedup vs baseline: 2.4536x; 1.0084x over previous
//
#include <hip/hip_runtime.h>
#include <hip/hip_bf16.h>

#define N_NODES 50000
#define N_EDGES 800000

typedef __attribute__((ext_vector_type(8))) short bf16x8;
typedef __attribute__((ext_vector_type(4))) float f32x4;
typedef __attribute__((ext_vector_type(2))) float f32x2;
typedef unsigned short ushort_t;

__device__ __forceinline__ float bf2f(unsigned short u) {
    union { unsigned u32; float f; } v; v.u32 = (unsigned)u << 16; return v.f;
}
__device__ __forceinline__ unsigned short f2bf(float f) {
    __hip_bfloat16 h = __float2bfloat16(f);
    return *reinterpret_cast<unsigned short*>(&h);
}
__device__ __forceinline__ f32x2 bfpair(unsigned u) {
    union { unsigned a; float f; } lo, hi;
    lo.a = u << 16;
    hi.a = u & 0xFFFF0000u;
    f32x2 r; r.x = lo.f; r.y = hi.f; return r;
}
__device__ __forceinline__ void pkfma(f32x2& d, f32x2 a, f32x2 b) {
    asm("v_pk_fma_f32 %0, %1, %2, %0" : "+v"(d) : "v"(a), "v"(b));
}
__device__ __forceinline__ void gload16(const void* src, void* lds) {
    __builtin_amdgcn_global_load_lds(
        (const __attribute__((address_space(1))) unsigned int*)src,
        (__attribute__((address_space(3))) unsigned int*)lds, 16, 0, 0);
}

// inline int64-vs-int32 layout detection (odd 32-bit words all zero -> int64)
__device__ __forceinline__ int detect_is32_block(const unsigned* __restrict__ w,
                                                 int* s_is32, int tid) {
    if (tid == 0) {
        unsigned o = 0;
#pragma unroll
        for (int k = 1; k < 32; k += 2) o |= w[k];
        *s_is32 = (o != 0u);
    }
    __syncthreads();
    return *s_is32;
}

__device__ __forceinline__ int edge_elem(const unsigned* __restrict__ w, int is32, long long idx) {
    return is32 ? (int)w[idx] : (int)w[2 * idx];
}

// ---------------- CSR build ----------------
__global__ void __launch_bounds__(256) hist_kernel(const unsigned* __restrict__ ew,
                                                   int* __restrict__ deg) {
    __shared__ int s_is32;
    int is32 = detect_is32_block(ew, &s_is32, threadIdx.x);
    int e = blockIdx.x * 256 + threadIdx.x;
    if (e >= N_EDGES) return;
    int d = edge_elem(ew, is32, (long long)N_EDGES + e);
    atomicAdd(&deg[d], 1);
}

__global__ void __launch_bounds__(256) scan1_kernel(const int* __restrict__ deg,
                                                    int* __restrict__ excl, int* __restrict__ bsum) {
    __shared__ int s[256];
    int b = blockIdx.x, t = threadIdx.x, i = b * 256 + t;
    int v = (i < N_NODES) ? deg[i] : 0;
    s[t] = v;
    __syncthreads();
    for (int off = 1; off < 256; off <<= 1) {
        int y = (t >= off) ? s[t - off] : 0;
        __syncthreads();
        s[t] += y;
        __syncthreads();
    }
    if (i < N_NODES) excl[i] = s[t] - v;
    if (t == 255) bsum[b] = s[255];
}

__global__ void __launch_bounds__(256) scan2_kernel(const int* __restrict__ bsum,
                                                    int* __restrict__ boff, int* __restrict__ row_ptr) {
    __shared__ int s[256];
    int t = threadIdx.x;
    int v = (t < 196) ? bsum[t] : 0;
    s[t] = v;
    __syncthreads();
    for (int off = 1; off < 256; off <<= 1) {
        int y = (t >= off) ? s[t - off] : 0;
        __syncthreads();
        s[t] += y;
        __syncthreads();
    }
    if (t < 196) boff[t] = s[t] - v;
    if (t == 255) row_ptr[N_NODES] = s[255];
}

__global__ void __launch_bounds__(256) scan3_kernel(const int* __restrict__ boff,
                                                    int* __restrict__ row_ptr, int* __restrict__ cursor) {
    int i = blockIdx.x * 256 + threadIdx.x;
    if (i < N_NODES) {
        int v = row_ptr[i] + boff[blockIdx.x];
        row_ptr[i] = v;
        cursor[i] = v;
    }
}

// packed scatter: one u32 per edge = src | dst<<16 (node ids < 65536)
__global__ void __launch_bounds__(256) scatter_kernel(const unsigned* __restrict__ ew,
                                                      int* __restrict__ cursor,
                                                      unsigned* __restrict__ edge_csr) {
    __shared__ int s_is32;
    int is32 = detect_is32_block(ew, &s_is32, threadIdx.x);
    int e = blockIdx.x * 256 + threadIdx.x;
    if (e >= N_EDGES) return;
    unsigned s = (unsigned)edge_elem(ew, is32, e);
    int d = edge_elem(ew, is32, (long long)N_EDGES + e);
    int pos = atomicAdd(&cursor[d], 1);
    edge_csr[pos] = s | ((unsigned)d << 16);
}

// ---------------- fused prep: x->bf16, W1^T->bf16, W2^T->bf16 ----------------
#define CONV_BLOCKS 6250   /* 50000*128/4 / 256 */
__global__ void __launch_bounds__(256) prep_kernel(const float* __restrict__ x,
                                                   ushort_t* __restrict__ xbf,
                                                   const float* __restrict__ W1,
                                                   ushort_t* __restrict__ W1t,
                                                   const float* __restrict__ W2,
                                                   ushort_t* __restrict__ W2t) {
    int b = blockIdx.x, t = threadIdx.x;
    if (b < CONV_BLOCKS) {
        int i = b * 256 + t;
        float4 v = ((const float4*)x)[i];
        ushort4 o;
        o.x = f2bf(v.x); o.y = f2bf(v.y); o.z = f2bf(v.z); o.w = f2bf(v.w);
        ((ushort4*)xbf)[i] = o;
    } else if (b < CONV_BLOCKS + 128) {
        int id = (b - CONV_BLOCKS) * 256 + t;       // id = n*128 + k
        int n = id >> 7, k = id & 127;
        W1t[id] = f2bf(W1[k * 256 + n]);
    } else {
        int id = (b - CONV_BLOCKS - 128) * 256 + t; // id = n*256 + k
        int n = id >> 8, k = id & 255;
        W2t[id] = f2bf(W2[k * 256 + n]);
    }
}

// ---------------- MFMA bf16 GEMM + fused alpha logits ----------------
// C[M,256] = A[M,K](bf16) @ Wt^T, stored as fp8 e4m3 (1B/ch).
// colblock == head; epilogue computes alpha_s/alpha_d from fp32 accs.
template <int K>
__global__ void __launch_bounds__(256) mfma_gemm_kernel(const ushort_t* __restrict__ A,
                                                        const ushort_t* __restrict__ Wt,
                                                        void* __restrict__ Cv, int M,
                                                        const float* __restrict__ a_src,
                                                        const float* __restrict__ a_dst,
                                                        float* __restrict__ alpha_s,
                                                        float* __restrict__ alpha_d) {
    constexpr int CPR = K / 8;
    constexpr int NT = K / 64;
    __shared__ ushort_t Bs[64 * K];
    __shared__ ushort_t As[2][64 * 64];
    __shared__ float ps[64][2], pd[64][2];

    int tid = threadIdx.x;
    int wave = tid >> 6, lane = tid & 63;
    int l15 = lane & 15, l4 = lane >> 4;
    int wr = wave >> 1, wc = wave & 1;
    int colblock = blockIdx.x;   // head
    int rowblock = blockIdx.y;

    for (int base = 0; base < 64 * CPR; base += 256) {
        int p = base + wave * 64 + lane;
        int row = p / CPR;
        int cs = p % CPR;
        int c = cs ^ (row & 7);
        const ushort_t* src = Wt + (long long)(colblock * 64 + row) * K + c * 8;
        void* dst = ((char*)Bs) + (base + wave * 64) * 16;
        gload16(src, dst);
    }
    {
        int r = lane >> 3, cs = lane & 7;
        int c = cs ^ r;
#pragma unroll
        for (int q = 0; q < 2; ++q) {
            int lrow = wave * 16 + q * 8;
            int grow = rowblock * 64 + lrow + r;
            if (grow >= M) grow = M - 1;
            const ushort_t* src = A + (long long)grow * K + c * 8;
            void* dst = ((char*)&As[0][0]) + lrow * 128;
            gload16(src, dst);
        }
    }
    __syncthreads();

    f32x4 acc[2][2] = {};
#pragma unroll
    for (int t = 0; t < NT; ++t) {
        if (t + 1 < NT) {
            int r = lane >> 3, cs = lane & 7;
            int c = cs ^ r;
#pragma unroll
            for (int q = 0; q < 2; ++q) {
                int lrow = wave * 16 + q * 8;
                int grow = rowblock * 64 + lrow + r;
                if (grow >= M) grow = M - 1;
                const ushort_t* src = A + (long long)grow * K + (t + 1) * 64 + c * 8;
                void* dst = ((char*)&As[(t + 1) & 1][0]) + lrow * 128;
                gload16(src, dst);
            }
        }
        const ushort_t* At = &As[t & 1][0];
#pragma unroll
        for (int w = 0; w < 2; ++w) {
            bf16x8 a[2], b[2];
#pragma unroll
            for (int mi = 0; mi < 2; ++mi) {
                int row = wr * 32 + mi * 16 + l15;
                int slot = (w * 4 + l4) ^ (l15 & 7);
                a[mi] = *(const bf16x8*)&At[row * 64 + slot * 8];
            }
#pragma unroll
            for (int ni = 0; ni < 2; ++ni) {
                int brow = wc * 32 + ni * 16 + l15;
                int slot = (t * 8 + w * 4 + l4) ^ (l15 & 7);
                b[ni] = *(const bf16x8*)&Bs[brow * CPR * 8 + slot * 8];
            }
#pragma unroll
            for (int mi = 0; mi < 2; ++mi)
#pragma unroll
                for (int ni = 0; ni < 2; ++ni)
                    acc[mi][ni] = __builtin_amdgcn_mfma_f32_16x16x32_bf16(a[mi], b[ni],
                                                                          acc[mi][ni], 0, 0, 0);
        }
        __syncthreads();
    }

    // ---- fused alpha partials: per-row dot with a_src/a_dst (this head) ----
    {
        float as0 = a_src[colblock * 64 + wc * 32 + l15];
        float as1 = a_src[colblock * 64 + wc * 32 + 16 + l15];
        float ad0 = a_dst[colblock * 64 + wc * 32 + l15];
        float ad1 = a_dst[colblock * 64 + wc * 32 + 16 + l15];
#pragma unroll
        for (int mi = 0; mi < 2; ++mi)
#pragma unroll
            for (int q = 0; q < 4; ++q) {
                float sv = acc[mi][0][q] * as0 + acc[mi][1][q] * as1;
                float dv = acc[mi][0][q] * ad0 + acc[mi][1][q] * ad1;
#pragma unroll
                for (int w = 1; w < 16; w <<= 1) {
                    sv += __shfl_xor(sv, w, 64);
                    dv += __shfl_xor(dv, w, 64);
                }
                if (l15 == 0) {
                    int row = wr * 32 + mi * 16 + l4 * 4 + q;
                    ps[row][wc] = sv;
                    pd[row][wc] = dv;
                }
            }
    }

    // ---- epilogue: repack via LDS (bf16 staging), store fp8 ----
    ushort_t* ep = ((ushort_t*)&As[0][0]) + wave * 1280;
#pragma unroll
    for (int mi = 0; mi < 2; ++mi)
#pragma unroll
        for (int ni = 0; ni < 2; ++ni)
#pragma unroll
            for (int q = 0; q < 4; ++q) {
                int row = mi * 16 + l4 * 4 + q;
                int col = ni * 16 + l15;
                ep[row * 40 + col] = f2bf(acc[mi][ni][q]);
            }
    __syncthreads();
#pragma unroll
    for (int j = 0; j < 2; ++j) {
        int p = lane * 2 + j;
        int row = p >> 2, seg = p & 3;
        uint4 v = *(const uint4*)&ep[row * 40 + seg * 8];
        int grow = rowblock * 64 + wr * 32 + row;
        int gcol = colblock * 64 + wc * 32 + seg * 8;
        if (grow < M) {
            f32x2 f01 = bfpair(v.x), f23 = bfpair(v.y);
            f32x2 f45 = bfpair(v.z), f67 = bfpair(v.w);
            int d0 = 0, d1 = 0;
            d0 = __builtin_amdgcn_cvt_pk_fp8_f32(f01.x, f01.y, d0, false);
            d0 = __builtin_amdgcn_cvt_pk_fp8_f32(f23.x, f23.y, d0, true);
            d1 = __builtin_amdgcn_cvt_pk_fp8_f32(f45.x, f45.y, d1, false);
            d1 = __builtin_amdgcn_cvt_pk_fp8_f32(f67.x, f67.y, d1, true);
            uint2 o; o.x = (unsigned)d0; o.y = (unsigned)d1;
            *(uint2*)((char*)Cv + (long long)grow * 256 + gcol) = o;
        }
    }
    if (tid < 64) {
        int ga = rowblock * 64 + tid;
        if (ga < M) {
            alpha_s[ga * 4 + colblock] = ps[tid][0] + ps[tid][1];
            alpha_d[ga * 4 + colblock] = pd[tid][0] + pd[tid][1];
        }
    }
}

// ---------------- per-edge softmax weights (all 4 heads) ----------------
__global__ void __launch_bounds__(256) weights_kernel(const float* __restrict__ alpha_s,
                                                      const float* __restrict__ alpha_d,
                                                      const unsigned* __restrict__ edge_csr,
                                                      float* __restrict__ w_csr) {
    int e = blockIdx.x * 256 + threadIdx.x;
    if (e >= N_EDGES) return;
    unsigned pk = edge_csr[e];
    int j = (int)(pk & 0xFFFFu), d = (int)(pk >> 16);
    float4 a = *(const float4*)&alpha_s[j * 4];
    float4 b = *(const float4*)&alpha_d[d * 4];
    float4 o;
    float e0 = a.x + b.x; e0 = e0 > 0.f ? e0 : 0.2f * e0; o.x = __expf(e0);
    float e1 = a.y + b.y; e1 = e1 > 0.f ? e1 : 0.2f * e1; o.y = __expf(e1);
    float e2 = a.z + b.z; e2 = e2 > 0.f ? e2 : 0.2f * e2; o.z = __expf(e2);
    float e3 = a.w + b.w; e3 = e3 > 0.f ? e3 : 0.2f * e3; o.w = __expf(e3);
    *(float4*)&w_csr[e * 4] = o;
}

// ---------------- softmax-weighted aggregation (one wave per node) ----------------
// g rows are fp8 e4m3 (256 B/row) for BOTH layers.
template <int LAYER>
__global__ void __launch_bounds__(256) aggregate_kernel(
    const void* __restrict__ gv, const float* __restrict__ alpha_s,
    const float* __restrict__ alpha_d, const int* __restrict__ row_ptr,
    const unsigned* __restrict__ edge_csr, const float* __restrict__ w_csr,
    const float* __restrict__ bias, ushort_t* __restrict__ out_bf,
    const float* __restrict__ fc_w, const float* __restrict__ fc_b,
    float* __restrict__ final_out) {
    int wave = threadIdx.x >> 6;
    int lane = threadIdx.x & 63;
    int i = blockIdx.x * 4 + wave;
    int hd = lane >> 4;
    const unsigned* g1 = (const unsigned*)gv;  // fp8 rows: 64 u32/row

    // self loop
    float e0 = alpha_s[i * 4 + hd] + alpha_d[i * 4 + hd];
    e0 = e0 > 0.f ? e0 : 0.2f * e0;
    float w0 = __expf(e0);
    f32x2 wp0; wp0.x = w0; wp0.y = w0;
    f32x2 acc01 = {0.f, 0.f}, acc23 = {0.f, 0.f};
    {
        unsigned sv = g1[((long long)i << 6) + lane];
        pkfma(acc01, wp0, __builtin_amdgcn_cvt_pk_f32_fp8(sv, false));
        pkfma(acc23, wp0, __builtin_amdgcn_cvt_pk_f32_fp8(sv, true));
    }
    float wsum = w0;

    int p = row_ptr[i], p1 = row_ptr[i + 1];
    for (; p + 8 <= p1; p += 8) {
        int j[8]; float wt[8]; unsigned hh[8];
#pragma unroll
        for (int u = 0; u < 8; ++u) j[u] = (int)(edge_csr[p + u] & 0xFFFFu);
#pragma unroll
        for (int u = 0; u < 8; ++u) wt[u] = w_csr[(p + u) * 4 + hd];
#pragma unroll
        for (int u = 0; u < 8; ++u) hh[u] = g1[((long long)j[u] << 6) + lane];
#pragma unroll
        for (int u = 0; u < 8; ++u) {
            wsum += wt[u];
            f32x2 wp; wp.x = wt[u]; wp.y = wt[u];
            pkfma(acc01, wp, __builtin_amdgcn_cvt_pk_f32_fp8(hh[u], false));
            pkfma(acc23, wp, __builtin_amdgcn_cvt_pk_f32_fp8(hh[u], true));
        }
    }
    for (; p < p1; ++p) {
        int j = (int)(edge_csr[p] & 0xFFFFu);
        float wt = w_csr[p * 4 + hd];
        unsigned hj = g1[((long long)j << 6) + lane];
        wsum += wt;
        f32x2 wp; wp.x = wt; wp.y = wt;
        pkfma(acc01, wp, __builtin_amdgcn_cvt_pk_f32_fp8(hj, false));
        pkfma(acc23, wp, __builtin_amdgcn_cvt_pk_f32_fp8(hj, true));
    }
    float inv = 1.f / (wsum + 1e-16f);
    int c = lane * 4;
    float4 b4 = *(const float4*)&bias[c];
    float o0 = acc01.x * inv + b4.x;
    float o1 = acc01.y * inv + b4.y;
    float o2 = acc23.x * inv + b4.z;
    float o3 = acc23.y * inv + b4.w;
    o0 = o0 > 0.f ? o0 : __expf(o0) - 1.f;
    o1 = o1 > 0.f ? o1 : __expf(o1) - 1.f;
    o2 = o2 > 0.f ? o2 : __expf(o2) - 1.f;
    o3 = o3 > 0.f ? o3 : __expf(o3) - 1.f;
    if (LAYER == 1) {
        ushort4 o;
        o.x = f2bf(o0); o.y = f2bf(o1); o.z = f2bf(o2); o.w = f2bf(o3);
        ((ushort4*)out_bf)[(long long)i * 64 + lane] = o;
    } else {
        float4 fw = *(const float4*)&fc_w[c];
        float dot = o0 * fw.x + o1 * fw.y + o2 * fw.z + o3 * fw.w;
#pragma unroll
        for (int off = 32; off; off >>= 1) dot += __shfl_down(dot, off, 64);
        if (lane == 0) final_out[i] = 1.f / (1.f + __expf(-(dot + fc_b[0])));
    }
}

// ---------------- launch ----------------
extern "C" void kernel_launch(void* const* d_in, const int* in_sizes, int n_in,
                              void* d_out, int out_size, void* d_ws, size_t ws_size,
                              hipStream_t stream) {
    const float* x   = (const float*)d_in[0];
    const unsigned* ei = (const unsigned*)d_in[1];
    const float* W1  = (const float*)d_in[2];
    const float* as1 = (const float*)d_in[3];
    const float* ad1 = (const float*)d_in[4];
    const float* b1  = (const float*)d_in[5];
    const float* W2  = (const float*)d_in[6];
    const float* as2 = (const float*)d_in[7];
    const float* ad2 = (const float*)d_in[8];
    const float* b2  = (const float*)d_in[9];
    const float* fcw = (const float*)d_in[10];
    const float* fcb = (const float*)d_in[11];

    char* ws = (char*)d_ws;
    void* g1f8       = (void*)(ws + 0);               // 12.8 MB (fp8)
    void* g2f8       = (void*)(ws + 12800000);        // 12.8 MB (fp8)
    ushort_t* hactbf = (ushort_t*)(ws + 25600000);    // 25.6 MB
    ushort_t* xbf    = (ushort_t*)(ws + 51200000);    // 12.8 MB
    ushort_t* W1t    = (ushort_t*)(ws + 64000000);
    ushort_t* W2t    = (ushort_t*)(ws + 64100000);
    float* asv       = (float*)(ws + 64300000);
    float* adv       = (float*)(ws + 65100000);
    int* row_ptr     = (int*)(ws + 65900000);
    int* deg         = (int*)(ws + 66100016);
    int* cursor      = (int*)(ws + 66300016);
    unsigned* edge_csr = (unsigned*)(ws + 66500016);  // 3.2 MB (packed src|dst<<16)
    float* w_csr     = (float*)(ws + 69700016);       // 12.8 MB
    int* bsum        = (int*)(ws + 82500040);
    int* boff        = (int*)(ws + 82501064);

    hipMemsetAsync(deg, 0, N_NODES * 4, stream);

    prep_kernel<<<CONV_BLOCKS + 128 + 256, 256, 0, stream>>>(x, xbf, W1, W1t, W2, W2t);
    hist_kernel<<<(N_EDGES + 255) / 256, 256, 0, stream>>>(ei, deg);
    scan1_kernel<<<196, 256, 0, stream>>>(deg, row_ptr, bsum);
    scan2_kernel<<<1, 256, 0, stream>>>(bsum, boff, row_ptr);
    scan3_kernel<<<196, 256, 0, stream>>>(boff, row_ptr, cursor);
    scatter_kernel<<<(N_EDGES + 255) / 256, 256, 0, stream>>>(ei, cursor, edge_csr);

    // layer 1 (g stored fp8)
    mfma_gemm_kernel<128><<<dim3(4, (N_NODES + 63) / 64), 256, 0, stream>>>(
        xbf, W1t, g1f8, N_NODES, as1, ad1, asv, adv);
    weights_kernel<<<(N_EDGES + 255) / 256, 256, 0, stream>>>(asv, adv, edge_csr, w_csr);
    aggregate_kernel<1><<<N_NODES / 4, 256, 0, stream>>>(g1f8, asv, adv, row_ptr, edge_csr, w_csr,
                                                         b1, hactbf, nullptr, nullptr, nullptr);
    // layer 2 (g stored fp8)
    mfma_gemm_kernel<256><<<dim3(4, (N_NODES + 63) / 64), 256, 0, stream>>>(
        hactbf, W2t, g2f8, N_NODES, as2, ad2, asv, adv);
    weights_kernel<<<(N_EDGES + 255) / 256, 256, 0, stream>>>(asv, adv, edge_csr, w_csr);
    aggregate_kernel<2><<<N_NODES / 4, 256, 0, stream>>>(g2f8, asv, adv, row_ptr, edge_csr, w_csr,
                                                         b2, nullptr, fcw, fcb, (float*)d_out);
}

// Round 9
// 196.268 us; speedup vs baseline: 3.3448x; 1.3632x over previous
//
#include <hip/hip_runtime.h>
#include <hip/hip_bf16.h>

#define N_NODES 50000
#define N_EDGES 800000
#define NCHUNK 256        // edge chunks
#define EPC 3125          // edges per chunk (= N_EDGES/NCHUNK exactly)
#define NBUCKET 196       // coarse buckets: dst>>8 (50000/256 -> 196)
#define SCAN_N 50176      // NBUCKET*NCHUNK
#define SCAN_BLOCKS 196   // SCAN_N/256

typedef __attribute__((ext_vector_type(8))) short bf16x8;
typedef __attribute__((ext_vector_type(4))) float f32x4;
typedef __attribute__((ext_vector_type(2))) float f32x2;
typedef unsigned short ushort_t;

__device__ __forceinline__ float bf2f(unsigned short u) {
    union { unsigned u32; float f; } v; v.u32 = (unsigned)u << 16; return v.f;
}
__device__ __forceinline__ unsigned short f2bf(float f) {
    __hip_bfloat16 h = __float2bfloat16(f);
    return *reinterpret_cast<unsigned short*>(&h);
}
__device__ __forceinline__ f32x2 bfpair(unsigned u) {
    union { unsigned a; float f; } lo, hi;
    lo.a = u << 16;
    hi.a = u & 0xFFFF0000u;
    f32x2 r; r.x = lo.f; r.y = hi.f; return r;
}
__device__ __forceinline__ void pkfma(f32x2& d, f32x2 a, f32x2 b) {
    asm("v_pk_fma_f32 %0, %1, %2, %0" : "+v"(d) : "v"(a), "v"(b));
}
__device__ __forceinline__ void gload16(const void* src, void* lds) {
    __builtin_amdgcn_global_load_lds(
        (const __attribute__((address_space(1))) unsigned int*)src,
        (__attribute__((address_space(3))) unsigned int*)lds, 16, 0, 0);
}

// inline int64-vs-int32 layout detection (odd 32-bit words all zero -> int64)
__device__ __forceinline__ int detect_is32_block(const unsigned* __restrict__ w,
                                                 int* s_is32, int tid) {
    if (tid == 0) {
        unsigned o = 0;
#pragma unroll
        for (int k = 1; k < 32; k += 2) o |= w[k];
        *s_is32 = (o != 0u);
    }
    __syncthreads();
    return *s_is32;
}

__device__ __forceinline__ int edge_elem(const unsigned* __restrict__ w, int is32, long long idx) {
    return is32 ? (int)w[idx] : (int)w[2 * idx];
}

// ---------------- S1: per-chunk coarse-bucket histogram (bucket-major out) ----------------
__global__ void __launch_bounds__(256) bucket_hist_kernel(const unsigned* __restrict__ ew,
                                                          int* __restrict__ chunkHist) {
    __shared__ int s_is32;
    __shared__ int hist[NBUCKET];
    int t = threadIdx.x, b = blockIdx.x;
    int is32 = detect_is32_block(ew, &s_is32, t);
    for (int k = t; k < NBUCKET; k += 256) hist[k] = 0;
    __syncthreads();
    long long e0 = (long long)b * EPC;
    for (int k = t; k < EPC; k += 256) {
        int d = edge_elem(ew, is32, (long long)N_EDGES + e0 + k);
        atomicAdd(&hist[d >> 8], 1);
    }
    __syncthreads();
    for (int k = t; k < NBUCKET; k += 256)
        chunkHist[k * NCHUNK + b] = hist[k];
}

// ---------------- generic 3-phase exclusive scan over SCAN_N elements ----------------
__global__ void __launch_bounds__(256) scan1_kernel(const int* __restrict__ in,
                                                    int* __restrict__ excl, int* __restrict__ bsum) {
    __shared__ int s[256];
    int b = blockIdx.x, t = threadIdx.x, i = b * 256 + t;
    int v = in[i];
    s[t] = v;
    __syncthreads();
    for (int off = 1; off < 256; off <<= 1) {
        int y = (t >= off) ? s[t - off] : 0;
        __syncthreads();
        s[t] += y;
        __syncthreads();
    }
    excl[i] = s[t] - v;
    if (t == 255) bsum[b] = s[255];
}

__global__ void __launch_bounds__(256) scan2_kernel(const int* __restrict__ bsum,
                                                    int* __restrict__ boff) {
    __shared__ int s[256];
    int t = threadIdx.x;
    int v = (t < SCAN_BLOCKS) ? bsum[t] : 0;
    s[t] = v;
    __syncthreads();
    for (int off = 1; off < 256; off <<= 1) {
        int y = (t >= off) ? s[t - off] : 0;
        __syncthreads();
        s[t] += y;
        __syncthreads();
    }
    if (t < SCAN_BLOCKS) boff[t] = s[t] - v;
}

__global__ void __launch_bounds__(256) scan3_kernel(const int* __restrict__ boff,
                                                    int* __restrict__ excl) {
    int i = blockIdx.x * 256 + threadIdx.x;
    excl[i] += boff[blockIdx.x];
}

// ---------------- S3: scatter edges into bucket-sorted order (private runs) ----------------
__global__ void __launch_bounds__(256) bucket_scatter_kernel(const unsigned* __restrict__ ew,
                                                             const int* __restrict__ chunkOff,
                                                             unsigned* __restrict__ ebuf) {
    __shared__ int s_is32;
    __shared__ int cur[NBUCKET];
    int t = threadIdx.x, b = blockIdx.x;
    int is32 = detect_is32_block(ew, &s_is32, t);
    for (int k = t; k < NBUCKET; k += 256) cur[k] = chunkOff[k * NCHUNK + b];
    __syncthreads();
    long long e0 = (long long)b * EPC;
    for (int k = t; k < EPC; k += 256) {
        long long e = e0 + k;
        unsigned s = (unsigned)edge_elem(ew, is32, e);
        int d = edge_elem(ew, is32, (long long)N_EDGES + e);
        int pos = atomicAdd(&cur[d >> 8], 1);
        ebuf[pos] = s | ((unsigned)d << 16);
    }
}

// ---------------- S4: exact per-dst sort within bucket + row_ptr ----------------
__global__ void __launch_bounds__(256) bucket_sort_kernel(const unsigned* __restrict__ ebuf,
                                                          const int* __restrict__ chunkOff,
                                                          unsigned* __restrict__ edge_csr,
                                                          int* __restrict__ row_ptr) {
    __shared__ int cnt[256];
    __shared__ int s[256];
    int b = blockIdx.x, t = threadIdx.x;
    int start = chunkOff[b * NCHUNK];
    int end = (b + 1 < NBUCKET) ? chunkOff[(b + 1) * NCHUNK] : N_EDGES;
    cnt[t] = 0;
    __syncthreads();
    for (int e = start + t; e < end; e += 256) {
        int d = (int)(ebuf[e] >> 16);
        atomicAdd(&cnt[d & 255], 1);
    }
    __syncthreads();
    s[t] = cnt[t];
    __syncthreads();
    for (int off = 1; off < 256; off <<= 1) {
        int y = (t >= off) ? s[t - off] : 0;
        __syncthreads();
        s[t] += y;
        __syncthreads();
    }
    int excl = s[t] - cnt[t];
    int node = b * 256 + t;
    if (node <= N_NODES) row_ptr[node] = start + excl;  // node==N_NODES at b=195,t=80
    cnt[t] = start + excl;  // becomes cursor
    __syncthreads();
    for (int e = start + t; e < end; e += 256) {
        unsigned pk = ebuf[e];
        int pos = atomicAdd(&cnt[(pk >> 16) & 255], 1);
        edge_csr[pos] = pk;
    }
}

// ---------------- fused prep: x->bf16, W1^T->bf16, W2^T->bf16 ----------------
#define CONV_BLOCKS 6250   /* 50000*128/4 / 256 */
__global__ void __launch_bounds__(256) prep_kernel(const float* __restrict__ x,
                                                   ushort_t* __restrict__ xbf,
                                                   const float* __restrict__ W1,
                                                   ushort_t* __restrict__ W1t,
                                                   const float* __restrict__ W2,
                                                   ushort_t* __restrict__ W2t) {
    int b = blockIdx.x, t = threadIdx.x;
    if (b < CONV_BLOCKS) {
        int i = b * 256 + t;
        float4 v = ((const float4*)x)[i];
        ushort4 o;
        o.x = f2bf(v.x); o.y = f2bf(v.y); o.z = f2bf(v.z); o.w = f2bf(v.w);
        ((ushort4*)xbf)[i] = o;
    } else if (b < CONV_BLOCKS + 128) {
        int id = (b - CONV_BLOCKS) * 256 + t;       // id = n*128 + k
        int n = id >> 7, k = id & 127;
        W1t[id] = f2bf(W1[k * 256 + n]);
    } else {
        int id = (b - CONV_BLOCKS - 128) * 256 + t; // id = n*256 + k
        int n = id >> 8, k = id & 255;
        W2t[id] = f2bf(W2[k * 256 + n]);
    }
}

// ---------------- MFMA bf16 GEMM + fused alpha logits ----------------
// C[M,256] = A[M,K](bf16) @ Wt^T, stored as fp8 e4m3 (1B/ch).
// colblock == head; epilogue computes alpha_s/alpha_d from fp32 accs.
template <int K>
__global__ void __launch_bounds__(256) mfma_gemm_kernel(const ushort_t* __restrict__ A,
                                                        const ushort_t* __restrict__ Wt,
                                                        void* __restrict__ Cv, int M,
                                                        const float* __restrict__ a_src,
                                                        const float* __restrict__ a_dst,
                                                        float* __restrict__ alpha_s,
                                                        float* __restrict__ alpha_d) {
    constexpr int CPR = K / 8;
    constexpr int NT = K / 64;
    __shared__ ushort_t Bs[64 * K];
    __shared__ ushort_t As[2][64 * 64];
    __shared__ float ps[64][2], pd[64][2];

    int tid = threadIdx.x;
    int wave = tid >> 6, lane = tid & 63;
    int l15 = lane & 15, l4 = lane >> 4;
    int wr = wave >> 1, wc = wave & 1;
    int colblock = blockIdx.x;   // head
    int rowblock = blockIdx.y;

    for (int base = 0; base < 64 * CPR; base += 256) {
        int p = base + wave * 64 + lane;
        int row = p / CPR;
        int cs = p % CPR;
        int c = cs ^ (row & 7);
        const ushort_t* src = Wt + (long long)(colblock * 64 + row) * K + c * 8;
        void* dst = ((char*)Bs) + (base + wave * 64) * 16;
        gload16(src, dst);
    }
    {
        int r = lane >> 3, cs = lane & 7;
        int c = cs ^ r;
#pragma unroll
        for (int q = 0; q < 2; ++q) {
            int lrow = wave * 16 + q * 8;
            int grow = rowblock * 64 + lrow + r;
            if (grow >= M) grow = M - 1;
            const ushort_t* src = A + (long long)grow * K + c * 8;
            void* dst = ((char*)&As[0][0]) + lrow * 128;
            gload16(src, dst);
        }
    }
    __syncthreads();

    f32x4 acc[2][2] = {};
#pragma unroll
    for (int t = 0; t < NT; ++t) {
        if (t + 1 < NT) {
            int r = lane >> 3, cs = lane & 7;
            int c = cs ^ r;
#pragma unroll
            for (int q = 0; q < 2; ++q) {
                int lrow = wave * 16 + q * 8;
                int grow = rowblock * 64 + lrow + r;
                if (grow >= M) grow = M - 1;
                const ushort_t* src = A + (long long)grow * K + (t + 1) * 64 + c * 8;
                void* dst = ((char*)&As[(t + 1) & 1][0]) + lrow * 128;
                gload16(src, dst);
            }
        }
        const ushort_t* At = &As[t & 1][0];
#pragma unroll
        for (int w = 0; w < 2; ++w) {
            bf16x8 a[2], b[2];
#pragma unroll
            for (int mi = 0; mi < 2; ++mi) {
                int row = wr * 32 + mi * 16 + l15;
                int slot = (w * 4 + l4) ^ (l15 & 7);
                a[mi] = *(const bf16x8*)&At[row * 64 + slot * 8];
            }
#pragma unroll
            for (int ni = 0; ni < 2; ++ni) {
                int brow = wc * 32 + ni * 16 + l15;
                int slot = (t * 8 + w * 4 + l4) ^ (l15 & 7);
                b[ni] = *(const bf16x8*)&Bs[brow * CPR * 8 + slot * 8];
            }
#pragma unroll
            for (int mi = 0; mi < 2; ++mi)
#pragma unroll
                for (int ni = 0; ni < 2; ++ni)
                    acc[mi][ni] = __builtin_amdgcn_mfma_f32_16x16x32_bf16(a[mi], b[ni],
                                                                          acc[mi][ni], 0, 0, 0);
        }
        __syncthreads();
    }

    // ---- fused alpha partials: per-row dot with a_src/a_dst (this head) ----
    {
        float as0 = a_src[colblock * 64 + wc * 32 + l15];
        float as1 = a_src[colblock * 64 + wc * 32 + 16 + l15];
        float ad0 = a_dst[colblock * 64 + wc * 32 + l15];
        float ad1 = a_dst[colblock * 64 + wc * 32 + 16 + l15];
#pragma unroll
        for (int mi = 0; mi < 2; ++mi)
#pragma unroll
            for (int q = 0; q < 4; ++q) {
                float sv = acc[mi][0][q] * as0 + acc[mi][1][q] * as1;
                float dv = acc[mi][0][q] * ad0 + acc[mi][1][q] * ad1;
#pragma unroll
                for (int w = 1; w < 16; w <<= 1) {
                    sv += __shfl_xor(sv, w, 64);
                    dv += __shfl_xor(dv, w, 64);
                }
                if (l15 == 0) {
                    int row = wr * 32 + mi * 16 + l4 * 4 + q;
                    ps[row][wc] = sv;
                    pd[row][wc] = dv;
                }
            }
    }

    // ---- epilogue: repack via LDS (bf16 staging), store fp8 ----
    ushort_t* ep = ((ushort_t*)&As[0][0]) + wave * 1280;
#pragma unroll
    for (int mi = 0; mi < 2; ++mi)
#pragma unroll
        for (int ni = 0; ni < 2; ++ni)
#pragma unroll
            for (int q = 0; q < 4; ++q) {
                int row = mi * 16 + l4 * 4 + q;
                int col = ni * 16 + l15;
                ep[row * 40 + col] = f2bf(acc[mi][ni][q]);
            }
    __syncthreads();
#pragma unroll
    for (int j = 0; j < 2; ++j) {
        int p = lane * 2 + j;
        int row = p >> 2, seg = p & 3;
        uint4 v = *(const uint4*)&ep[row * 40 + seg * 8];
        int grow = rowblock * 64 + wr * 32 + row;
        int gcol = colblock * 64 + wc * 32 + seg * 8;
        if (grow < M) {
            f32x2 f01 = bfpair(v.x), f23 = bfpair(v.y);
            f32x2 f45 = bfpair(v.z), f67 = bfpair(v.w);
            int d0 = 0, d1 = 0;
            d0 = __builtin_amdgcn_cvt_pk_fp8_f32(f01.x, f01.y, d0, false);
            d0 = __builtin_amdgcn_cvt_pk_fp8_f32(f23.x, f23.y, d0, true);
            d1 = __builtin_amdgcn_cvt_pk_fp8_f32(f45.x, f45.y, d1, false);
            d1 = __builtin_amdgcn_cvt_pk_fp8_f32(f67.x, f67.y, d1, true);
            uint2 o; o.x = (unsigned)d0; o.y = (unsigned)d1;
            *(uint2*)((char*)Cv + (long long)grow * 256 + gcol) = o;
        }
    }
    if (tid < 64) {
        int ga = rowblock * 64 + tid;
        if (ga < M) {
            alpha_s[ga * 4 + colblock] = ps[tid][0] + ps[tid][1];
            alpha_d[ga * 4 + colblock] = pd[tid][0] + pd[tid][1];
        }
    }
}

// ---------------- per-edge softmax weights (all 4 heads) ----------------
__global__ void __launch_bounds__(256) weights_kernel(const float* __restrict__ alpha_s,
                                                      const float* __restrict__ alpha_d,
                                                      const unsigned* __restrict__ edge_csr,
                                                      float* __restrict__ w_csr) {
    int e = blockIdx.x * 256 + threadIdx.x;
    if (e >= N_EDGES) return;
    unsigned pk = edge_csr[e];
    int j = (int)(pk & 0xFFFFu), d = (int)(pk >> 16);
    float4 a = *(const float4*)&alpha_s[j * 4];
    float4 b = *(const float4*)&alpha_d[d * 4];
    float4 o;
    float e0 = a.x + b.x; e0 = e0 > 0.f ? e0 : 0.2f * e0; o.x = __expf(e0);
    float e1 = a.y + b.y; e1 = e1 > 0.f ? e1 : 0.2f * e1; o.y = __expf(e1);
    float e2 = a.z + b.z; e2 = e2 > 0.f ? e2 : 0.2f * e2; o.z = __expf(e2);
    float e3 = a.w + b.w; e3 = e3 > 0.f ? e3 : 0.2f * e3; o.w = __expf(e3);
    *(float4*)&w_csr[e * 4] = o;
}

// ---------------- softmax-weighted aggregation (one wave per node) ----------------
// g rows are fp8 e4m3 (256 B/row) for BOTH layers.
template <int LAYER>
__global__ void __launch_bounds__(256) aggregate_kernel(
    const void* __restrict__ gv, const float* __restrict__ alpha_s,
    const float* __restrict__ alpha_d, const int* __restrict__ row_ptr,
    const unsigned* __restrict__ edge_csr, const float* __restrict__ w_csr,
    const float* __restrict__ bias, ushort_t* __restrict__ out_bf,
    const float* __restrict__ fc_w, const float* __restrict__ fc_b,
    float* __restrict__ final_out) {
    int wave = threadIdx.x >> 6;
    int lane = threadIdx.x & 63;
    int i = blockIdx.x * 4 + wave;
    int hd = lane >> 4;
    const unsigned* g1 = (const unsigned*)gv;  // fp8 rows: 64 u32/row

    // self loop
    float e0 = alpha_s[i * 4 + hd] + alpha_d[i * 4 + hd];
    e0 = e0 > 0.f ? e0 : 0.2f * e0;
    float w0 = __expf(e0);
    f32x2 wp0; wp0.x = w0; wp0.y = w0;
    f32x2 acc01 = {0.f, 0.f}, acc23 = {0.f, 0.f};
    {
        unsigned sv = g1[((long long)i << 6) + lane];
        pkfma(acc01, wp0, __builtin_amdgcn_cvt_pk_f32_fp8(sv, false));
        pkfma(acc23, wp0, __builtin_amdgcn_cvt_pk_f32_fp8(sv, true));
    }
    float wsum = w0;

    int p = row_ptr[i], p1 = row_ptr[i + 1];
    for (; p + 8 <= p1; p += 8) {
        int j[8]; float wt[8]; unsigned hh[8];
#pragma unroll
        for (int u = 0; u < 8; ++u) j[u] = (int)(edge_csr[p + u] & 0xFFFFu);
#pragma unroll
        for (int u = 0; u < 8; ++u) wt[u] = w_csr[(p + u) * 4 + hd];
#pragma unroll
        for (int u = 0; u < 8; ++u) hh[u] = g1[((long long)j[u] << 6) + lane];
#pragma unroll
        for (int u = 0; u < 8; ++u) {
            wsum += wt[u];
            f32x2 wp; wp.x = wt[u]; wp.y = wt[u];
            pkfma(acc01, wp, __builtin_amdgcn_cvt_pk_f32_fp8(hh[u], false));
            pkfma(acc23, wp, __builtin_amdgcn_cvt_pk_f32_fp8(hh[u], true));
        }
    }
    for (; p < p1; ++p) {
        int j = (int)(edge_csr[p] & 0xFFFFu);
        float wt = w_csr[p * 4 + hd];
        unsigned hj = g1[((long long)j << 6) + lane];
        wsum += wt;
        f32x2 wp; wp.x = wt; wp.y = wt;
        pkfma(acc01, wp, __builtin_amdgcn_cvt_pk_f32_fp8(hj, false));
        pkfma(acc23, wp, __builtin_amdgcn_cvt_pk_f32_fp8(hj, true));
    }
    float inv = 1.f / (wsum + 1e-16f);
    int c = lane * 4;
    float4 b4 = *(const float4*)&bias[c];
    float o0 = acc01.x * inv + b4.x;
    float o1 = acc01.y * inv + b4.y;
    float o2 = acc23.x * inv + b4.z;
    float o3 = acc23.y * inv + b4.w;
    o0 = o0 > 0.f ? o0 : __expf(o0) - 1.f;
    o1 = o1 > 0.f ? o1 : __expf(o1) - 1.f;
    o2 = o2 > 0.f ? o2 : __expf(o2) - 1.f;
    o3 = o3 > 0.f ? o3 : __expf(o3) - 1.f;
    if (LAYER == 1) {
        ushort4 o;
        o.x = f2bf(o0); o.y = f2bf(o1); o.z = f2bf(o2); o.w = f2bf(o3);
        ((ushort4*)out_bf)[(long long)i * 64 + lane] = o;
    } else {
        float4 fw = *(const float4*)&fc_w[c];
        float dot = o0 * fw.x + o1 * fw.y + o2 * fw.z + o3 * fw.w;
#pragma unroll
        for (int off = 32; off; off >>= 1) dot += __shfl_down(dot, off, 64);
        if (lane == 0) final_out[i] = 1.f / (1.f + __expf(-(dot + fc_b[0])));
    }
}

// ---------------- launch ----------------
extern "C" void kernel_launch(void* const* d_in, const int* in_sizes, int n_in,
                              void* d_out, int out_size, void* d_ws, size_t ws_size,
                              hipStream_t stream) {
    const float* x   = (const float*)d_in[0];
    const unsigned* ei = (const unsigned*)d_in[1];
    const float* W1  = (const float*)d_in[2];
    const float* as1 = (const float*)d_in[3];
    const float* ad1 = (const float*)d_in[4];
    const float* b1  = (const float*)d_in[5];
    const float* W2  = (const float*)d_in[6];
    const float* as2 = (const float*)d_in[7];
    const float* ad2 = (const float*)d_in[8];
    const float* b2  = (const float*)d_in[9];
    const float* fcw = (const float*)d_in[10];
    const float* fcb = (const float*)d_in[11];

    char* ws = (char*)d_ws;
    void* g1f8         = (void*)(ws + 0);               // 12.8 MB (fp8)
    void* g2f8         = (void*)(ws + 12800000);        // 12.8 MB (fp8)
    ushort_t* hactbf   = (ushort_t*)(ws + 25600000);    // 25.6 MB
    ushort_t* xbf      = (ushort_t*)(ws + 51200000);    // 12.8 MB
    ushort_t* W1t      = (ushort_t*)(ws + 64000000);
    ushort_t* W2t      = (ushort_t*)(ws + 64100000);
    float* asv         = (float*)(ws + 64300000);
    float* adv         = (float*)(ws + 65100000);
    int* row_ptr       = (int*)(ws + 65900000);         // 50001 ints
    int* chunkHist     = (int*)(ws + 66110000);         // 50176 ints
    int* chunkOff      = (int*)(ws + 66320000);         // 50176 ints
    unsigned* ebuf     = (unsigned*)(ws + 66530000);    // 3.2 MB (bucket-sorted)
    unsigned* edge_csr = (unsigned*)(ws + 69730000);    // 3.2 MB (exact CSR)
    float* w_csr       = (float*)(ws + 72930000);       // 12.8 MB
    int* bsum          = (int*)(ws + 85730000);         // 196 ints
    int* boff          = (int*)(ws + 85731024);         // 196 ints

    prep_kernel<<<CONV_BLOCKS + 128 + 256, 256, 0, stream>>>(x, xbf, W1, W1t, W2, W2t);

    // CSR build via two-level counting sort (no device-wide atomics, dense writes)
    bucket_hist_kernel<<<NCHUNK, 256, 0, stream>>>(ei, chunkHist);
    scan1_kernel<<<SCAN_BLOCKS, 256, 0, stream>>>(chunkHist, chunkOff, bsum);
    scan2_kernel<<<1, 256, 0, stream>>>(bsum, boff);
    scan3_kernel<<<SCAN_BLOCKS, 256, 0, stream>>>(boff, chunkOff);
    bucket_scatter_kernel<<<NCHUNK, 256, 0, stream>>>(ei, chunkOff, ebuf);
    bucket_sort_kernel<<<NBUCKET, 256, 0, stream>>>(ebuf, chunkOff, edge_csr, row_ptr);

    // layer 1 (g stored fp8)
    mfma_gemm_kernel<128><<<dim3(4, (N_NODES + 63) / 64), 256, 0, stream>>>(
        xbf, W1t, g1f8, N_NODES, as1, ad1, asv, adv);
    weights_kernel<<<(N_EDGES + 255) / 256, 256, 0, stream>>>(asv, adv, edge_csr, w_csr);
    aggregate_kernel<1><<<N_NODES / 4, 256, 0, stream>>>(g1f8, asv, adv, row_ptr, edge_csr, w_csr,
                                                         b1, hactbf, nullptr, nullptr, nullptr);
    // layer 2 (g stored fp8)
    mfma_gemm_kernel<256><<<dim3(4, (N_NODES + 63) / 64), 256, 0, stream>>>(
        hactbf, W2t, g2f8, N_NODES, as2, ad2, asv, adv);
    weights_kernel<<<(N_EDGES + 255) / 256, 256, 0, stream>>>(asv, adv, edge_csr, w_csr);
    aggregate_kernel<2><<<N_NODES / 4, 256, 0, stream>>>(g2f8, asv, adv, row_ptr, edge_csr, w_csr,
                                                         b2, nullptr, fcw, fcb, (float*)d_out);
}

// Round 10
// 187.378 us; speedup vs baseline: 3.5035x; 1.0474x over previous
//
#include <hip/hip_runtime.h>
#include <hip/hip_bf16.h>

#define N_NODES 50000
#define N_EDGES 800000
#define NCHUNK 256        // edge chunks
#define EPC 3125          // edges per chunk (= N_EDGES/NCHUNK exactly)
#define NBUCKET 196       // coarse buckets: dst>>8 (50000/256 -> 196)
#define SCAN_N 50176      // NBUCKET*NCHUNK
#define SCAN_BLOCKS 196   // SCAN_N/256

typedef __attribute__((ext_vector_type(8))) short bf16x8;
typedef __attribute__((ext_vector_type(4))) float f32x4;
typedef __attribute__((ext_vector_type(2))) float f32x2;
typedef unsigned short ushort_t;

__device__ __forceinline__ float bf2f(unsigned short u) {
    union { unsigned u32; float f; } v; v.u32 = (unsigned)u << 16; return v.f;
}
__device__ __forceinline__ unsigned short f2bf(float f) {
    __hip_bfloat16 h = __float2bfloat16(f);
    return *reinterpret_cast<unsigned short*>(&h);
}
__device__ __forceinline__ f32x2 bfpair(unsigned u) {
    union { unsigned a; float f; } lo, hi;
    lo.a = u << 16;
    hi.a = u & 0xFFFF0000u;
    f32x2 r; r.x = lo.f; r.y = hi.f; return r;
}
__device__ __forceinline__ void pkfma(f32x2& d, f32x2 a, f32x2 b) {
    asm("v_pk_fma_f32 %0, %1, %2, %0" : "+v"(d) : "v"(a), "v"(b));
}
__device__ __forceinline__ void gload16(const void* src, void* lds) {
    __builtin_amdgcn_global_load_lds(
        (const __attribute__((address_space(1))) unsigned int*)src,
        (__attribute__((address_space(3))) unsigned int*)lds, 16, 0, 0);
}

// inline int64-vs-int32 layout detection (odd 32-bit words all zero -> int64)
__device__ __forceinline__ int detect_is32_block(const unsigned* __restrict__ w,
                                                 int* s_is32, int tid) {
    if (tid == 0) {
        unsigned o = 0;
#pragma unroll
        for (int k = 1; k < 32; k += 2) o |= w[k];
        *s_is32 = (o != 0u);
    }
    __syncthreads();
    return *s_is32;
}

__device__ __forceinline__ int edge_elem(const unsigned* __restrict__ w, int is32, long long idx) {
    return is32 ? (int)w[idx] : (int)w[2 * idx];
}

// ---------------- S1: per-chunk coarse-bucket histogram (bucket-major out) ----------------
__global__ void __launch_bounds__(256) bucket_hist_kernel(const unsigned* __restrict__ ew,
                                                          int* __restrict__ chunkHist) {
    __shared__ int s_is32;
    __shared__ int hist[NBUCKET];
    int t = threadIdx.x, b = blockIdx.x;
    int is32 = detect_is32_block(ew, &s_is32, t);
    for (int k = t; k < NBUCKET; k += 256) hist[k] = 0;
    __syncthreads();
    long long e0 = (long long)b * EPC;
    for (int k = t; k < EPC; k += 256) {
        int d = edge_elem(ew, is32, (long long)N_EDGES + e0 + k);
        atomicAdd(&hist[d >> 8], 1);
    }
    __syncthreads();
    for (int k = t; k < NBUCKET; k += 256)
        chunkHist[k * NCHUNK + b] = hist[k];
}

// ---------------- generic 3-phase exclusive scan over SCAN_N elements ----------------
__global__ void __launch_bounds__(256) scan1_kernel(const int* __restrict__ in,
                                                    int* __restrict__ excl, int* __restrict__ bsum) {
    __shared__ int s[256];
    int b = blockIdx.x, t = threadIdx.x, i = b * 256 + t;
    int v = in[i];
    s[t] = v;
    __syncthreads();
    for (int off = 1; off < 256; off <<= 1) {
        int y = (t >= off) ? s[t - off] : 0;
        __syncthreads();
        s[t] += y;
        __syncthreads();
    }
    excl[i] = s[t] - v;
    if (t == 255) bsum[b] = s[255];
}

__global__ void __launch_bounds__(256) scan2_kernel(const int* __restrict__ bsum,
                                                    int* __restrict__ boff) {
    __shared__ int s[256];
    int t = threadIdx.x;
    int v = (t < SCAN_BLOCKS) ? bsum[t] : 0;
    s[t] = v;
    __syncthreads();
    for (int off = 1; off < 256; off <<= 1) {
        int y = (t >= off) ? s[t - off] : 0;
        __syncthreads();
        s[t] += y;
        __syncthreads();
    }
    if (t < SCAN_BLOCKS) boff[t] = s[t] - v;
}

__global__ void __launch_bounds__(256) scan3_kernel(const int* __restrict__ boff,
                                                    int* __restrict__ excl) {
    int i = blockIdx.x * 256 + threadIdx.x;
    excl[i] += boff[blockIdx.x];
}

// ---------------- S3: scatter edges into bucket-sorted order (private runs) ----------------
__global__ void __launch_bounds__(256) bucket_scatter_kernel(const unsigned* __restrict__ ew,
                                                             const int* __restrict__ chunkOff,
                                                             unsigned* __restrict__ ebuf) {
    __shared__ int s_is32;
    __shared__ int cur[NBUCKET];
    int t = threadIdx.x, b = blockIdx.x;
    int is32 = detect_is32_block(ew, &s_is32, t);
    for (int k = t; k < NBUCKET; k += 256) cur[k] = chunkOff[k * NCHUNK + b];
    __syncthreads();
    long long e0 = (long long)b * EPC;
    for (int k = t; k < EPC; k += 256) {
        long long e = e0 + k;
        unsigned s = (unsigned)edge_elem(ew, is32, e);
        int d = edge_elem(ew, is32, (long long)N_EDGES + e);
        int pos = atomicAdd(&cur[d >> 8], 1);
        ebuf[pos] = s | ((unsigned)d << 16);
    }
}

// ---------------- S4: exact per-dst sort within bucket + row_ptr ----------------
__global__ void __launch_bounds__(256) bucket_sort_kernel(const unsigned* __restrict__ ebuf,
                                                          const int* __restrict__ chunkOff,
                                                          unsigned* __restrict__ edge_csr,
                                                          int* __restrict__ row_ptr) {
    __shared__ int cnt[256];
    __shared__ int s[256];
    int b = blockIdx.x, t = threadIdx.x;
    int start = chunkOff[b * NCHUNK];
    int end = (b + 1 < NBUCKET) ? chunkOff[(b + 1) * NCHUNK] : N_EDGES;
    cnt[t] = 0;
    __syncthreads();
    for (int e = start + t; e < end; e += 256) {
        int d = (int)(ebuf[e] >> 16);
        atomicAdd(&cnt[d & 255], 1);
    }
    __syncthreads();
    s[t] = cnt[t];
    __syncthreads();
    for (int off = 1; off < 256; off <<= 1) {
        int y = (t >= off) ? s[t - off] : 0;
        __syncthreads();
        s[t] += y;
        __syncthreads();
    }
    int excl = s[t] - cnt[t];
    int node = b * 256 + t;
    if (node <= N_NODES) row_ptr[node] = start + excl;  // node==N_NODES at b=195,t=80
    cnt[t] = start + excl;  // becomes cursor
    __syncthreads();
    for (int e = start + t; e < end; e += 256) {
        unsigned pk = ebuf[e];
        int pos = atomicAdd(&cnt[(pk >> 16) & 255], 1);
        edge_csr[pos] = pk;
    }
}

// ---------------- fused prep: x->bf16, W1^T->bf16, W2^T->bf16 ----------------
#define CONV_BLOCKS 6250   /* 50000*128/4 / 256 */
__global__ void __launch_bounds__(256) prep_kernel(const float* __restrict__ x,
                                                   ushort_t* __restrict__ xbf,
                                                   const float* __restrict__ W1,
                                                   ushort_t* __restrict__ W1t,
                                                   const float* __restrict__ W2,
                                                   ushort_t* __restrict__ W2t) {
    int b = blockIdx.x, t = threadIdx.x;
    if (b < CONV_BLOCKS) {
        int i = b * 256 + t;
        float4 v = ((const float4*)x)[i];
        ushort4 o;
        o.x = f2bf(v.x); o.y = f2bf(v.y); o.z = f2bf(v.z); o.w = f2bf(v.w);
        ((ushort4*)xbf)[i] = o;
    } else if (b < CONV_BLOCKS + 128) {
        int id = (b - CONV_BLOCKS) * 256 + t;       // id = n*128 + k
        int n = id >> 7, k = id & 127;
        W1t[id] = f2bf(W1[k * 256 + n]);
    } else {
        int id = (b - CONV_BLOCKS - 128) * 256 + t; // id = n*256 + k
        int n = id >> 8, k = id & 255;
        W2t[id] = f2bf(W2[k * 256 + n]);
    }
}

// ---------------- MFMA bf16 GEMM + fused alpha logits ----------------
// C[M,256] = A[M,K](bf16) @ Wt^T, stored as fp8 e4m3 (1B/ch).
// colblock == head; epilogue computes alpha_s/alpha_d from fp32 accs.
template <int K>
__global__ void __launch_bounds__(256) mfma_gemm_kernel(const ushort_t* __restrict__ A,
                                                        const ushort_t* __restrict__ Wt,
                                                        void* __restrict__ Cv, int M,
                                                        const float* __restrict__ a_src,
                                                        const float* __restrict__ a_dst,
                                                        float* __restrict__ alpha_s,
                                                        float* __restrict__ alpha_d) {
    constexpr int CPR = K / 8;
    constexpr int NT = K / 64;
    __shared__ ushort_t Bs[64 * K];
    __shared__ ushort_t As[2][64 * 64];
    __shared__ float ps[64][2], pd[64][2];

    int tid = threadIdx.x;
    int wave = tid >> 6, lane = tid & 63;
    int l15 = lane & 15, l4 = lane >> 4;
    int wr = wave >> 1, wc = wave & 1;
    int colblock = blockIdx.x;   // head
    int rowblock = blockIdx.y;

    for (int base = 0; base < 64 * CPR; base += 256) {
        int p = base + wave * 64 + lane;
        int row = p / CPR;
        int cs = p % CPR;
        int c = cs ^ (row & 7);
        const ushort_t* src = Wt + (long long)(colblock * 64 + row) * K + c * 8;
        void* dst = ((char*)Bs) + (base + wave * 64) * 16;
        gload16(src, dst);
    }
    {
        int r = lane >> 3, cs = lane & 7;
        int c = cs ^ r;
#pragma unroll
        for (int q = 0; q < 2; ++q) {
            int lrow = wave * 16 + q * 8;
            int grow = rowblock * 64 + lrow + r;
            if (grow >= M) grow = M - 1;
            const ushort_t* src = A + (long long)grow * K + c * 8;
            void* dst = ((char*)&As[0][0]) + lrow * 128;
            gload16(src, dst);
        }
    }
    __syncthreads();

    f32x4 acc[2][2] = {};
#pragma unroll
    for (int t = 0; t < NT; ++t) {
        if (t + 1 < NT) {
            int r = lane >> 3, cs = lane & 7;
            int c = cs ^ r;
#pragma unroll
            for (int q = 0; q < 2; ++q) {
                int lrow = wave * 16 + q * 8;
                int grow = rowblock * 64 + lrow + r;
                if (grow >= M) grow = M - 1;
                const ushort_t* src = A + (long long)grow * K + (t + 1) * 64 + c * 8;
                void* dst = ((char*)&As[(t + 1) & 1][0]) + lrow * 128;
                gload16(src, dst);
            }
        }
        const ushort_t* At = &As[t & 1][0];
#pragma unroll
        for (int w = 0; w < 2; ++w) {
            bf16x8 a[2], b[2];
#pragma unroll
            for (int mi = 0; mi < 2; ++mi) {
                int row = wr * 32 + mi * 16 + l15;
                int slot = (w * 4 + l4) ^ (l15 & 7);
                a[mi] = *(const bf16x8*)&At[row * 64 + slot * 8];
            }
#pragma unroll
            for (int ni = 0; ni < 2; ++ni) {
                int brow = wc * 32 + ni * 16 + l15;
                int slot = (t * 8 + w * 4 + l4) ^ (l15 & 7);
                b[ni] = *(const bf16x8*)&Bs[brow * CPR * 8 + slot * 8];
            }
#pragma unroll
            for (int mi = 0; mi < 2; ++mi)
#pragma unroll
                for (int ni = 0; ni < 2; ++ni)
                    acc[mi][ni] = __builtin_amdgcn_mfma_f32_16x16x32_bf16(a[mi], b[ni],
                                                                          acc[mi][ni], 0, 0, 0);
        }
        __syncthreads();
    }

    // ---- fused alpha partials: per-row dot with a_src/a_dst (this head) ----
    {
        float as0 = a_src[colblock * 64 + wc * 32 + l15];
        float as1 = a_src[colblock * 64 + wc * 32 + 16 + l15];
        float ad0 = a_dst[colblock * 64 + wc * 32 + l15];
        float ad1 = a_dst[colblock * 64 + wc * 32 + 16 + l15];
#pragma unroll
        for (int mi = 0; mi < 2; ++mi)
#pragma unroll
            for (int q = 0; q < 4; ++q) {
                float sv = acc[mi][0][q] * as0 + acc[mi][1][q] * as1;
                float dv = acc[mi][0][q] * ad0 + acc[mi][1][q] * ad1;
#pragma unroll
                for (int w = 1; w < 16; w <<= 1) {
                    sv += __shfl_xor(sv, w, 64);
                    dv += __shfl_xor(dv, w, 64);
                }
                if (l15 == 0) {
                    int row = wr * 32 + mi * 16 + l4 * 4 + q;
                    ps[row][wc] = sv;
                    pd[row][wc] = dv;
                }
            }
    }

    // ---- epilogue: repack via LDS (bf16 staging), store fp8 ----
    ushort_t* ep = ((ushort_t*)&As[0][0]) + wave * 1280;
#pragma unroll
    for (int mi = 0; mi < 2; ++mi)
#pragma unroll
        for (int ni = 0; ni < 2; ++ni)
#pragma unroll
            for (int q = 0; q < 4; ++q) {
                int row = mi * 16 + l4 * 4 + q;
                int col = ni * 16 + l15;
                ep[row * 40 + col] = f2bf(acc[mi][ni][q]);
            }
    __syncthreads();
#pragma unroll
    for (int j = 0; j < 2; ++j) {
        int p = lane * 2 + j;
        int row = p >> 2, seg = p & 3;
        uint4 v = *(const uint4*)&ep[row * 40 + seg * 8];
        int grow = rowblock * 64 + wr * 32 + row;
        int gcol = colblock * 64 + wc * 32 + seg * 8;
        if (grow < M) {
            f32x2 f01 = bfpair(v.x), f23 = bfpair(v.y);
            f32x2 f45 = bfpair(v.z), f67 = bfpair(v.w);
            int d0 = 0, d1 = 0;
            d0 = __builtin_amdgcn_cvt_pk_fp8_f32(f01.x, f01.y, d0, false);
            d0 = __builtin_amdgcn_cvt_pk_fp8_f32(f23.x, f23.y, d0, true);
            d1 = __builtin_amdgcn_cvt_pk_fp8_f32(f45.x, f45.y, d1, false);
            d1 = __builtin_amdgcn_cvt_pk_fp8_f32(f67.x, f67.y, d1, true);
            uint2 o; o.x = (unsigned)d0; o.y = (unsigned)d1;
            *(uint2*)((char*)Cv + (long long)grow * 256 + gcol) = o;
        }
    }
    if (tid < 64) {
        int ga = rowblock * 64 + tid;
        if (ga < M) {
            alpha_s[ga * 4 + colblock] = ps[tid][0] + ps[tid][1];
            alpha_d[ga * 4 + colblock] = pd[tid][0] + pd[tid][1];
        }
    }
}

// ---------------- softmax-weighted aggregation (one wave per node) ----------------
// g rows are fp8 e4m3 (256 B/row). Edge weights computed inline:
// w = exp(leaky(alpha_s[j] + alpha_d[i])), alpha_d[i] loop-invariant.
template <int LAYER>
__global__ void __launch_bounds__(256) aggregate_kernel(
    const void* __restrict__ gv, const float* __restrict__ alpha_s,
    const float* __restrict__ alpha_d, const int* __restrict__ row_ptr,
    const unsigned* __restrict__ edge_csr,
    const float* __restrict__ bias, ushort_t* __restrict__ out_bf,
    const float* __restrict__ fc_w, const float* __restrict__ fc_b,
    float* __restrict__ final_out) {
    int wave = threadIdx.x >> 6;
    int lane = threadIdx.x & 63;
    int i = blockIdx.x * 4 + wave;
    int hd = lane >> 4;
    const char* gb = (const char*)gv;           // fp8 rows: 256 B/row
    unsigned loff = (unsigned)(lane << 2);

    float ad = alpha_d[i * 4 + hd];
    // self loop
    float e0 = alpha_s[i * 4 + hd] + ad;
    e0 = e0 > 0.f ? e0 : 0.2f * e0;
    float w0 = __expf(e0);
    f32x2 wp0; wp0.x = w0; wp0.y = w0;
    f32x2 acc01 = {0.f, 0.f}, acc23 = {0.f, 0.f};
    {
        unsigned sv = *(const unsigned*)(gb + (((unsigned)i << 8) | loff));
        pkfma(acc01, wp0, __builtin_amdgcn_cvt_pk_f32_fp8(sv, false));
        pkfma(acc23, wp0, __builtin_amdgcn_cvt_pk_f32_fp8(sv, true));
    }
    float wsum = w0;

    int p = row_ptr[i], p1 = row_ptr[i + 1];
    for (; p + 8 <= p1; p += 8) {
        int j[8]; float as[8]; unsigned hh[8];
#pragma unroll
        for (int u = 0; u < 8; ++u) j[u] = (int)(edge_csr[p + u] & 0xFFFFu);
#pragma unroll
        for (int u = 0; u < 8; ++u) as[u] = alpha_s[j[u] * 4 + hd];
#pragma unroll
        for (int u = 0; u < 8; ++u)
            hh[u] = *(const unsigned*)(gb + (((unsigned)j[u] << 8) | loff));
#pragma unroll
        for (int u = 0; u < 8; ++u) {
            float e = as[u] + ad;
            e = e > 0.f ? e : 0.2f * e;
            float wt = __expf(e);
            wsum += wt;
            f32x2 wp; wp.x = wt; wp.y = wt;
            pkfma(acc01, wp, __builtin_amdgcn_cvt_pk_f32_fp8(hh[u], false));
            pkfma(acc23, wp, __builtin_amdgcn_cvt_pk_f32_fp8(hh[u], true));
        }
    }
    for (; p < p1; ++p) {
        int j = (int)(edge_csr[p] & 0xFFFFu);
        float e = alpha_s[j * 4 + hd] + ad;
        e = e > 0.f ? e : 0.2f * e;
        float wt = __expf(e);
        unsigned hj = *(const unsigned*)(gb + (((unsigned)j << 8) | loff));
        wsum += wt;
        f32x2 wp; wp.x = wt; wp.y = wt;
        pkfma(acc01, wp, __builtin_amdgcn_cvt_pk_f32_fp8(hj, false));
        pkfma(acc23, wp, __builtin_amdgcn_cvt_pk_f32_fp8(hj, true));
    }
    float inv = 1.f / (wsum + 1e-16f);
    int c = lane * 4;
    float4 b4 = *(const float4*)&bias[c];
    float o0 = acc01.x * inv + b4.x;
    float o1 = acc01.y * inv + b4.y;
    float o2 = acc23.x * inv + b4.z;
    float o3 = acc23.y * inv + b4.w;
    o0 = o0 > 0.f ? o0 : __expf(o0) - 1.f;
    o1 = o1 > 0.f ? o1 : __expf(o1) - 1.f;
    o2 = o2 > 0.f ? o2 : __expf(o2) - 1.f;
    o3 = o3 > 0.f ? o3 : __expf(o3) - 1.f;
    if (LAYER == 1) {
        ushort4 o;
        o.x = f2bf(o0); o.y = f2bf(o1); o.z = f2bf(o2); o.w = f2bf(o3);
        ((ushort4*)out_bf)[(long long)i * 64 + lane] = o;
    } else {
        float4 fw = *(const float4*)&fc_w[c];
        float dot = o0 * fw.x + o1 * fw.y + o2 * fw.z + o3 * fw.w;
#pragma unroll
        for (int off = 32; off; off >>= 1) dot += __shfl_down(dot, off, 64);
        if (lane == 0) final_out[i] = 1.f / (1.f + __expf(-(dot + fc_b[0])));
    }
}

// ---------------- launch ----------------
extern "C" void kernel_launch(void* const* d_in, const int* in_sizes, int n_in,
                              void* d_out, int out_size, void* d_ws, size_t ws_size,
                              hipStream_t stream) {
    const float* x   = (const float*)d_in[0];
    const unsigned* ei = (const unsigned*)d_in[1];
    const float* W1  = (const float*)d_in[2];
    const float* as1 = (const float*)d_in[3];
    const float* ad1 = (const float*)d_in[4];
    const float* b1  = (const float*)d_in[5];
    const float* W2  = (const float*)d_in[6];
    const float* as2 = (const float*)d_in[7];
    const float* ad2 = (const float*)d_in[8];
    const float* b2  = (const float*)d_in[9];
    const float* fcw = (const float*)d_in[10];
    const float* fcb = (const float*)d_in[11];

    char* ws = (char*)d_ws;
    void* g1f8         = (void*)(ws + 0);               // 12.8 MB (fp8)
    void* g2f8         = (void*)(ws + 12800000);        // 12.8 MB (fp8)
    ushort_t* hactbf   = (ushort_t*)(ws + 25600000);    // 25.6 MB
    ushort_t* xbf      = (ushort_t*)(ws + 51200000);    // 12.8 MB
    ushort_t* W1t      = (ushort_t*)(ws + 64000000);
    ushort_t* W2t      = (ushort_t*)(ws + 64100000);
    float* asv         = (float*)(ws + 64300000);
    float* adv         = (float*)(ws + 65100000);
    int* row_ptr       = (int*)(ws + 65900000);         // 50001 ints
    int* chunkHist     = (int*)(ws + 66110000);         // 50176 ints
    int* chunkOff      = (int*)(ws + 66320000);         // 50176 ints
    unsigned* ebuf     = (unsigned*)(ws + 66530000);    // 3.2 MB (bucket-sorted)
    unsigned* edge_csr = (unsigned*)(ws + 69730000);    // 3.2 MB (exact CSR)
    int* bsum          = (int*)(ws + 72930000);         // 196 ints
    int* boff          = (int*)(ws + 72931024);         // 196 ints

    prep_kernel<<<CONV_BLOCKS + 128 + 256, 256, 0, stream>>>(x, xbf, W1, W1t, W2, W2t);

    // CSR build via two-level counting sort (no device-wide atomics, dense writes)
    bucket_hist_kernel<<<NCHUNK, 256, 0, stream>>>(ei, chunkHist);
    scan1_kernel<<<SCAN_BLOCKS, 256, 0, stream>>>(chunkHist, chunkOff, bsum);
    scan2_kernel<<<1, 256, 0, stream>>>(bsum, boff);
    scan3_kernel<<<SCAN_BLOCKS, 256, 0, stream>>>(boff, chunkOff);
    bucket_scatter_kernel<<<NCHUNK, 256, 0, stream>>>(ei, chunkOff, ebuf);
    bucket_sort_kernel<<<NBUCKET, 256, 0, stream>>>(ebuf, chunkOff, edge_csr, row_ptr);

    // layer 1 (g stored fp8)
    mfma_gemm_kernel<128><<<dim3(4, (N_NODES + 63) / 64), 256, 0, stream>>>(
        xbf, W1t, g1f8, N_NODES, as1, ad1, asv, adv);
    aggregate_kernel<1><<<N_NODES / 4, 256, 0, stream>>>(g1f8, asv, adv, row_ptr, edge_csr,
                                                         b1, hactbf, nullptr, nullptr, nullptr);
    // layer 2 (g stored fp8)
    mfma_gemm_kernel<256><<<dim3(4, (N_NODES + 63) / 64), 256, 0, stream>>>(
        hactbf, W2t, g2f8, N_NODES, as2, ad2, asv, adv);
    aggregate_kernel<2><<<N_NODES / 4, 256, 0, stream>>>(g2f8, asv, adv, row_ptr, edge_csr,
                                                         b2, nullptr, fcw, fcb, (float*)d_out);
}

// Round 11
// 185.927 us; speedup vs baseline: 3.5308x; 1.0078x over previous
//
#include <hip/hip_runtime.h>
#include <hip/hip_bf16.h>

#define N_NODES 50000
#define N_EDGES 800000
#define NCHUNK 256        // edge chunks
#define EPC 3125          // edges per chunk (= N_EDGES/NCHUNK exactly)
#define NBUCKET 196       // coarse buckets: dst>>8 (50000/256 -> 196)
#define SCAN_N 50176      // NBUCKET*NCHUNK
#define SCAN_BLOCKS 196   // SCAN_N/256

typedef __attribute__((ext_vector_type(8))) short bf16x8;
typedef __attribute__((ext_vector_type(4))) float f32x4;
typedef __attribute__((ext_vector_type(2))) float f32x2;
typedef unsigned short ushort_t;

__device__ __forceinline__ float bf2f(unsigned short u) {
    union { unsigned u32; float f; } v; v.u32 = (unsigned)u << 16; return v.f;
}
__device__ __forceinline__ unsigned short f2bf(float f) {
    __hip_bfloat16 h = __float2bfloat16(f);
    return *reinterpret_cast<unsigned short*>(&h);
}
__device__ __forceinline__ f32x2 bfpair(unsigned u) {
    union { unsigned a; float f; } lo, hi;
    lo.a = u << 16;
    hi.a = u & 0xFFFF0000u;
    f32x2 r; r.x = lo.f; r.y = hi.f; return r;
}
__device__ __forceinline__ void pkfma(f32x2& d, f32x2 a, f32x2 b) {
    asm("v_pk_fma_f32 %0, %1, %2, %0" : "+v"(d) : "v"(a), "v"(b));
}
__device__ __forceinline__ void gload16(const void* src, void* lds) {
    __builtin_amdgcn_global_load_lds(
        (const __attribute__((address_space(1))) unsigned int*)src,
        (__attribute__((address_space(3))) unsigned int*)lds, 16, 0, 0);
}

// inline int64-vs-int32 layout detection (odd 32-bit words all zero -> int64)
__device__ __forceinline__ int detect_is32_block(const unsigned* __restrict__ w,
                                                 int* s_is32, int tid) {
    if (tid == 0) {
        unsigned o = 0;
#pragma unroll
        for (int k = 1; k < 32; k += 2) o |= w[k];
        *s_is32 = (o != 0u);
    }
    __syncthreads();
    return *s_is32;
}

__device__ __forceinline__ int edge_elem(const unsigned* __restrict__ w, int is32, long long idx) {
    return is32 ? (int)w[idx] : (int)w[2 * idx];
}

// ---------------- fused prep: x->bf16, W1^T, W2^T, and S1 bucket histogram ----------------
#define CONV_BLOCKS 6250   /* 50000*128/4 / 256 */
#define PREP_W_BLOCKS (CONV_BLOCKS + 128 + 256)
__global__ void __launch_bounds__(256) prep_kernel(const float* __restrict__ x,
                                                   ushort_t* __restrict__ xbf,
                                                   const float* __restrict__ W1,
                                                   ushort_t* __restrict__ W1t,
                                                   const float* __restrict__ W2,
                                                   ushort_t* __restrict__ W2t,
                                                   const unsigned* __restrict__ ew,
                                                   int* __restrict__ chunkHist) {
    int b = blockIdx.x, t = threadIdx.x;
    if (b < CONV_BLOCKS) {
        int i = b * 256 + t;
        float4 v = ((const float4*)x)[i];
        ushort4 o;
        o.x = f2bf(v.x); o.y = f2bf(v.y); o.z = f2bf(v.z); o.w = f2bf(v.w);
        ((ushort4*)xbf)[i] = o;
    } else if (b < CONV_BLOCKS + 128) {
        int id = (b - CONV_BLOCKS) * 256 + t;       // id = n*128 + k
        int n = id >> 7, k = id & 127;
        W1t[id] = f2bf(W1[k * 256 + n]);
    } else if (b < CONV_BLOCKS + 128 + 256) {
        int id = (b - CONV_BLOCKS - 128) * 256 + t; // id = n*256 + k
        int n = id >> 8, k = id & 255;
        W2t[id] = f2bf(W2[k * 256 + n]);
    } else {
        // S1: per-chunk coarse-bucket histogram (bucket-major out)
        __shared__ int s_is32;
        __shared__ int hist[NBUCKET];
        int c = b - PREP_W_BLOCKS;
        int is32 = detect_is32_block(ew, &s_is32, t);
        for (int k = t; k < NBUCKET; k += 256) hist[k] = 0;
        __syncthreads();
        long long e0 = (long long)c * EPC;
        for (int k = t; k < EPC; k += 256) {
            int d = edge_elem(ew, is32, (long long)N_EDGES + e0 + k);
            atomicAdd(&hist[d >> 8], 1);
        }
        __syncthreads();
        for (int k = t; k < NBUCKET; k += 256)
            chunkHist[k * NCHUNK + c] = hist[k];
    }
}

// ---------------- generic 3-phase exclusive scan over SCAN_N elements ----------------
__global__ void __launch_bounds__(256) scan1_kernel(const int* __restrict__ in,
                                                    int* __restrict__ excl, int* __restrict__ bsum) {
    __shared__ int s[256];
    int b = blockIdx.x, t = threadIdx.x, i = b * 256 + t;
    int v = in[i];
    s[t] = v;
    __syncthreads();
    for (int off = 1; off < 256; off <<= 1) {
        int y = (t >= off) ? s[t - off] : 0;
        __syncthreads();
        s[t] += y;
        __syncthreads();
    }
    excl[i] = s[t] - v;
    if (t == 255) bsum[b] = s[255];
}

__global__ void __launch_bounds__(256) scan2_kernel(const int* __restrict__ bsum,
                                                    int* __restrict__ boff) {
    __shared__ int s[256];
    int t = threadIdx.x;
    int v = (t < SCAN_BLOCKS) ? bsum[t] : 0;
    s[t] = v;
    __syncthreads();
    for (int off = 1; off < 256; off <<= 1) {
        int y = (t >= off) ? s[t - off] : 0;
        __syncthreads();
        s[t] += y;
        __syncthreads();
    }
    if (t < SCAN_BLOCKS) boff[t] = s[t] - v;
}

__global__ void __launch_bounds__(256) scan3_kernel(const int* __restrict__ boff,
                                                    int* __restrict__ excl) {
    int i = blockIdx.x * 256 + threadIdx.x;
    excl[i] += boff[blockIdx.x];
}

// ---------------- S3: scatter edges into bucket-sorted order (private runs) ----------------
__global__ void __launch_bounds__(256) bucket_scatter_kernel(const unsigned* __restrict__ ew,
                                                             const int* __restrict__ chunkOff,
                                                             unsigned* __restrict__ ebuf) {
    __shared__ int s_is32;
    __shared__ int cur[NBUCKET];
    int t = threadIdx.x, b = blockIdx.x;
    int is32 = detect_is32_block(ew, &s_is32, t);
    for (int k = t; k < NBUCKET; k += 256) cur[k] = chunkOff[k * NCHUNK + b];
    __syncthreads();
    long long e0 = (long long)b * EPC;
    for (int k = t; k < EPC; k += 256) {
        long long e = e0 + k;
        unsigned s = (unsigned)edge_elem(ew, is32, e);
        int d = edge_elem(ew, is32, (long long)N_EDGES + e);
        int pos = atomicAdd(&cur[d >> 8], 1);
        ebuf[pos] = s | ((unsigned)d << 16);
    }
}

// ---------------- S4: exact per-dst sort within bucket + row_ptr + degree hist ----------------
__global__ void __launch_bounds__(256) bucket_sort_kernel(const unsigned* __restrict__ ebuf,
                                                          const int* __restrict__ chunkOff,
                                                          unsigned* __restrict__ edge_csr,
                                                          int* __restrict__ row_ptr,
                                                          int* __restrict__ dhist) {
    __shared__ int cnt[256];
    __shared__ int s[256];
    __shared__ int dh[64];
    int b = blockIdx.x, t = threadIdx.x;
    int start = chunkOff[b * NCHUNK];
    int end = (b + 1 < NBUCKET) ? chunkOff[(b + 1) * NCHUNK] : N_EDGES;
    cnt[t] = 0;
    if (t < 64) dh[t] = 0;
    __syncthreads();
    for (int e = start + t; e < end; e += 256) {
        int d = (int)(ebuf[e] >> 16);
        atomicAdd(&cnt[d & 255], 1);
    }
    __syncthreads();
    int node = b * 256 + t;
    int mydeg = cnt[t];
    if (node < N_NODES) atomicAdd(&dh[mydeg < 63 ? mydeg : 63], 1);
    s[t] = mydeg;
    __syncthreads();
    for (int off = 1; off < 256; off <<= 1) {
        int y = (t >= off) ? s[t - off] : 0;
        __syncthreads();
        s[t] += y;
        __syncthreads();
    }
    int excl = s[t] - mydeg;
    if (node <= N_NODES) row_ptr[node] = start + excl;  // node==N_NODES at b=195,t=80
    cnt[t] = start + excl;  // becomes cursor
    __syncthreads();
    for (int e = start + t; e < end; e += 256) {
        unsigned pk = ebuf[e];
        int pos = atomicAdd(&cnt[(pk >> 16) & 255], 1);
        edge_csr[pos] = pk;
    }
    if (t < 64 && dh[t]) atomicAdd(&dhist[t], dh[t]);
}

// ---------------- degree-bin scan (64 bins, one wave) ----------------
__global__ void __launch_bounds__(64) dscan_kernel(const int* __restrict__ dhist,
                                                   int* __restrict__ dcur) {
    int t = threadIdx.x;
    int v = dhist[t];
    int sum = v;
#pragma unroll
    for (int off = 1; off < 64; off <<= 1) {
        int y = __shfl_up(sum, off, 64);
        if (t >= off) sum += y;
    }
    dcur[t] = sum - v;
}

// ---------------- scatter node ids into degree-grouped perm ----------------
__global__ void __launch_bounds__(256) dscatter_kernel(const int* __restrict__ row_ptr,
                                                       int* __restrict__ dcur,
                                                       int* __restrict__ perm) {
    __shared__ int lh[64], lbase[64];
    int t = threadIdx.x, i = blockIdx.x * 256 + t;
    if (t < 64) lh[t] = 0;
    __syncthreads();
    int deg = 0;
    if (i < N_NODES) {
        deg = row_ptr[i + 1] - row_ptr[i];
        if (deg > 63) deg = 63;
        atomicAdd(&lh[deg], 1);
    }
    __syncthreads();
    if (t < 64) {
        lbase[t] = lh[t] ? atomicAdd(&dcur[t], lh[t]) : 0;
        lh[t] = 0;
    }
    __syncthreads();
    if (i < N_NODES) {
        int rank = atomicAdd(&lh[deg], 1);
        perm[lbase[deg] + rank] = i;
    }
}

// ---------------- MFMA bf16 GEMM + fused alpha logits ----------------
// C[M,256] = A[M,K](bf16) @ Wt^T, stored as fp8 e4m3 (1B/ch).
// colblock == head; epilogue computes alpha_s/alpha_d from fp32 accs.
template <int K>
__global__ void __launch_bounds__(256) mfma_gemm_kernel(const ushort_t* __restrict__ A,
                                                        const ushort_t* __restrict__ Wt,
                                                        void* __restrict__ Cv, int M,
                                                        const float* __restrict__ a_src,
                                                        const float* __restrict__ a_dst,
                                                        float* __restrict__ alpha_s,
                                                        float* __restrict__ alpha_d) {
    constexpr int CPR = K / 8;
    constexpr int NT = K / 64;
    __shared__ ushort_t Bs[64 * K];
    __shared__ ushort_t As[2][64 * 64];
    __shared__ float ps[64][2], pd[64][2];

    int tid = threadIdx.x;
    int wave = tid >> 6, lane = tid & 63;
    int l15 = lane & 15, l4 = lane >> 4;
    int wr = wave >> 1, wc = wave & 1;
    int colblock = blockIdx.x;   // head
    int rowblock = blockIdx.y;

    for (int base = 0; base < 64 * CPR; base += 256) {
        int p = base + wave * 64 + lane;
        int row = p / CPR;
        int cs = p % CPR;
        int c = cs ^ (row & 7);
        const ushort_t* src = Wt + (long long)(colblock * 64 + row) * K + c * 8;
        void* dst = ((char*)Bs) + (base + wave * 64) * 16;
        gload16(src, dst);
    }
    {
        int r = lane >> 3, cs = lane & 7;
        int c = cs ^ r;
#pragma unroll
        for (int q = 0; q < 2; ++q) {
            int lrow = wave * 16 + q * 8;
            int grow = rowblock * 64 + lrow + r;
            if (grow >= M) grow = M - 1;
            const ushort_t* src = A + (long long)grow * K + c * 8;
            void* dst = ((char*)&As[0][0]) + lrow * 128;
            gload16(src, dst);
        }
    }
    __syncthreads();

    f32x4 acc[2][2] = {};
#pragma unroll
    for (int t = 0; t < NT; ++t) {
        if (t + 1 < NT) {
            int r = lane >> 3, cs = lane & 7;
            int c = cs ^ r;
#pragma unroll
            for (int q = 0; q < 2; ++q) {
                int lrow = wave * 16 + q * 8;
                int grow = rowblock * 64 + lrow + r;
                if (grow >= M) grow = M - 1;
                const ushort_t* src = A + (long long)grow * K + (t + 1) * 64 + c * 8;
                void* dst = ((char*)&As[(t + 1) & 1][0]) + lrow * 128;
                gload16(src, dst);
            }
        }
        const ushort_t* At = &As[t & 1][0];
#pragma unroll
        for (int w = 0; w < 2; ++w) {
            bf16x8 a[2], b[2];
#pragma unroll
            for (int mi = 0; mi < 2; ++mi) {
                int row = wr * 32 + mi * 16 + l15;
                int slot = (w * 4 + l4) ^ (l15 & 7);
                a[mi] = *(const bf16x8*)&At[row * 64 + slot * 8];
            }
#pragma unroll
            for (int ni = 0; ni < 2; ++ni) {
                int brow = wc * 32 + ni * 16 + l15;
                int slot = (t * 8 + w * 4 + l4) ^ (l15 & 7);
                b[ni] = *(const bf16x8*)&Bs[brow * CPR * 8 + slot * 8];
            }
#pragma unroll
            for (int mi = 0; mi < 2; ++mi)
#pragma unroll
                for (int ni = 0; ni < 2; ++ni)
                    acc[mi][ni] = __builtin_amdgcn_mfma_f32_16x16x32_bf16(a[mi], b[ni],
                                                                          acc[mi][ni], 0, 0, 0);
        }
        __syncthreads();
    }

    // ---- fused alpha partials: per-row dot with a_src/a_dst (this head) ----
    {
        float as0 = a_src[colblock * 64 + wc * 32 + l15];
        float as1 = a_src[colblock * 64 + wc * 32 + 16 + l15];
        float ad0 = a_dst[colblock * 64 + wc * 32 + l15];
        float ad1 = a_dst[colblock * 64 + wc * 32 + 16 + l15];
#pragma unroll
        for (int mi = 0; mi < 2; ++mi)
#pragma unroll
            for (int q = 0; q < 4; ++q) {
                float sv = acc[mi][0][q] * as0 + acc[mi][1][q] * as1;
                float dv = acc[mi][0][q] * ad0 + acc[mi][1][q] * ad1;
#pragma unroll
                for (int w = 1; w < 16; w <<= 1) {
                    sv += __shfl_xor(sv, w, 64);
                    dv += __shfl_xor(dv, w, 64);
                }
                if (l15 == 0) {
                    int row = wr * 32 + mi * 16 + l4 * 4 + q;
                    ps[row][wc] = sv;
                    pd[row][wc] = dv;
                }
            }
    }

    // ---- epilogue: repack via LDS (bf16 staging), store fp8 ----
    ushort_t* ep = ((ushort_t*)&As[0][0]) + wave * 1280;
#pragma unroll
    for (int mi = 0; mi < 2; ++mi)
#pragma unroll
        for (int ni = 0; ni < 2; ++ni)
#pragma unroll
            for (int q = 0; q < 4; ++q) {
                int row = mi * 16 + l4 * 4 + q;
                int col = ni * 16 + l15;
                ep[row * 40 + col] = f2bf(acc[mi][ni][q]);
            }
    __syncthreads();
#pragma unroll
    for (int j = 0; j < 2; ++j) {
        int p = lane * 2 + j;
        int row = p >> 2, seg = p & 3;
        uint4 v = *(const uint4*)&ep[row * 40 + seg * 8];
        int grow = rowblock * 64 + wr * 32 + row;
        int gcol = colblock * 64 + wc * 32 + seg * 8;
        if (grow < M) {
            f32x2 f01 = bfpair(v.x), f23 = bfpair(v.y);
            f32x2 f45 = bfpair(v.z), f67 = bfpair(v.w);
            int d0 = 0, d1 = 0;
            d0 = __builtin_amdgcn_cvt_pk_fp8_f32(f01.x, f01.y, d0, false);
            d0 = __builtin_amdgcn_cvt_pk_fp8_f32(f23.x, f23.y, d0, true);
            d1 = __builtin_amdgcn_cvt_pk_fp8_f32(f45.x, f45.y, d1, false);
            d1 = __builtin_amdgcn_cvt_pk_fp8_f32(f67.x, f67.y, d1, true);
            uint2 o; o.x = (unsigned)d0; o.y = (unsigned)d1;
            *(uint2*)((char*)Cv + (long long)grow * 256 + gcol) = o;
        }
    }
    if (tid < 64) {
        int ga = rowblock * 64 + tid;
        if (ga < M) {
            alpha_s[ga * 4 + colblock] = ps[tid][0] + ps[tid][1];
            alpha_d[ga * 4 + colblock] = pd[tid][0] + pd[tid][1];
        }
    }
}

// ---------------- softmax-weighted aggregation (one wave per node, degree-grouped) ----------------
// g rows are fp8 e4m3 (256 B/row). Edge weights computed inline.
// Node id comes from perm[] (degree-grouped scheduling); wave-uniform state scalarized.
template <int LAYER>
__global__ void __launch_bounds__(256) aggregate_kernel(
    const void* __restrict__ gv, const float* __restrict__ alpha_s,
    const float* __restrict__ alpha_d, const int* __restrict__ row_ptr,
    const unsigned* __restrict__ edge_csr, const int* __restrict__ perm,
    const float* __restrict__ bias, ushort_t* __restrict__ out_bf,
    const float* __restrict__ fc_w, const float* __restrict__ fc_b,
    float* __restrict__ final_out) {
    int wave = threadIdx.x >> 6;
    int lane = threadIdx.x & 63;
    int i = __builtin_amdgcn_readfirstlane(perm[blockIdx.x * 4 + wave]);
    int hd = lane >> 4;
    const char* gb = (const char*)gv;           // fp8 rows: 256 B/row
    unsigned loff = (unsigned)(lane << 2);

    float ad = alpha_d[i * 4 + hd];
    // self loop
    float e0 = alpha_s[i * 4 + hd] + ad;
    e0 = e0 > 0.f ? e0 : 0.2f * e0;
    float w0 = __expf(e0);
    f32x2 wp0; wp0.x = w0; wp0.y = w0;
    f32x2 acc01 = {0.f, 0.f}, acc23 = {0.f, 0.f};
    {
        unsigned sv = *(const unsigned*)(gb + (((unsigned)i << 8) | loff));
        pkfma(acc01, wp0, __builtin_amdgcn_cvt_pk_f32_fp8(sv, false));
        pkfma(acc23, wp0, __builtin_amdgcn_cvt_pk_f32_fp8(sv, true));
    }
    float wsum = w0;

    int p = __builtin_amdgcn_readfirstlane(row_ptr[i]);
    int p1 = __builtin_amdgcn_readfirstlane(row_ptr[i + 1]);
    for (; p + 8 <= p1; p += 8) {
        int j[8]; float as[8]; unsigned hh[8];
#pragma unroll
        for (int u = 0; u < 8; ++u)
            j[u] = (int)(edge_csr[p + u] & 0xFFFFu);
#pragma unroll
        for (int u = 0; u < 8; ++u) as[u] = alpha_s[j[u] * 4 + hd];
#pragma unroll
        for (int u = 0; u < 8; ++u)
            hh[u] = *(const unsigned*)(gb + (((unsigned)j[u] << 8) | loff));
#pragma unroll
        for (int u = 0; u < 8; ++u) {
            float e = as[u] + ad;
            e = e > 0.f ? e : 0.2f * e;
            float wt = __expf(e);
            wsum += wt;
            f32x2 wp; wp.x = wt; wp.y = wt;
            pkfma(acc01, wp, __builtin_amdgcn_cvt_pk_f32_fp8(hh[u], false));
            pkfma(acc23, wp, __builtin_amdgcn_cvt_pk_f32_fp8(hh[u], true));
        }
    }
    for (; p < p1; ++p) {
        int j = (int)(edge_csr[p] & 0xFFFFu);
        float e = alpha_s[j * 4 + hd] + ad;
        e = e > 0.f ? e : 0.2f * e;
        float wt = __expf(e);
        unsigned hj = *(const unsigned*)(gb + (((unsigned)j << 8) | loff));
        wsum += wt;
        f32x2 wp; wp.x = wt; wp.y = wt;
        pkfma(acc01, wp, __builtin_amdgcn_cvt_pk_f32_fp8(hj, false));
        pkfma(acc23, wp, __builtin_amdgcn_cvt_pk_f32_fp8(hj, true));
    }
    float inv = 1.f / (wsum + 1e-16f);
    int c = lane * 4;
    float4 b4 = *(const float4*)&bias[c];
    float o0 = acc01.x * inv + b4.x;
    float o1 = acc01.y * inv + b4.y;
    float o2 = acc23.x * inv + b4.z;
    float o3 = acc23.y * inv + b4.w;
    o0 = o0 > 0.f ? o0 : __expf(o0) - 1.f;
    o1 = o1 > 0.f ? o1 : __expf(o1) - 1.f;
    o2 = o2 > 0.f ? o2 : __expf(o2) - 1.f;
    o3 = o3 > 0.f ? o3 : __expf(o3) - 1.f;
    if (LAYER == 1) {
        ushort4 o;
        o.x = f2bf(o0); o.y = f2bf(o1); o.z = f2bf(o2); o.w = f2bf(o3);
        ((ushort4*)out_bf)[(long long)i * 64 + lane] = o;
    } else {
        float4 fw = *(const float4*)&fc_w[c];
        float dot = o0 * fw.x + o1 * fw.y + o2 * fw.z + o3 * fw.w;
#pragma unroll
        for (int off = 32; off; off >>= 1) dot += __shfl_down(dot, off, 64);
        if (lane == 0) final_out[i] = 1.f / (1.f + __expf(-(dot + fc_b[0])));
    }
}

// ---------------- launch ----------------
extern "C" void kernel_launch(void* const* d_in, const int* in_sizes, int n_in,
                              void* d_out, int out_size, void* d_ws, size_t ws_size,
                              hipStream_t stream) {
    const float* x   = (const float*)d_in[0];
    const unsigned* ei = (const unsigned*)d_in[1];
    const float* W1  = (const float*)d_in[2];
    const float* as1 = (const float*)d_in[3];
    const float* ad1 = (const float*)d_in[4];
    const float* b1  = (const float*)d_in[5];
    const float* W2  = (const float*)d_in[6];
    const float* as2 = (const float*)d_in[7];
    const float* ad2 = (const float*)d_in[8];
    const float* b2  = (const float*)d_in[9];
    const float* fcw = (const float*)d_in[10];
    const float* fcb = (const float*)d_in[11];

    char* ws = (char*)d_ws;
    void* g1f8         = (void*)(ws + 0);               // 12.8 MB (fp8)
    void* g2f8         = (void*)(ws + 12800000);        // 12.8 MB (fp8)
    ushort_t* hactbf   = (ushort_t*)(ws + 25600000);    // 25.6 MB
    ushort_t* xbf      = (ushort_t*)(ws + 51200000);    // 12.8 MB
    ushort_t* W1t      = (ushort_t*)(ws + 64000000);
    ushort_t* W2t      = (ushort_t*)(ws + 64100000);
    float* asv         = (float*)(ws + 64300000);
    float* adv         = (float*)(ws + 65100000);
    int* row_ptr       = (int*)(ws + 65900000);         // 50001 ints
    int* chunkHist     = (int*)(ws + 66110000);         // 50176 ints
    int* chunkOff      = (int*)(ws + 66320000);         // 50176 ints
    unsigned* ebuf     = (unsigned*)(ws + 66530000);    // 3.2 MB (bucket-sorted)
    unsigned* edge_csr = (unsigned*)(ws + 69730000);    // 3.2 MB (exact CSR)
    int* perm          = (int*)(ws + 72930000);         // 200 KB (degree-grouped order)
    int* bsum          = (int*)(ws + 73130000);         // 196 ints
    int* boff          = (int*)(ws + 73131024);         // 196 ints
    int* dhist         = (int*)(ws + 73132048);         // 64 ints
    int* dcur          = (int*)(ws + 73132304);         // 64 ints

    hipMemsetAsync(dhist, 0, 64 * 4, stream);

    prep_kernel<<<PREP_W_BLOCKS + NCHUNK, 256, 0, stream>>>(x, xbf, W1, W1t, W2, W2t,
                                                            ei, chunkHist);
    scan1_kernel<<<SCAN_BLOCKS, 256, 0, stream>>>(chunkHist, chunkOff, bsum);
    scan2_kernel<<<1, 256, 0, stream>>>(bsum, boff);
    scan3_kernel<<<SCAN_BLOCKS, 256, 0, stream>>>(boff, chunkOff);
    bucket_scatter_kernel<<<NCHUNK, 256, 0, stream>>>(ei, chunkOff, ebuf);
    bucket_sort_kernel<<<NBUCKET, 256, 0, stream>>>(ebuf, chunkOff, edge_csr, row_ptr, dhist);
    dscan_kernel<<<1, 64, 0, stream>>>(dhist, dcur);
    dscatter_kernel<<<SCAN_BLOCKS, 256, 0, stream>>>(row_ptr, dcur, perm);

    // layer 1 (g stored fp8)
    mfma_gemm_kernel<128><<<dim3(4, (N_NODES + 63) / 64), 256, 0, stream>>>(
        xbf, W1t, g1f8, N_NODES, as1, ad1, asv, adv);
    aggregate_kernel<1><<<N_NODES / 4, 256, 0, stream>>>(g1f8, asv, adv, row_ptr, edge_csr, perm,
                                                         b1, hactbf, nullptr, nullptr, nullptr);
    // layer 2 (g stored fp8)
    mfma_gemm_kernel<256><<<dim3(4, (N_NODES + 63) / 64), 256, 0, stream>>>(
        hactbf, W2t, g2f8, N_NODES, as2, ad2, asv, adv);
    aggregate_kernel<2><<<N_NODES / 4, 256, 0, stream>>>(g2f8, asv, adv, row_ptr, edge_csr, perm,
                                                         b2, nullptr, fcw, fcb, (float*)d_out);
}

// Round 13
// 176.511 us; speedup vs baseline: 3.7192x; 1.0533x over previous
//
#include <hip/hip_runtime.h>
#include <hip/hip_bf16.h>

#define N_NODES 50000
#define N_EDGES 800000
#define NCHUNK 256        // edge chunks
#define EPC 3125          // edges per chunk (= N_EDGES/NCHUNK exactly)
#define NBUCKET 196       // coarse buckets: dst>>8 (50000/256 -> 196)
#define SCAN_N 50176      // NBUCKET*NCHUNK
#define SCAN_BLOCKS 196   // SCAN_N/256

typedef __attribute__((ext_vector_type(8))) short bf16x8;
typedef __attribute__((ext_vector_type(4))) float f32x4;
typedef __attribute__((ext_vector_type(2))) float f32x2;
typedef unsigned short ushort_t;

__device__ __forceinline__ float bf2f(unsigned short u) {
    union { unsigned u32; float f; } v; v.u32 = (unsigned)u << 16; return v.f;
}
__device__ __forceinline__ unsigned short f2bf(float f) {
    __hip_bfloat16 h = __float2bfloat16(f);
    return *reinterpret_cast<unsigned short*>(&h);
}
__device__ __forceinline__ f32x2 bfpair(unsigned u) {
    union { unsigned a; float f; } lo, hi;
    lo.a = u << 16;
    hi.a = u & 0xFFFF0000u;
    f32x2 r; r.x = lo.f; r.y = hi.f; return r;
}
// d += a * b (packed f32x2; all operands are VGPR pairs — VOP3P requirement)
__device__ __forceinline__ void pkfma(f32x2& d, f32x2 a, f32x2 b) {
    asm("v_pk_fma_f32 %0, %1, %2, %0" : "+v"(d) : "v"(a), "v"(b));
}
__device__ __forceinline__ void gload16(const void* src, void* lds) {
    __builtin_amdgcn_global_load_lds(
        (const __attribute__((address_space(1))) unsigned int*)src,
        (__attribute__((address_space(3))) unsigned int*)lds, 16, 0, 0);
}

// inline int64-vs-int32 layout detection (odd 32-bit words all zero -> int64)
__device__ __forceinline__ int detect_is32_block(const unsigned* __restrict__ w,
                                                 int* s_is32, int tid) {
    if (tid == 0) {
        unsigned o = 0;
#pragma unroll
        for (int k = 1; k < 32; k += 2) o |= w[k];
        *s_is32 = (o != 0u);
    }
    __syncthreads();
    return *s_is32;
}

__device__ __forceinline__ int edge_elem(const unsigned* __restrict__ w, int is32, long long idx) {
    return is32 ? (int)w[idx] : (int)w[2 * idx];
}

// ---------------- fused prep: x->bf16, W1^T, W2^T, S1 bucket histogram, zero dhist/dcur ----------------
#define CONV_BLOCKS 6250   /* 50000*128/4 / 256 */
#define PREP_W_BLOCKS (CONV_BLOCKS + 128 + 256)
__global__ void __launch_bounds__(256) prep_kernel(const float* __restrict__ x,
                                                   ushort_t* __restrict__ xbf,
                                                   const float* __restrict__ W1,
                                                   ushort_t* __restrict__ W1t,
                                                   const float* __restrict__ W2,
                                                   ushort_t* __restrict__ W2t,
                                                   const unsigned* __restrict__ ew,
                                                   int* __restrict__ chunkHist,
                                                   int* __restrict__ dhist,
                                                   int* __restrict__ dcur) {
    int b = blockIdx.x, t = threadIdx.x;
    if (b < CONV_BLOCKS) {
        if (b == 0 && t < 64) { dhist[t] = 0; dcur[t] = 0; }
        int i = b * 256 + t;
        float4 v = ((const float4*)x)[i];
        ushort4 o;
        o.x = f2bf(v.x); o.y = f2bf(v.y); o.z = f2bf(v.z); o.w = f2bf(v.w);
        ((ushort4*)xbf)[i] = o;
    } else if (b < CONV_BLOCKS + 128) {
        int id = (b - CONV_BLOCKS) * 256 + t;       // id = n*128 + k
        int n = id >> 7, k = id & 127;
        W1t[id] = f2bf(W1[k * 256 + n]);
    } else if (b < CONV_BLOCKS + 128 + 256) {
        int id = (b - CONV_BLOCKS - 128) * 256 + t; // id = n*256 + k
        int n = id >> 8, k = id & 255;
        W2t[id] = f2bf(W2[k * 256 + n]);
    } else {
        // S1: per-chunk coarse-bucket histogram (bucket-major out)
        __shared__ int s_is32;
        __shared__ int hist[NBUCKET];
        int c = b - PREP_W_BLOCKS;
        int is32 = detect_is32_block(ew, &s_is32, t);
        for (int k = t; k < NBUCKET; k += 256) hist[k] = 0;
        __syncthreads();
        long long e0 = (long long)c * EPC;
        for (int k = t; k < EPC; k += 256) {
            int d = edge_elem(ew, is32, (long long)N_EDGES + e0 + k);
            atomicAdd(&hist[d >> 8], 1);
        }
        __syncthreads();
        for (int k = t; k < NBUCKET; k += 256)
            chunkHist[k * NCHUNK + c] = hist[k];
    }
}

// ---------------- scan over SCAN_N elements (block-local) ----------------
__global__ void __launch_bounds__(256) scan1_kernel(const int* __restrict__ in,
                                                    int* __restrict__ excl, int* __restrict__ bsum) {
    __shared__ int s[256];
    int b = blockIdx.x, t = threadIdx.x, i = b * 256 + t;
    int v = in[i];
    s[t] = v;
    __syncthreads();
    for (int off = 1; off < 256; off <<= 1) {
        int y = (t >= off) ? s[t - off] : 0;
        __syncthreads();
        s[t] += y;
        __syncthreads();
    }
    excl[i] = s[t] - v;
    if (t == 255) bsum[b] = s[255];
}

// scan3 with inlined bsum prefix (removes separate scan2 dispatch)
__global__ void __launch_bounds__(256) scan3_kernel(const int* __restrict__ bsum,
                                                    int* __restrict__ excl) {
    __shared__ int sboff;
    int b = blockIdx.x, t = threadIdx.x;
    if (t < 64) {
        int add = 0;
        for (int k = t; k < b; k += 64) add += bsum[k];
#pragma unroll
        for (int off = 32; off; off >>= 1) add += __shfl_down(add, off, 64);
        if (t == 0) sboff = add;
    }
    __syncthreads();
    excl[b * 256 + t] += sboff;
}

// ---------------- S3: scatter edges into bucket-sorted order (private runs) ----------------
__global__ void __launch_bounds__(256) bucket_scatter_kernel(const unsigned* __restrict__ ew,
                                                             const int* __restrict__ chunkOff,
                                                             unsigned* __restrict__ ebuf) {
    __shared__ int s_is32;
    __shared__ int cur[NBUCKET];
    int t = threadIdx.x, b = blockIdx.x;
    int is32 = detect_is32_block(ew, &s_is32, t);
    for (int k = t; k < NBUCKET; k += 256) cur[k] = chunkOff[k * NCHUNK + b];
    __syncthreads();
    long long e0 = (long long)b * EPC;
    for (int k = t; k < EPC; k += 256) {
        long long e = e0 + k;
        unsigned s = (unsigned)edge_elem(ew, is32, e);
        int d = edge_elem(ew, is32, (long long)N_EDGES + e);
        int pos = atomicAdd(&cur[d >> 8], 1);
        ebuf[pos] = s | ((unsigned)d << 16);
    }
}

// ---------------- S4: exact per-dst sort within bucket + row_ptr + degree hist ----------------
__global__ void __launch_bounds__(256) bucket_sort_kernel(const unsigned* __restrict__ ebuf,
                                                          const int* __restrict__ chunkOff,
                                                          unsigned* __restrict__ edge_csr,
                                                          int* __restrict__ row_ptr,
                                                          int* __restrict__ dhist) {
    __shared__ int cnt[256];
    __shared__ int s[256];
    __shared__ int dh[64];
    int b = blockIdx.x, t = threadIdx.x;
    int start = chunkOff[b * NCHUNK];
    int end = (b + 1 < NBUCKET) ? chunkOff[(b + 1) * NCHUNK] : N_EDGES;
    cnt[t] = 0;
    if (t < 64) dh[t] = 0;
    __syncthreads();
    for (int e = start + t; e < end; e += 256) {
        int d = (int)(ebuf[e] >> 16);
        atomicAdd(&cnt[d & 255], 1);
    }
    __syncthreads();
    int node = b * 256 + t;
    int mydeg = cnt[t];
    if (node < N_NODES) atomicAdd(&dh[mydeg < 63 ? mydeg : 63], 1);
    s[t] = mydeg;
    __syncthreads();
    for (int off = 1; off < 256; off <<= 1) {
        int y = (t >= off) ? s[t - off] : 0;
        __syncthreads();
        s[t] += y;
        __syncthreads();
    }
    int excl = s[t] - mydeg;
    if (node <= N_NODES) row_ptr[node] = start + excl;  // node==N_NODES at b=195,t=80
    cnt[t] = start + excl;  // becomes cursor
    __syncthreads();
    for (int e = start + t; e < end; e += 256) {
        unsigned pk = ebuf[e];
        int pos = atomicAdd(&cnt[(pk >> 16) & 255], 1);
        edge_csr[pos] = pk;
    }
    if (t < 64 && dh[t]) atomicAdd(&dhist[t], dh[t]);
}

// ---------------- scatter node ids into degree-grouped perm (inlined bin scan) ----------------
__global__ void __launch_bounds__(256) dscatter_kernel(const int* __restrict__ row_ptr,
                                                       const int* __restrict__ dhist,
                                                       int* __restrict__ dcur,
                                                       int* __restrict__ perm) {
    __shared__ int lh[64], lbase[64], sbase[64];
    int t = threadIdx.x, i = blockIdx.x * 256 + t;
    if (t < 64) {
        int v = dhist[t];
        int sum = v;
#pragma unroll
        for (int off = 1; off < 64; off <<= 1) {
            int y = __shfl_up(sum, off, 64);
            if (t >= off) sum += y;
        }
        sbase[t] = sum - v;
        lh[t] = 0;
    }
    __syncthreads();
    int deg = 0;
    if (i < N_NODES) {
        deg = row_ptr[i + 1] - row_ptr[i];
        if (deg > 63) deg = 63;
        atomicAdd(&lh[deg], 1);
    }
    __syncthreads();
    if (t < 64) {
        lbase[t] = lh[t] ? (sbase[t] + atomicAdd(&dcur[t], lh[t])) : 0;
        lh[t] = 0;
    }
    __syncthreads();
    if (i < N_NODES) {
        int rank = atomicAdd(&lh[deg], 1);
        perm[lbase[deg] + rank] = i;
    }
}

// ---------------- MFMA bf16 GEMM + fused alpha logits ----------------
// C[M,256] = A[M,K](bf16) @ Wt^T, stored as fp8 e4m3 (1B/ch).
// colblock == head; epilogue computes alpha_s/alpha_d from fp32 accs.
template <int K>
__global__ void __launch_bounds__(256) mfma_gemm_kernel(const ushort_t* __restrict__ A,
                                                        const ushort_t* __restrict__ Wt,
                                                        void* __restrict__ Cv, int M,
                                                        const float* __restrict__ a_src,
                                                        const float* __restrict__ a_dst,
                                                        float* __restrict__ alpha_s,
                                                        float* __restrict__ alpha_d) {
    constexpr int CPR = K / 8;
    constexpr int NT = K / 64;
    __shared__ ushort_t Bs[64 * K];
    __shared__ ushort_t As[2][64 * 64];
    __shared__ float ps[64][2], pd[64][2];

    int tid = threadIdx.x;
    int wave = tid >> 6, lane = tid & 63;
    int l15 = lane & 15, l4 = lane >> 4;
    int wr = wave >> 1, wc = wave & 1;
    int colblock = blockIdx.x;   // head
    int rowblock = blockIdx.y;

    for (int base = 0; base < 64 * CPR; base += 256) {
        int p = base + wave * 64 + lane;
        int row = p / CPR;
        int cs = p % CPR;
        int c = cs ^ (row & 7);
        const ushort_t* src = Wt + (long long)(colblock * 64 + row) * K + c * 8;
        void* dst = ((char*)Bs) + (base + wave * 64) * 16;
        gload16(src, dst);
    }
    {
        int r = lane >> 3, cs = lane & 7;
        int c = cs ^ r;
#pragma unroll
        for (int q = 0; q < 2; ++q) {
            int lrow = wave * 16 + q * 8;
            int grow = rowblock * 64 + lrow + r;
            if (grow >= M) grow = M - 1;
            const ushort_t* src = A + (long long)grow * K + c * 8;
            void* dst = ((char*)&As[0][0]) + lrow * 128;
            gload16(src, dst);
        }
    }
    __syncthreads();

    f32x4 acc[2][2] = {};
#pragma unroll
    for (int t = 0; t < NT; ++t) {
        if (t + 1 < NT) {
            int r = lane >> 3, cs = lane & 7;
            int c = cs ^ r;
#pragma unroll
            for (int q = 0; q < 2; ++q) {
                int lrow = wave * 16 + q * 8;
                int grow = rowblock * 64 + lrow + r;
                if (grow >= M) grow = M - 1;
                const ushort_t* src = A + (long long)grow * K + (t + 1) * 64 + c * 8;
                void* dst = ((char*)&As[(t + 1) & 1][0]) + lrow * 128;
                gload16(src, dst);
            }
        }
        const ushort_t* At = &As[t & 1][0];
#pragma unroll
        for (int w = 0; w < 2; ++w) {
            bf16x8 a[2], b[2];
#pragma unroll
            for (int mi = 0; mi < 2; ++mi) {
                int row = wr * 32 + mi * 16 + l15;
                int slot = (w * 4 + l4) ^ (l15 & 7);
                a[mi] = *(const bf16x8*)&At[row * 64 + slot * 8];
            }
#pragma unroll
            for (int ni = 0; ni < 2; ++ni) {
                int brow = wc * 32 + ni * 16 + l15;
                int slot = (t * 8 + w * 4 + l4) ^ (l15 & 7);
                b[ni] = *(const bf16x8*)&Bs[brow * CPR * 8 + slot * 8];
            }
#pragma unroll
            for (int mi = 0; mi < 2; ++mi)
#pragma unroll
                for (int ni = 0; ni < 2; ++ni)
                    acc[mi][ni] = __builtin_amdgcn_mfma_f32_16x16x32_bf16(a[mi], b[ni],
                                                                          acc[mi][ni], 0, 0, 0);
        }
        __syncthreads();
    }

    // ---- fused alpha partials: per-row dot with a_src/a_dst (this head) ----
    {
        float as0 = a_src[colblock * 64 + wc * 32 + l15];
        float as1 = a_src[colblock * 64 + wc * 32 + 16 + l15];
        float ad0 = a_dst[colblock * 64 + wc * 32 + l15];
        float ad1 = a_dst[colblock * 64 + wc * 32 + 16 + l15];
#pragma unroll
        for (int mi = 0; mi < 2; ++mi)
#pragma unroll
            for (int q = 0; q < 4; ++q) {
                float sv = acc[mi][0][q] * as0 + acc[mi][1][q] * as1;
                float dv = acc[mi][0][q] * ad0 + acc[mi][1][q] * ad1;
#pragma unroll
                for (int w = 1; w < 16; w <<= 1) {
                    sv += __shfl_xor(sv, w, 64);
                    dv += __shfl_xor(dv, w, 64);
                }
                if (l15 == 0) {
                    int row = wr * 32 + mi * 16 + l4 * 4 + q;
                    ps[row][wc] = sv;
                    pd[row][wc] = dv;
                }
            }
    }

    // ---- epilogue: repack via LDS (bf16 staging), store fp8 ----
    ushort_t* ep = ((ushort_t*)&As[0][0]) + wave * 1280;
#pragma unroll
    for (int mi = 0; mi < 2; ++mi)
#pragma unroll
        for (int ni = 0; ni < 2; ++ni)
#pragma unroll
            for (int q = 0; q < 4; ++q) {
                int row = mi * 16 + l4 * 4 + q;
                int col = ni * 16 + l15;
                ep[row * 40 + col] = f2bf(acc[mi][ni][q]);
            }
    __syncthreads();
#pragma unroll
    for (int j = 0; j < 2; ++j) {
        int p = lane * 2 + j;
        int row = p >> 2, seg = p & 3;
        uint4 v = *(const uint4*)&ep[row * 40 + seg * 8];
        int grow = rowblock * 64 + wr * 32 + row;
        int gcol = colblock * 64 + wc * 32 + seg * 8;
        if (grow < M) {
            f32x2 f01 = bfpair(v.x), f23 = bfpair(v.y);
            f32x2 f45 = bfpair(v.z), f67 = bfpair(v.w);
            int d0 = 0, d1 = 0;
            d0 = __builtin_amdgcn_cvt_pk_fp8_f32(f01.x, f01.y, d0, false);
            d0 = __builtin_amdgcn_cvt_pk_fp8_f32(f23.x, f23.y, d0, true);
            d1 = __builtin_amdgcn_cvt_pk_fp8_f32(f45.x, f45.y, d1, false);
            d1 = __builtin_amdgcn_cvt_pk_fp8_f32(f67.x, f67.y, d1, true);
            uint2 o; o.x = (unsigned)d0; o.y = (unsigned)d1;
            *(uint2*)((char*)Cv + (long long)grow * 256 + gcol) = o;
        }
    }
    if (tid < 64) {
        int ga = rowblock * 64 + tid;
        if (ga < M) {
            alpha_s[ga * 4 + colblock] = ps[tid][0] + ps[tid][1];
            alpha_d[ga * 4 + colblock] = pd[tid][0] + pd[tid][1];
        }
    }
}

// ---------------- softmax-weighted aggregation (one wave per node, degree-grouped) ----------------
template <int U>
__device__ __forceinline__ void agg_batch(int p, const unsigned* __restrict__ edge_csr,
                                          const float* __restrict__ alpha_s,
                                          const char* __restrict__ gb, unsigned loff,
                                          int hd, float ad, float& wsum,
                                          f32x2& acc01, f32x2& acc23) {
    int j[U]; float as[U]; unsigned hh[U];
#pragma unroll
    for (int u = 0; u < U; ++u) j[u] = (int)(edge_csr[p + u] & 0xFFFFu);
#pragma unroll
    for (int u = 0; u < U; ++u) as[u] = alpha_s[j[u] * 4 + hd];
#pragma unroll
    for (int u = 0; u < U; ++u)
        hh[u] = *(const unsigned*)(gb + (((unsigned)j[u] << 8) | loff));
#pragma unroll
    for (int u = 0; u < U; ++u) {
        float e = as[u] + ad;
        e = e > 0.f ? e : 0.2f * e;
        float wt = __expf(e);
        wsum += wt;
        f32x2 wp; wp.x = wt; wp.y = wt;
        pkfma(acc01, wp, __builtin_amdgcn_cvt_pk_f32_fp8(hh[u], false));
        pkfma(acc23, wp, __builtin_amdgcn_cvt_pk_f32_fp8(hh[u], true));
    }
}

template <int LAYER>
__global__ void __launch_bounds__(256) aggregate_kernel(
    const void* __restrict__ gv, const float* __restrict__ alpha_s,
    const float* __restrict__ alpha_d, const int* __restrict__ row_ptr,
    const unsigned* __restrict__ edge_csr, const int* __restrict__ perm,
    const float* __restrict__ bias, ushort_t* __restrict__ out_bf,
    const float* __restrict__ fc_w, const float* __restrict__ fc_b,
    float* __restrict__ final_out) {
    int wave = threadIdx.x >> 6;
    int lane = threadIdx.x & 63;
    int i = __builtin_amdgcn_readfirstlane(perm[blockIdx.x * 4 + wave]);
    int hd = lane >> 4;
    const char* gb = (const char*)gv;           // fp8 rows: 256 B/row
    unsigned loff = (unsigned)(lane << 2);

    float ad = alpha_d[i * 4 + hd];
    // self loop
    float e0 = alpha_s[i * 4 + hd] + ad;
    e0 = e0 > 0.f ? e0 : 0.2f * e0;
    float w0 = __expf(e0);
    f32x2 acc01 = {0.f, 0.f}, acc23 = {0.f, 0.f};
    {
        unsigned sv = *(const unsigned*)(gb + (((unsigned)i << 8) | loff));
        f32x2 wp0; wp0.x = w0; wp0.y = w0;
        pkfma(acc01, wp0, __builtin_amdgcn_cvt_pk_f32_fp8(sv, false));
        pkfma(acc23, wp0, __builtin_amdgcn_cvt_pk_f32_fp8(sv, true));
    }
    float wsum = w0;

    int p = __builtin_amdgcn_readfirstlane(row_ptr[i]);
    int p1 = __builtin_amdgcn_readfirstlane(row_ptr[i + 1]);
    for (; p + 16 <= p1; p += 16)
        agg_batch<16>(p, edge_csr, alpha_s, gb, loff, hd, ad, wsum, acc01, acc23);
    for (; p + 8 <= p1; p += 8)
        agg_batch<8>(p, edge_csr, alpha_s, gb, loff, hd, ad, wsum, acc01, acc23);
    for (; p + 4 <= p1; p += 4)
        agg_batch<4>(p, edge_csr, alpha_s, gb, loff, hd, ad, wsum, acc01, acc23);
    for (; p < p1; ++p)
        agg_batch<1>(p, edge_csr, alpha_s, gb, loff, hd, ad, wsum, acc01, acc23);

    float inv = 1.f / (wsum + 1e-16f);
    int c = lane * 4;
    float4 b4 = *(const float4*)&bias[c];
    float o0 = acc01.x * inv + b4.x;
    float o1 = acc01.y * inv + b4.y;
    float o2 = acc23.x * inv + b4.z;
    float o3 = acc23.y * inv + b4.w;
    o0 = o0 > 0.f ? o0 : __expf(o0) - 1.f;
    o1 = o1 > 0.f ? o1 : __expf(o1) - 1.f;
    o2 = o2 > 0.f ? o2 : __expf(o2) - 1.f;
    o3 = o3 > 0.f ? o3 : __expf(o3) - 1.f;
    if (LAYER == 1) {
        ushort4 o;
        o.x = f2bf(o0); o.y = f2bf(o1); o.z = f2bf(o2); o.w = f2bf(o3);
        ((ushort4*)out_bf)[(long long)i * 64 + lane] = o;
    } else {
        float4 fw = *(const float4*)&fc_w[c];
        float dot = o0 * fw.x + o1 * fw.y + o2 * fw.z + o3 * fw.w;
#pragma unroll
        for (int off = 32; off; off >>= 1) dot += __shfl_down(dot, off, 64);
        if (lane == 0) final_out[i] = 1.f / (1.f + __expf(-(dot + fc_b[0])));
    }
}

// ---------------- launch ----------------
extern "C" void kernel_launch(void* const* d_in, const int* in_sizes, int n_in,
                              void* d_out, int out_size, void* d_ws, size_t ws_size,
                              hipStream_t stream) {
    const float* x   = (const float*)d_in[0];
    const unsigned* ei = (const unsigned*)d_in[1];
    const float* W1  = (const float*)d_in[2];
    const float* as1 = (const float*)d_in[3];
    const float* ad1 = (const float*)d_in[4];
    const float* b1  = (const float*)d_in[5];
    const float* W2  = (const float*)d_in[6];
    const float* as2 = (const float*)d_in[7];
    const float* ad2 = (const float*)d_in[8];
    const float* b2  = (const float*)d_in[9];
    const float* fcw = (const float*)d_in[10];
    const float* fcb = (const float*)d_in[11];

    char* ws = (char*)d_ws;
    void* g1f8         = (void*)(ws + 0);               // 12.8 MB (fp8)
    void* g2f8         = (void*)(ws + 12800000);        // 12.8 MB (fp8)
    ushort_t* hactbf   = (ushort_t*)(ws + 25600000);    // 25.6 MB
    ushort_t* xbf      = (ushort_t*)(ws + 51200000);    // 12.8 MB
    ushort_t* W1t      = (ushort_t*)(ws + 64000000);
    ushort_t* W2t      = (ushort_t*)(ws + 64100000);
    float* asv         = (float*)(ws + 64300000);
    float* adv         = (float*)(ws + 65100000);
    int* row_ptr       = (int*)(ws + 65900000);         // 50001 ints
    int* chunkHist     = (int*)(ws + 66110000);         // 50176 ints
    int* chunkOff      = (int*)(ws + 66320000);         // 50176 ints
    unsigned* ebuf     = (unsigned*)(ws + 66530000);    // 3.2 MB (bucket-sorted)
    unsigned* edge_csr = (unsigned*)(ws + 69730000);    // 3.2 MB (exact CSR)
    int* perm          = (int*)(ws + 72930000);         // 200 KB (degree-grouped order)
    int* bsum          = (int*)(ws + 73130000);         // 196 ints
    int* dhist         = (int*)(ws + 73132048);         // 64 ints
    int* dcur          = (int*)(ws + 73132304);         // 64 ints

    prep_kernel<<<PREP_W_BLOCKS + NCHUNK, 256, 0, stream>>>(x, xbf, W1, W1t, W2, W2t,
                                                            ei, chunkHist, dhist, dcur);
    scan1_kernel<<<SCAN_BLOCKS, 256, 0, stream>>>(chunkHist, chunkOff, bsum);
    scan3_kernel<<<SCAN_BLOCKS, 256, 0, stream>>>(bsum, chunkOff);
    bucket_scatter_kernel<<<NCHUNK, 256, 0, stream>>>(ei, chunkOff, ebuf);
    bucket_sort_kernel<<<NBUCKET, 256, 0, stream>>>(ebuf, chunkOff, edge_csr, row_ptr, dhist);
    dscatter_kernel<<<SCAN_BLOCKS, 256, 0, stream>>>(row_ptr, dhist, dcur, perm);

    // layer 1 (g stored fp8)
    mfma_gemm_kernel<128><<<dim3(4, (N_NODES + 63) / 64), 256, 0, stream>>>(
        xbf, W1t, g1f8, N_NODES, as1, ad1, asv, adv);
    aggregate_kernel<1><<<N_NODES / 4, 256, 0, stream>>>(g1f8, asv, adv, row_ptr, edge_csr, perm,
                                                         b1, hactbf, nullptr, nullptr, nullptr);
    // layer 2 (g stored fp8)
    mfma_gemm_kernel<256><<<dim3(4, (N_NODES + 63) / 64), 256, 0, stream>>>(
        hactbf, W2t, g2f8, N_NODES, as2, ad2, asv, adv);
    aggregate_kernel<2><<<N_NODES / 4, 256, 0, stream>>>(g2f8, asv, adv, row_ptr, edge_csr, perm,
                                                         b2, nullptr, fcw, fcb, (float*)d_out);
}

// Round 14
// 174.740 us; speedup vs baseline: 3.7569x; 1.0101x over previous
//
#include <hip/hip_runtime.h>
#include <hip/hip_bf16.h>

#define N_NODES 50000
#define N_EDGES 800000
#define NCHUNK 256        // edge chunks
#define EPC 3125          // edges per chunk (= N_EDGES/NCHUNK exactly)
#define NBUCKET 196       // coarse buckets: dst>>8 (50000/256 -> 196)
#define SCAN_N 50176      // NBUCKET*NCHUNK
#define SCAN_BLOCKS 196   // SCAN_N/256

typedef __attribute__((ext_vector_type(8))) short bf16x8;
typedef __attribute__((ext_vector_type(4))) float f32x4;
typedef __attribute__((ext_vector_type(2))) float f32x2;
typedef unsigned short ushort_t;

__device__ __forceinline__ float bf2f(unsigned short u) {
    union { unsigned u32; float f; } v; v.u32 = (unsigned)u << 16; return v.f;
}
__device__ __forceinline__ unsigned short f2bf(float f) {
    __hip_bfloat16 h = __float2bfloat16(f);
    return *reinterpret_cast<unsigned short*>(&h);
}
__device__ __forceinline__ f32x2 bfpair(unsigned u) {
    union { unsigned a; float f; } lo, hi;
    lo.a = u << 16;
    hi.a = u & 0xFFFF0000u;
    f32x2 r; r.x = lo.f; r.y = hi.f; return r;
}
// d += a * b (packed f32x2; all operands are VGPR pairs — VOP3P requirement)
__device__ __forceinline__ void pkfma(f32x2& d, f32x2 a, f32x2 b) {
    asm("v_pk_fma_f32 %0, %1, %2, %0" : "+v"(d) : "v"(a), "v"(b));
}
__device__ __forceinline__ void gload16(const void* src, void* lds) {
    __builtin_amdgcn_global_load_lds(
        (const __attribute__((address_space(1))) unsigned int*)src,
        (__attribute__((address_space(3))) unsigned int*)lds, 16, 0, 0);
}

// inline int64-vs-int32 layout detection (odd 32-bit words all zero -> int64)
__device__ __forceinline__ int detect_is32_block(const unsigned* __restrict__ w,
                                                 int* s_is32, int tid) {
    if (tid == 0) {
        unsigned o = 0;
#pragma unroll
        for (int k = 1; k < 32; k += 2) o |= w[k];
        *s_is32 = (o != 0u);
    }
    __syncthreads();
    return *s_is32;
}

__device__ __forceinline__ int edge_elem(const unsigned* __restrict__ w, int is32, long long idx) {
    return is32 ? (int)w[idx] : (int)w[2 * idx];
}

// ---------------- fused prep: x->bf16, W1^T, W2^T, S1 bucket histogram, zero dhist/dcur ----------------
#define CONV_BLOCKS 6250   /* 50000*128/4 / 256 */
#define PREP_W_BLOCKS (CONV_BLOCKS + 128 + 256)
__global__ void __launch_bounds__(256) prep_kernel(const float* __restrict__ x,
                                                   ushort_t* __restrict__ xbf,
                                                   const float* __restrict__ W1,
                                                   ushort_t* __restrict__ W1t,
                                                   const float* __restrict__ W2,
                                                   ushort_t* __restrict__ W2t,
                                                   const unsigned* __restrict__ ew,
                                                   int* __restrict__ chunkHist,
                                                   int* __restrict__ dhist,
                                                   int* __restrict__ dcur) {
    int b = blockIdx.x, t = threadIdx.x;
    if (b < CONV_BLOCKS) {
        if (b == 0 && t < 64) { dhist[t] = 0; dcur[t] = 0; }
        int i = b * 256 + t;
        float4 v = ((const float4*)x)[i];
        ushort4 o;
        o.x = f2bf(v.x); o.y = f2bf(v.y); o.z = f2bf(v.z); o.w = f2bf(v.w);
        ((ushort4*)xbf)[i] = o;
    } else if (b < CONV_BLOCKS + 128) {
        int id = (b - CONV_BLOCKS) * 256 + t;       // id = n*128 + k
        int n = id >> 7, k = id & 127;
        W1t[id] = f2bf(W1[k * 256 + n]);
    } else if (b < CONV_BLOCKS + 128 + 256) {
        int id = (b - CONV_BLOCKS - 128) * 256 + t; // id = n*256 + k
        int n = id >> 8, k = id & 255;
        W2t[id] = f2bf(W2[k * 256 + n]);
    } else {
        // S1: per-chunk coarse-bucket histogram (bucket-major out)
        __shared__ int s_is32;
        __shared__ int hist[NBUCKET];
        int c = b - PREP_W_BLOCKS;
        int is32 = detect_is32_block(ew, &s_is32, t);
        for (int k = t; k < NBUCKET; k += 256) hist[k] = 0;
        __syncthreads();
        long long e0 = (long long)c * EPC;
        for (int k = t; k < EPC; k += 256) {
            int d = edge_elem(ew, is32, (long long)N_EDGES + e0 + k);
            atomicAdd(&hist[d >> 8], 1);
        }
        __syncthreads();
        for (int k = t; k < NBUCKET; k += 256)
            chunkHist[k * NCHUNK + c] = hist[k];
    }
}

// ---------------- scan over SCAN_N elements (block-local) ----------------
__global__ void __launch_bounds__(256) scan1_kernel(const int* __restrict__ in,
                                                    int* __restrict__ excl, int* __restrict__ bsum) {
    __shared__ int s[256];
    int b = blockIdx.x, t = threadIdx.x, i = b * 256 + t;
    int v = in[i];
    s[t] = v;
    __syncthreads();
    for (int off = 1; off < 256; off <<= 1) {
        int y = (t >= off) ? s[t - off] : 0;
        __syncthreads();
        s[t] += y;
        __syncthreads();
    }
    excl[i] = s[t] - v;
    if (t == 255) bsum[b] = s[255];
}

// scan3 with inlined bsum prefix (removes separate scan2 dispatch)
__global__ void __launch_bounds__(256) scan3_kernel(const int* __restrict__ bsum,
                                                    int* __restrict__ excl) {
    __shared__ int sboff;
    int b = blockIdx.x, t = threadIdx.x;
    if (t < 64) {
        int add = 0;
        for (int k = t; k < b; k += 64) add += bsum[k];
#pragma unroll
        for (int off = 32; off; off >>= 1) add += __shfl_down(add, off, 64);
        if (t == 0) sboff = add;
    }
    __syncthreads();
    excl[b * 256 + t] += sboff;
}

// ---------------- S3: scatter edges into bucket-sorted order (private runs) ----------------
__global__ void __launch_bounds__(256) bucket_scatter_kernel(const unsigned* __restrict__ ew,
                                                             const int* __restrict__ chunkOff,
                                                             unsigned* __restrict__ ebuf) {
    __shared__ int s_is32;
    __shared__ int cur[NBUCKET];
    int t = threadIdx.x, b = blockIdx.x;
    int is32 = detect_is32_block(ew, &s_is32, t);
    for (int k = t; k < NBUCKET; k += 256) cur[k] = chunkOff[k * NCHUNK + b];
    __syncthreads();
    long long e0 = (long long)b * EPC;
    for (int k = t; k < EPC; k += 256) {
        long long e = e0 + k;
        unsigned s = (unsigned)edge_elem(ew, is32, e);
        int d = edge_elem(ew, is32, (long long)N_EDGES + e);
        int pos = atomicAdd(&cur[d >> 8], 1);
        ebuf[pos] = s | ((unsigned)d << 16);
    }
}

// ---------------- S4: exact per-dst sort within bucket + row_ptr + degree hist ----------------
__global__ void __launch_bounds__(256) bucket_sort_kernel(const unsigned* __restrict__ ebuf,
                                                          const int* __restrict__ chunkOff,
                                                          unsigned* __restrict__ edge_csr,
                                                          int* __restrict__ row_ptr,
                                                          int* __restrict__ dhist) {
    __shared__ int cnt[256];
    __shared__ int s[256];
    __shared__ int dh[64];
    int b = blockIdx.x, t = threadIdx.x;
    int start = chunkOff[b * NCHUNK];
    int end = (b + 1 < NBUCKET) ? chunkOff[(b + 1) * NCHUNK] : N_EDGES;
    cnt[t] = 0;
    if (t < 64) dh[t] = 0;
    __syncthreads();
    for (int e = start + t; e < end; e += 256) {
        int d = (int)(ebuf[e] >> 16);
        atomicAdd(&cnt[d & 255], 1);
    }
    __syncthreads();
    int node = b * 256 + t;
    int mydeg = cnt[t];
    if (node < N_NODES) atomicAdd(&dh[mydeg < 63 ? mydeg : 63], 1);
    s[t] = mydeg;
    __syncthreads();
    for (int off = 1; off < 256; off <<= 1) {
        int y = (t >= off) ? s[t - off] : 0;
        __syncthreads();
        s[t] += y;
        __syncthreads();
    }
    int excl = s[t] - mydeg;
    if (node <= N_NODES) row_ptr[node] = start + excl;  // node==N_NODES at b=195,t=80
    cnt[t] = start + excl;  // becomes cursor
    __syncthreads();
    for (int e = start + t; e < end; e += 256) {
        unsigned pk = ebuf[e];
        int pos = atomicAdd(&cnt[(pk >> 16) & 255], 1);
        edge_csr[pos] = pk;
    }
    if (t < 64 && dh[t]) atomicAdd(&dhist[t], dh[t]);
}

// ---------------- scatter node ids into degree-grouped perm (inlined bin scan) ----------------
__global__ void __launch_bounds__(256) dscatter_kernel(const int* __restrict__ row_ptr,
                                                       const int* __restrict__ dhist,
                                                       int* __restrict__ dcur,
                                                       int* __restrict__ perm) {
    __shared__ int lh[64], lbase[64], sbase[64];
    int t = threadIdx.x, i = blockIdx.x * 256 + t;
    if (t < 64) {
        int v = dhist[t];
        int sum = v;
#pragma unroll
        for (int off = 1; off < 64; off <<= 1) {
            int y = __shfl_up(sum, off, 64);
            if (t >= off) sum += y;
        }
        sbase[t] = sum - v;
        lh[t] = 0;
    }
    __syncthreads();
    int deg = 0;
    if (i < N_NODES) {
        deg = row_ptr[i + 1] - row_ptr[i];
        if (deg > 63) deg = 63;
        atomicAdd(&lh[deg], 1);
    }
    __syncthreads();
    if (t < 64) {
        lbase[t] = lh[t] ? (sbase[t] + atomicAdd(&dcur[t], lh[t])) : 0;
        lh[t] = 0;
    }
    __syncthreads();
    if (i < N_NODES) {
        int rank = atomicAdd(&lh[deg], 1);
        perm[lbase[deg] + rank] = i;
    }
}

// ---------------- MFMA bf16 GEMM + fused alpha logits ----------------
// C[M,256] = A[M,K](bf16) @ Wt^T, stored as fp8 e4m3 (1B/ch).
// colblock == head; epilogue computes alpha_s/alpha_d from fp32 accs.
template <int K>
__global__ void __launch_bounds__(256) mfma_gemm_kernel(const ushort_t* __restrict__ A,
                                                        const ushort_t* __restrict__ Wt,
                                                        void* __restrict__ Cv, int M,
                                                        const float* __restrict__ a_src,
                                                        const float* __restrict__ a_dst,
                                                        float* __restrict__ alpha_s,
                                                        float* __restrict__ alpha_d) {
    constexpr int CPR = K / 8;
    constexpr int NT = K / 64;
    __shared__ ushort_t Bs[64 * K];
    __shared__ ushort_t As[2][64 * 64];
    __shared__ float ps[64][2], pd[64][2];

    int tid = threadIdx.x;
    int wave = tid >> 6, lane = tid & 63;
    int l15 = lane & 15, l4 = lane >> 4;
    int wr = wave >> 1, wc = wave & 1;
    int colblock = blockIdx.x;   // head
    int rowblock = blockIdx.y;

    for (int base = 0; base < 64 * CPR; base += 256) {
        int p = base + wave * 64 + lane;
        int row = p / CPR;
        int cs = p % CPR;
        int c = cs ^ (row & 7);
        const ushort_t* src = Wt + (long long)(colblock * 64 + row) * K + c * 8;
        void* dst = ((char*)Bs) + (base + wave * 64) * 16;
        gload16(src, dst);
    }
    {
        int r = lane >> 3, cs = lane & 7;
        int c = cs ^ r;
#pragma unroll
        for (int q = 0; q < 2; ++q) {
            int lrow = wave * 16 + q * 8;
            int grow = rowblock * 64 + lrow + r;
            if (grow >= M) grow = M - 1;
            const ushort_t* src = A + (long long)grow * K + c * 8;
            void* dst = ((char*)&As[0][0]) + lrow * 128;
            gload16(src, dst);
        }
    }
    __syncthreads();

    f32x4 acc[2][2] = {};
#pragma unroll
    for (int t = 0; t < NT; ++t) {
        if (t + 1 < NT) {
            int r = lane >> 3, cs = lane & 7;
            int c = cs ^ r;
#pragma unroll
            for (int q = 0; q < 2; ++q) {
                int lrow = wave * 16 + q * 8;
                int grow = rowblock * 64 + lrow + r;
                if (grow >= M) grow = M - 1;
                const ushort_t* src = A + (long long)grow * K + (t + 1) * 64 + c * 8;
                void* dst = ((char*)&As[(t + 1) & 1][0]) + lrow * 128;
                gload16(src, dst);
            }
        }
        const ushort_t* At = &As[t & 1][0];
#pragma unroll
        for (int w = 0; w < 2; ++w) {
            bf16x8 a[2], b[2];
#pragma unroll
            for (int mi = 0; mi < 2; ++mi) {
                int row = wr * 32 + mi * 16 + l15;
                int slot = (w * 4 + l4) ^ (l15 & 7);
                a[mi] = *(const bf16x8*)&At[row * 64 + slot * 8];
            }
#pragma unroll
            for (int ni = 0; ni < 2; ++ni) {
                int brow = wc * 32 + ni * 16 + l15;
                int slot = (t * 8 + w * 4 + l4) ^ (l15 & 7);
                b[ni] = *(const bf16x8*)&Bs[brow * CPR * 8 + slot * 8];
            }
#pragma unroll
            for (int mi = 0; mi < 2; ++mi)
#pragma unroll
                for (int ni = 0; ni < 2; ++ni)
                    acc[mi][ni] = __builtin_amdgcn_mfma_f32_16x16x32_bf16(a[mi], b[ni],
                                                                          acc[mi][ni], 0, 0, 0);
        }
        __syncthreads();
    }

    // ---- fused alpha partials: per-row dot with a_src/a_dst (this head) ----
    {
        float as0 = a_src[colblock * 64 + wc * 32 + l15];
        float as1 = a_src[colblock * 64 + wc * 32 + 16 + l15];
        float ad0 = a_dst[colblock * 64 + wc * 32 + l15];
        float ad1 = a_dst[colblock * 64 + wc * 32 + 16 + l15];
#pragma unroll
        for (int mi = 0; mi < 2; ++mi)
#pragma unroll
            for (int q = 0; q < 4; ++q) {
                float sv = acc[mi][0][q] * as0 + acc[mi][1][q] * as1;
                float dv = acc[mi][0][q] * ad0 + acc[mi][1][q] * ad1;
#pragma unroll
                for (int w = 1; w < 16; w <<= 1) {
                    sv += __shfl_xor(sv, w, 64);
                    dv += __shfl_xor(dv, w, 64);
                }
                if (l15 == 0) {
                    int row = wr * 32 + mi * 16 + l4 * 4 + q;
                    ps[row][wc] = sv;
                    pd[row][wc] = dv;
                }
            }
    }

    // ---- epilogue: repack via LDS (bf16 staging), store fp8 ----
    ushort_t* ep = ((ushort_t*)&As[0][0]) + wave * 1280;
#pragma unroll
    for (int mi = 0; mi < 2; ++mi)
#pragma unroll
        for (int ni = 0; ni < 2; ++ni)
#pragma unroll
            for (int q = 0; q < 4; ++q) {
                int row = mi * 16 + l4 * 4 + q;
                int col = ni * 16 + l15;
                ep[row * 40 + col] = f2bf(acc[mi][ni][q]);
            }
    __syncthreads();
#pragma unroll
    for (int j = 0; j < 2; ++j) {
        int p = lane * 2 + j;
        int row = p >> 2, seg = p & 3;
        uint4 v = *(const uint4*)&ep[row * 40 + seg * 8];
        int grow = rowblock * 64 + wr * 32 + row;
        int gcol = colblock * 64 + wc * 32 + seg * 8;
        if (grow < M) {
            f32x2 f01 = bfpair(v.x), f23 = bfpair(v.y);
            f32x2 f45 = bfpair(v.z), f67 = bfpair(v.w);
            int d0 = 0, d1 = 0;
            d0 = __builtin_amdgcn_cvt_pk_fp8_f32(f01.x, f01.y, d0, false);
            d0 = __builtin_amdgcn_cvt_pk_fp8_f32(f23.x, f23.y, d0, true);
            d1 = __builtin_amdgcn_cvt_pk_fp8_f32(f45.x, f45.y, d1, false);
            d1 = __builtin_amdgcn_cvt_pk_fp8_f32(f67.x, f67.y, d1, true);
            uint2 o; o.x = (unsigned)d0; o.y = (unsigned)d1;
            *(uint2*)((char*)Cv + (long long)grow * 256 + gcol) = o;
        }
    }
    if (tid < 64) {
        int ga = rowblock * 64 + tid;
        if (ga < M) {
            alpha_s[ga * 4 + colblock] = ps[tid][0] + ps[tid][1];
            alpha_d[ga * 4 + colblock] = pd[tid][0] + pd[tid][1];
        }
    }
}

// ---------------- softmax-weighted aggregation (one wave per node, degree-grouped) ----------------
// Per-edge weight exp deduplicated across the 16-lane head group:
// lane l computes wt for edge (l15 & (U-1)), head (l>>4); redistribution via __shfl.
template <int U>
__device__ __forceinline__ void agg_batch(int p, const unsigned* __restrict__ edge_csr,
                                          const float* __restrict__ alpha_s,
                                          const char* __restrict__ gb, unsigned loff,
                                          int l15, int hd, float ad, float& wsum,
                                          f32x2& acc01, f32x2& acc23) {
    int j[U]; unsigned hh[U];
#pragma unroll
    for (int u = 0; u < U; ++u) j[u] = (int)(edge_csr[p + u] & 0xFFFFu);
#pragma unroll
    for (int u = 0; u < U; ++u)
        hh[u] = *(const unsigned*)(gb + (((unsigned)j[u] << 8) | loff));
    // one exp per lane (direct load avoids runtime-indexed register array -> scratch)
    int myj = (int)(edge_csr[p + (l15 & (U - 1))] & 0xFFFFu);
    float e = alpha_s[myj * 4 + hd] + ad;
    e = e > 0.f ? e : 0.2f * e;
    float wt_mine = __expf(e);
    int sbase = hd << 4;
#pragma unroll
    for (int u = 0; u < U; ++u) {
        float wt = __shfl(wt_mine, sbase | u, 64);
        wsum += wt;
        f32x2 wp; wp.x = wt; wp.y = wt;
        pkfma(acc01, wp, __builtin_amdgcn_cvt_pk_f32_fp8(hh[u], false));
        pkfma(acc23, wp, __builtin_amdgcn_cvt_pk_f32_fp8(hh[u], true));
    }
}

template <int LAYER>
__global__ void __launch_bounds__(256) aggregate_kernel(
    const void* __restrict__ gv, const float* __restrict__ alpha_s,
    const float* __restrict__ alpha_d, const int* __restrict__ row_ptr,
    const unsigned* __restrict__ edge_csr, const int* __restrict__ perm,
    const float* __restrict__ bias, ushort_t* __restrict__ out_bf,
    const float* __restrict__ fc_w, const float* __restrict__ fc_b,
    float* __restrict__ final_out) {
    int wave = threadIdx.x >> 6;
    int lane = threadIdx.x & 63;
    int i = __builtin_amdgcn_readfirstlane(perm[blockIdx.x * 4 + wave]);
    int hd = lane >> 4;
    int l15 = lane & 15;
    const char* gb = (const char*)gv;           // fp8 rows: 256 B/row
    unsigned loff = (unsigned)(lane << 2);

    float ad = alpha_d[i * 4 + hd];
    // self loop
    float e0 = alpha_s[i * 4 + hd] + ad;
    e0 = e0 > 0.f ? e0 : 0.2f * e0;
    float w0 = __expf(e0);
    f32x2 acc01 = {0.f, 0.f}, acc23 = {0.f, 0.f};
    {
        unsigned sv = *(const unsigned*)(gb + (((unsigned)i << 8) | loff));
        f32x2 wp0; wp0.x = w0; wp0.y = w0;
        pkfma(acc01, wp0, __builtin_amdgcn_cvt_pk_f32_fp8(sv, false));
        pkfma(acc23, wp0, __builtin_amdgcn_cvt_pk_f32_fp8(sv, true));
    }
    float wsum = w0;

    int p = __builtin_amdgcn_readfirstlane(row_ptr[i]);
    int p1 = __builtin_amdgcn_readfirstlane(row_ptr[i + 1]);
    for (; p + 16 <= p1; p += 16)
        agg_batch<16>(p, edge_csr, alpha_s, gb, loff, l15, hd, ad, wsum, acc01, acc23);
    for (; p + 8 <= p1; p += 8)
        agg_batch<8>(p, edge_csr, alpha_s, gb, loff, l15, hd, ad, wsum, acc01, acc23);
    for (; p + 4 <= p1; p += 4)
        agg_batch<4>(p, edge_csr, alpha_s, gb, loff, l15, hd, ad, wsum, acc01, acc23);
    for (; p < p1; ++p)
        agg_batch<1>(p, edge_csr, alpha_s, gb, loff, l15, hd, ad, wsum, acc01, acc23);

    float inv = 1.f / (wsum + 1e-16f);
    int c = lane * 4;
    float4 b4 = *(const float4*)&bias[c];
    float o0 = acc01.x * inv + b4.x;
    float o1 = acc01.y * inv + b4.y;
    float o2 = acc23.x * inv + b4.z;
    float o3 = acc23.y * inv + b4.w;
    o0 = o0 > 0.f ? o0 : __expf(o0) - 1.f;
    o1 = o1 > 0.f ? o1 : __expf(o1) - 1.f;
    o2 = o2 > 0.f ? o2 : __expf(o2) - 1.f;
    o3 = o3 > 0.f ? o3 : __expf(o3) - 1.f;
    if (LAYER == 1) {
        ushort4 o;
        o.x = f2bf(o0); o.y = f2bf(o1); o.z = f2bf(o2); o.w = f2bf(o3);
        ((ushort4*)out_bf)[(long long)i * 64 + lane] = o;
    } else {
        float4 fw = *(const float4*)&fc_w[c];
        float dot = o0 * fw.x + o1 * fw.y + o2 * fw.z + o3 * fw.w;
#pragma unroll
        for (int off = 32; off; off >>= 1) dot += __shfl_down(dot, off, 64);
        if (lane == 0) final_out[i] = 1.f / (1.f + __expf(-(dot + fc_b[0])));
    }
}

// ---------------- launch ----------------
extern "C" void kernel_launch(void* const* d_in, const int* in_sizes, int n_in,
                              void* d_out, int out_size, void* d_ws, size_t ws_size,
                              hipStream_t stream) {
    const float* x   = (const float*)d_in[0];
    const unsigned* ei = (const unsigned*)d_in[1];
    const float* W1  = (const float*)d_in[2];
    const float* as1 = (const float*)d_in[3];
    const float* ad1 = (const float*)d_in[4];
    const float* b1  = (const float*)d_in[5];
    const float* W2  = (const float*)d_in[6];
    const float* as2 = (const float*)d_in[7];
    const float* ad2 = (const float*)d_in[8];
    const float* b2  = (const float*)d_in[9];
    const float* fcw = (const float*)d_in[10];
    const float* fcb = (const float*)d_in[11];

    char* ws = (char*)d_ws;
    void* g1f8         = (void*)(ws + 0);               // 12.8 MB (fp8)
    void* g2f8         = (void*)(ws + 12800000);        // 12.8 MB (fp8)
    ushort_t* hactbf   = (ushort_t*)(ws + 25600000);    // 25.6 MB
    ushort_t* xbf      = (ushort_t*)(ws + 51200000);    // 12.8 MB
    ushort_t* W1t      = (ushort_t*)(ws + 64000000);
    ushort_t* W2t      = (ushort_t*)(ws + 64100000);
    float* asv         = (float*)(ws + 64300000);
    float* adv         = (float*)(ws + 65100000);
    int* row_ptr       = (int*)(ws + 65900000);         // 50001 ints
    int* chunkHist     = (int*)(ws + 66110000);         // 50176 ints
    int* chunkOff      = (int*)(ws + 66320000);         // 50176 ints
    unsigned* ebuf     = (unsigned*)(ws + 66530000);    // 3.2 MB (bucket-sorted)
    unsigned* edge_csr = (unsigned*)(ws + 69730000);    // 3.2 MB (exact CSR)
    int* perm          = (int*)(ws + 72930000);         // 200 KB (degree-grouped order)
    int* bsum          = (int*)(ws + 73130000);         // 196 ints
    int* dhist         = (int*)(ws + 73132048);         // 64 ints
    int* dcur          = (int*)(ws + 73132304);         // 64 ints

    prep_kernel<<<PREP_W_BLOCKS + NCHUNK, 256, 0, stream>>>(x, xbf, W1, W1t, W2, W2t,
                                                            ei, chunkHist, dhist, dcur);
    scan1_kernel<<<SCAN_BLOCKS, 256, 0, stream>>>(chunkHist, chunkOff, bsum);
    scan3_kernel<<<SCAN_BLOCKS, 256, 0, stream>>>(bsum, chunkOff);
    bucket_scatter_kernel<<<NCHUNK, 256, 0, stream>>>(ei, chunkOff, ebuf);
    bucket_sort_kernel<<<NBUCKET, 256, 0, stream>>>(ebuf, chunkOff, edge_csr, row_ptr, dhist);
    dscatter_kernel<<<SCAN_BLOCKS, 256, 0, stream>>>(row_ptr, dhist, dcur, perm);

    // layer 1 (g stored fp8)
    mfma_gemm_kernel<128><<<dim3(4, (N_NODES + 63) / 64), 256, 0, stream>>>(
        xbf, W1t, g1f8, N_NODES, as1, ad1, asv, adv);
    aggregate_kernel<1><<<N_NODES / 4, 256, 0, stream>>>(g1f8, asv, adv, row_ptr, edge_csr, perm,
                                                         b1, hactbf, nullptr, nullptr, nullptr);
    // layer 2 (g stored fp8)
    mfma_gemm_kernel<256><<<dim3(4, (N_NODES + 63) / 64), 256, 0, stream>>>(
        hactbf, W2t, g2f8, N_NODES, as2, ad2, asv, adv);
    aggregate_kernel<2><<<N_NODES / 4, 256, 0, stream>>>(g2f8, asv, adv, row_ptr, edge_csr, perm,
                                                         b2, nullptr, fcw, fcb, (float*)d_out);
}